// Round 7
// baseline (1234.118 us; speedup 1.0000x reference)
//
#include <hip/hip_runtime.h>
#include <hip/hip_bf16.h>
#include <cmath>

#define NB 4
#define NNEG 33
#define NN 10000
#define NE 100000
#define NW 3
#define DD 64
#define NL 3
#define NR 200
#define NFL 2
#define NFFN 256
#define LN_EPS 1e-5f
#define RPB 4   // rows per k_xform block (132 = 33*4)

// ---- ws layout (float offsets) ----
// Interleaved state layout: XI[n][b][d] (node-major).
#define OFF_QUERY 0                                   // NB*DD
#define OFF_H0    256                                 // NB ints
#define OFF_TSW   288                                 // NB*NNEG ints
#define OFF_MINT  448                                 // 1 int
#define OFF_RELI  512                                 // NL*NR*NB*DD  relI[l][et][b][d]
#define OFF_TWI   (OFF_RELI + NL*NR*NB*DD)            // NL*NR*NB*DD
#define OFF_TBI   (OFF_TWI + NL*NR*NB*DD)             // NL*NR*NB*DD
#define OFF_LINT  (OFF_TBI + NL*NR*NB*DD)             // NL*2*DD*DD  linT[l][k][c]
#define OFF_X     (OFF_LINT + NL*2*DD*DD)             // NN*NB*DD (interleaved)
#define OFF_TOK   (OFF_X + NB*NN*DD)                  // NB*NNEG*NW*DD
#define OFF_X2    (OFF_TOK + NB*NNEG*NW*DD)           // NN*NB*DD
// int offsets (4B units)
#define IOFF_PTR  (OFF_X2 + NB*NN*DD)                 // NW*(NN+1) ints
#define IOFF_CUR  (IOFF_PTR + NW*(NN+1))              // NW*NN ints
#define IOFF_REC  ((IOFF_CUR + NW*NN + 3) & ~3)       // NW*NE*4 ints, 16B aligned

// ---------------- prep ----------------
__global__ void k_prep(const int* __restrict__ qt, const float* __restrict__ qemb,
                       float* __restrict__ ws) {
  int tid = threadIdx.x;
  if (tid < NB * DD) {
    int b = tid / DD, d = tid % DD;
    int h0 = qt[(b * NNEG + 0) * 3 + 0];
    bool itn = true;
    for (int j = 1; j < NNEG; ++j) itn = itn && (qt[(b * NNEG + j) * 3 + 0] == h0);
    int r0 = qt[(b * NNEG + 0) * 3 + 1] + (itn ? 0 : NR / 2);
    ws[OFF_QUERY + b * DD + d] = qemb[r0 * DD + d];
    if (d == 0) {
      int t0 = qt[(b * NNEG + 0) * 3 + 2];
      ((int*)ws)[OFF_H0 + b] = itn ? h0 : t0;
    }
  }
  if (tid < NB * NNEG) {
    int b = tid / NNEG, j = tid % NNEG;
    int h0 = qt[(b * NNEG + 0) * 3 + 0];
    bool itn = true;
    for (int jj = 1; jj < NNEG; ++jj) itn = itn && (qt[(b * NNEG + jj) * 3 + 0] == h0);
    int h = qt[(b * NNEG + j) * 3 + 0], t = qt[(b * NNEG + j) * 3 + 2];
    ((int*)ws)[OFF_TSW + tid] = itn ? t : h;
  }
  if (tid == 0) ((int*)ws)[OFF_MINT] = 0x7fffffff;
}

// ---------------- min over edge_time[0] ----------------
__global__ void k_mint(const int* __restrict__ etime, float* __restrict__ ws) {
  int i = blockIdx.x * blockDim.x + threadIdx.x;
  int v = (i < NE) ? etime[i] : 0x7fffffff;
  for (int m = 1; m < 64; m <<= 1) v = min(v, __shfl_xor(v, m));
  if ((threadIdx.x & 63) == 0) atomicMin(&((int*)ws)[OFF_MINT], v);
}

// ---------------- zero ptr array ----------------
__global__ void k_zero_ptr(float* __restrict__ ws) {
  int i = blockIdx.x * 256 + threadIdx.x;
  if (i < NW * (NN + 1)) ((int*)ws)[IOFF_PTR + i] = 0;
}

// ---------------- b-replicated tw/tb tables ----------------
__global__ void k_twprep(const float* __restrict__ tw, const float* __restrict__ tb,
                         float* __restrict__ ws) {
  int idx = blockIdx.x * 256 + threadIdx.x;
  if (idx >= NL * NR * NB * DD) return;
  int l = idx / (NR * NB * DD);
  int rem = idx % (NR * NB * DD);
  int et = rem >> 8;
  int d = rem & 63;
  ws[OFF_TWI + idx] = tw[(l * NR + et) * DD + d];
  ws[OFF_TBI + idx] = tb[(l * NR + et) * DD + d];
}

// ---------------- transpose lin_w: linT[l][k][c] = lin_w[l][c][k] ----------------
__global__ void k_transpose(const float* __restrict__ lin_w, float* __restrict__ ws) {
  int idx = blockIdx.x * blockDim.x + threadIdx.x;
  if (idx < NL * 2 * DD * DD) {
    int l = idx / (2 * DD * DD), r = idx % (2 * DD * DD), k = r / DD, c = r % DD;
    ws[OFF_LINT + idx] = lin_w[(l * DD + c) * 2 * DD + k];
  }
}

// ---------------- histogram of dst ----------------
__global__ void k_hist(const int* __restrict__ eidx, float* __restrict__ ws) {
  int e = blockIdx.x * 256 + threadIdx.x, w = blockIdx.y;
  if (e >= NE) return;
  int dst = eidx[(w * 2 + 1) * NE + e];
  atomicAdd(&((int*)ws)[IOFF_PTR + w * (NN + 1) + dst + 1], 1);
}

// ---------------- inclusive scan -> ptr (one block per w) ----------------
__global__ void k_scan(float* __restrict__ ws) {
  int w = blockIdx.x;
  int* p = (int*)ws + IOFF_PTR + w * (NN + 1);
  __shared__ int wsum[4];
  __shared__ int runv;
  if (threadIdx.x == 0) runv = 0;
  __syncthreads();
  int lane = threadIdx.x & 63, wv = threadIdx.x >> 6;
  for (int base = 0; base < NN + 1; base += 256) {
    int i = base + threadIdx.x;
    int v = (i <= NN) ? p[i] : 0;
    for (int off = 1; off < 64; off <<= 1) {
      int t = __shfl_up(v, off);
      if (lane >= off) v += t;
    }
    if (lane == 63) wsum[wv] = v;
    __syncthreads();
    int add = runv;
    for (int u = 0; u < wv; ++u) add += wsum[u];
    v += add;
    if (i <= NN) p[i] = v;
    __syncthreads();
    if (threadIdx.x == 255) runv = v;
    __syncthreads();
  }
}

// ---------------- cursor init ----------------
__global__ void k_curinit(float* __restrict__ ws) {
  int i = blockIdx.x * 256 + threadIdx.x;
  if (i >= NW * NN) return;
  int w = i / NN, n = i % NN;
  ((int*)ws)[IOFF_CUR + i] = ((int*)ws)[IOFF_PTR + w * (NN + 1) + n];
}

// ---------------- scatter edges into CSR records {src, et, dt, weight} ----------------
__global__ void k_scatter(const int* __restrict__ eidx, const int* __restrict__ etype,
                          const int* __restrict__ etime, const float* __restrict__ eweight,
                          float* __restrict__ ws) {
  int e = blockIdx.x * 256 + threadIdx.x, w = blockIdx.y;
  if (e >= NE) return;
  int* wsi = (int*)ws;
  int dst = eidx[(w * 2 + 1) * NE + e];
  int pos = atomicAdd(&wsi[IOFF_CUR + w * NN + dst], 1);
  float dt = (float)etime[w * NE + e] - (float)wsi[OFF_MINT];
  int4 rec;
  rec.x = eidx[(w * 2 + 0) * NE + e];
  rec.y = etype[w * NE + e];
  rec.z = __float_as_int(dt);
  rec.w = __float_as_int(eweight[w * NE + e]);
  ((int4*)(wsi + IOFF_REC))[(size_t)w * NE + pos] = rec;
}

// ---------------- rel = query @ rel_lin_w.T + b (written interleaved) ----------------
__global__ void k_rel(const float* __restrict__ rlw, const float* __restrict__ rlb,
                      float* __restrict__ ws) {
  int l = blockIdx.y;
  int rd = blockIdx.x * blockDim.x + threadIdx.x;
  const float4* wrow = (const float4*)(rlw + ((size_t)(l * NR * DD + rd)) * DD);
  float4 wreg[16];
#pragma unroll
  for (int kk = 0; kk < 16; ++kk) wreg[kk] = wrow[kk];
  float bias = rlb[l * NR * DD + rd];
  int r = rd >> 6, d = rd & 63;
  for (int b = 0; b < NB; ++b) {
    const float4* q4 = (const float4*)(ws + OFF_QUERY + b * DD);
    float acc = 0.f;
#pragma unroll
    for (int kk = 0; kk < 16; ++kk) {
      float4 q = q4[kk];
      acc += q.x * wreg[kk].x + q.y * wreg[kk].y + q.z * wreg[kk].z + q.w * wreg[kk].w;
    }
    ws[OFF_RELI + (size_t)(l * NR + r) * (NB * DD) + b * DD + d] = acc + bias;
  }
}

// ---------------- fused gather-aggregate + node GEMM + LN + residual ----------------
// Wave wv handles node n = blk*4+wv entirely:
//   phase 1 (gather): lane = b*16+q accumulates agg[n][b][4q..4q+3] -> LDS
//   phase 2 (gemm):   lane = c computes hid[n][b][c] for b=0..3, LN, residual, store.
__global__ __launch_bounds__(256) void k_aggemm(const float* __restrict__ xcur,
                                                float* __restrict__ xnxt,
                                                const float* __restrict__ linb,
                                                const float* __restrict__ lns,
                                                const float* __restrict__ lnb,
                                                const float* __restrict__ ws, int w, int l,
                                                int init0) {
  __shared__ float aggbuf[4][NB][DD];
  int lane = threadIdx.x & 63;
  int wv = threadIdx.x >> 6;
  int n = blockIdx.x * 4 + wv;
  int b = lane >> 4;
  const int* wsi = (const int*)ws;
  int p0 = __builtin_amdgcn_readfirstlane(wsi[IOFF_PTR + w * (NN + 1) + n]);
  int p1 = __builtin_amdgcn_readfirstlane(wsi[IOFF_PTR + w * (NN + 1) + n + 1]);
  const int4* recs = ((const int4*)(wsi + IOFF_REC)) + (size_t)w * NE;
  const float4* XI4 = (const float4*)xcur;
  const float4* RELI4 = (const float4*)(ws + OFF_RELI) + (size_t)l * NR * 64;
  const float4* TWI4 = (const float4*)(ws + OFF_TWI) + (size_t)l * NR * 64;
  const float4* TBI4 = (const float4*)(ws + OFF_TBI) + (size_t)l * NR * 64;
  int h00 = wsi[OFF_H0 + 0], h01 = wsi[OFF_H0 + 1];
  int h02 = wsi[OFF_H0 + 2], h03 = wsi[OFF_H0 + 3];
  int h0b = wsi[OFF_H0 + b];
  float4 q4b = ((const float4*)(ws + OFF_QUERY))[lane];
  float4 acc;
  if (n == h0b) acc = q4b;
  else { acc.x = 0.f; acc.y = 0.f; acc.z = 0.f; acc.w = 0.f; }

  if (init0) {
    for (int j = p0; j < p1; ++j) {
      int4 rec = recs[j];
      int src = rec.x;
      if (!((src == h00) | (src == h01) | (src == h02) | (src == h03))) continue;
      int et = rec.y;
      float dtf = __int_as_float(rec.z);
      float m = (src == h0b) ? __int_as_float(rec.w) : 0.f;
      int base = et * 64 + lane;
      float4 r4 = RELI4[base];
      float4 w4 = TWI4[base];
      float4 b4 = TBI4[base];
      acc.x = fmaf(q4b.x * r4.x, cosf(fmaf(dtf, w4.x, b4.x)) * m, acc.x);
      acc.y = fmaf(q4b.y * r4.y, cosf(fmaf(dtf, w4.y, b4.y)) * m, acc.y);
      acc.z = fmaf(q4b.z * r4.z, cosf(fmaf(dtf, w4.z, b4.z)) * m, acc.z);
      acc.w = fmaf(q4b.w * r4.w, cosf(fmaf(dtf, w4.w, b4.w)) * m, acc.w);
    }
  } else {
#define EDGE_BODY(J)                                                        \
    {                                                                       \
      int4 rec = recs[J];                                                   \
      int src = rec.x, et = rec.y;                                          \
      float dtf = __int_as_float(rec.z), wgt = __int_as_float(rec.w);       \
      int base = et * 64 + lane;                                            \
      float4 x4 = XI4[(size_t)src * 64 + lane];                             \
      float4 r4 = RELI4[base];                                              \
      float4 w4 = TWI4[base];                                               \
      float4 b4 = TBI4[base];                                               \
      acc.x = fmaf(x4.x * r4.x, cosf(fmaf(dtf, w4.x, b4.x)) * wgt, acc.x);  \
      acc.y = fmaf(x4.y * r4.y, cosf(fmaf(dtf, w4.y, b4.y)) * wgt, acc.y);  \
      acc.z = fmaf(x4.z * r4.z, cosf(fmaf(dtf, w4.z, b4.z)) * wgt, acc.z);  \
      acc.w = fmaf(x4.w * r4.w, cosf(fmaf(dtf, w4.w, b4.w)) * wgt, acc.w);  \
    }
    int j = p0;
    for (; j + 1 < p1; j += 2) {
      EDGE_BODY(j);
      EDGE_BODY(j + 1);
    }
    if (j < p1) EDGE_BODY(j);
#undef EDGE_BODY
  }
  // wave-private LDS handoff (intra-wave: no __syncthreads needed)
  *(float4*)&aggbuf[wv][b][(lane & 15) * 4] = acc;

  // ---- GEMM phase: lane = output col c ----
  int c = lane;
  const float* WT = ws + OFF_LINT + l * 2 * DD * DD;  // [128][64]
  float bias = linb[l * DD + c];
  float ga[NB];
#pragma unroll
  for (int r = 0; r < NB; ++r) ga[r] = bias;
  if (init0) {
#pragma unroll
    for (int r = 0; r < NB; ++r) {
      if (n == wsi[OFF_H0 + r]) {
        const float4* q4 = (const float4*)(ws + OFF_QUERY + r * DD);
        for (int kk = 0; kk < 16; ++kk) {
          float4 q = q4[kk];
          ga[r] = fmaf(q.x, WT[(4 * kk + 0) * DD + c], ga[r]);
          ga[r] = fmaf(q.y, WT[(4 * kk + 1) * DD + c], ga[r]);
          ga[r] = fmaf(q.z, WT[(4 * kk + 2) * DD + c], ga[r]);
          ga[r] = fmaf(q.w, WT[(4 * kk + 3) * DD + c], ga[r]);
        }
      }
    }
  } else {
    const float4* xr = (const float4*)(xcur + (size_t)n * (NB * DD));
    for (int kk = 0; kk < 16; ++kk) {
      float w0 = WT[(4 * kk + 0) * DD + c];
      float w1 = WT[(4 * kk + 1) * DD + c];
      float w2 = WT[(4 * kk + 2) * DD + c];
      float w3 = WT[(4 * kk + 3) * DD + c];
#pragma unroll
      for (int r = 0; r < NB; ++r) {
        float4 xv = xr[r * 16 + kk];  // lane-uniform broadcast
        ga[r] = fmaf(xv.x, w0, ga[r]);
        ga[r] = fmaf(xv.y, w1, ga[r]);
        ga[r] = fmaf(xv.z, w2, ga[r]);
        ga[r] = fmaf(xv.w, w3, ga[r]);
      }
    }
  }
  for (int kk = 0; kk < 16; ++kk) {
    float w0 = WT[(64 + 4 * kk + 0) * DD + c];
    float w1 = WT[(64 + 4 * kk + 1) * DD + c];
    float w2 = WT[(64 + 4 * kk + 2) * DD + c];
    float w3 = WT[(64 + 4 * kk + 3) * DD + c];
#pragma unroll
    for (int r = 0; r < NB; ++r) {
      float4 av = *(const float4*)&aggbuf[wv][r][4 * kk];  // broadcast
      ga[r] = fmaf(av.x, w0, ga[r]);
      ga[r] = fmaf(av.y, w1, ga[r]);
      ga[r] = fmaf(av.z, w2, ga[r]);
      ga[r] = fmaf(av.w, w3, ga[r]);
    }
  }
  float sc = lns[l * DD + c], bc = lnb[l * DD + c];
#pragma unroll
  for (int r = 0; r < NB; ++r) {
    float v = ga[r];
    float s = v;
    for (int m = 1; m < 64; m <<= 1) s += __shfl_xor(s, m);
    float mean = s * (1.f / 64.f);
    float cv = v - mean;
    float vv = cv * cv;
    for (int m = 1; m < 64; m <<= 1) vv += __shfl_xor(vv, m);
    vv *= (1.f / 64.f);
    float y = cv * __frsqrt_rn(vv + LN_EPS) * sc + bc;
    y = fmaxf(y, 0.f);
    float xo;
    if (init0)
      xo = (n == wsi[OFF_H0 + r]) ? ws[OFF_QUERY + r * DD + c] : 0.f;
    else
      xo = xcur[(size_t)n * (NB * DD) + r * DD + c];
    xnxt[(size_t)n * (NB * DD) + r * DD + c] = xo + y;
  }
}

// ---------------- gather tail features into tokens (+pe) ----------------
__global__ void k_gather(const float* __restrict__ pe, const float* __restrict__ xfin,
                         float* __restrict__ ws, int w) {
  int i = blockIdx.x * 256 + threadIdx.x;
  if (i >= NB * NNEG * DD) return;
  int bj = i / DD, d = i % DD;
  int b = bj / NNEG;
  int t = ((const int*)ws)[OFF_TSW + bj];
  ws[OFF_TOK + bj * NW * DD + w * DD + d] =
      xfin[(size_t)t * (NB * DD) + b * DD + d] + pe[w * DD + d];
}

// ---------------- transformer + final MLP: LDS weights, 4 rows/thread ----------------
__global__ __launch_bounds__(192) void k_xform(
    const float* __restrict__ wq, const float* __restrict__ wk,
    const float* __restrict__ wv, const float* __restrict__ wo,
    const float* __restrict__ ffw1, const float* __restrict__ ffb1,
    const float* __restrict__ ffw2, const float* __restrict__ ffb2,
    const float* __restrict__ fln1s, const float* __restrict__ fln1b,
    const float* __restrict__ fln2s, const float* __restrict__ fln2b,
    const float* __restrict__ m1w, const float* __restrict__ m1b,
    const float* __restrict__ m2w, const float* __restrict__ m2b,
    float* __restrict__ ws, float* __restrict__ out) {
  __shared__ float tok[RPB][NW][DD], kvb[RPB][NW][DD], vvb[RPB][NW][DD];
  __shared__ float hbuf[RPB][NW][NFFN];
  __shared__ float feat[RPB][2 * DD];
  __shared__ float red[RPB][2];
  __shared__ float4 wbuf4[4352];  // 68 KB padded staging buffer
  int tid = threadIdx.x;          // 0..191
  int tk = tid >> 6, d = tid & 63;
  int row0 = blockIdx.x * RPB;
#pragma unroll
  for (int rr = 0; rr < RPB; ++rr)
    tok[rr][tk][d] = ws[OFF_TOK + (row0 + rr) * NW * DD + tk * DD + d];
  float t1[RPB];
  for (int f = 0; f < NFL; ++f) {
    // ---- stage wq,wk,wv,wo as 4x [64][68] ----
    {
      const float4* s0 = (const float4*)(wq + (size_t)f * DD * DD);
      const float4* s1 = (const float4*)(wk + (size_t)f * DD * DD);
      const float4* s2 = (const float4*)(wv + (size_t)f * DD * DD);
      const float4* s3 = (const float4*)(wo + (size_t)f * DD * DD);
      for (int idx = tid; idx < 4096; idx += 192) {
        int m = idx >> 10, rem = idx & 1023;
        int rrow = rem >> 4, c4 = rem & 15;
        const float4* s = (m == 0) ? s0 : (m == 1) ? s1 : (m == 2) ? s2 : s3;
        wbuf4[(m * 64 + rrow) * 17 + c4] = s[rem];
      }
    }
    __syncthreads();
    // ---- QKV: weights read once, applied to 4 rows ----
    float qd[RPB], kd[RPB], vd[RPB];
#pragma unroll
    for (int rr = 0; rr < RPB; ++rr) { qd[rr] = 0.f; kd[rr] = 0.f; vd[rr] = 0.f; }
#pragma unroll
    for (int kk = 0; kk < 16; ++kk) {
      float4 aq = wbuf4[(0 * 64 + d) * 17 + kk];
      float4 ak = wbuf4[(1 * 64 + d) * 17 + kk];
      float4 av = wbuf4[(2 * 64 + d) * 17 + kk];
#pragma unroll
      for (int rr = 0; rr < RPB; ++rr) {
        float4 tv = *(const float4*)&tok[rr][tk][4 * kk];
        qd[rr] += tv.x * aq.x + tv.y * aq.y + tv.z * aq.z + tv.w * aq.w;
        kd[rr] += tv.x * ak.x + tv.y * ak.y + tv.z * ak.z + tv.w * ak.w;
        vd[rr] += tv.x * av.x + tv.y * av.y + tv.z * av.z + tv.w * av.w;
      }
    }
#pragma unroll
    for (int rr = 0; rr < RPB; ++rr) {
      kvb[rr][tk][d] = kd[rr];
      vvb[rr][tk][d] = vd[rr];
    }
    __syncthreads();
    // ---- attention (head = d>>4) ----
    float od[RPB];
#pragma unroll
    for (int rr = 0; rr < RPB; ++rr) {
      float sc[NW];
#pragma unroll
      for (int j = 0; j < NW; ++j) {
        float p = qd[rr] * kvb[rr][j][d];
        p += __shfl_xor(p, 1);
        p += __shfl_xor(p, 2);
        p += __shfl_xor(p, 4);
        p += __shfl_xor(p, 8);
        sc[j] = p * 0.25f;  // 1/sqrt(16)
      }
      float mx = fmaxf(sc[0], fmaxf(sc[1], sc[2]));
      float e0 = expf(sc[0] - mx), e1 = expf(sc[1] - mx), e2 = expf(sc[2] - mx);
      float inv = 1.f / (e0 + e1 + e2);
      od[rr] = (e0 * vvb[rr][0][d] + e1 * vvb[rr][1][d] + e2 * vvb[rr][2][d]) * inv;
    }
    __syncthreads();
#pragma unroll
    for (int rr = 0; rr < RPB; ++rr) kvb[rr][tk][d] = od[rr];  // o-buffer (wave rows)
    // ---- o @ wo.T ----
    float ao[RPB];
#pragma unroll
    for (int rr = 0; rr < RPB; ++rr) ao[rr] = 0.f;
#pragma unroll
    for (int kk = 0; kk < 16; ++kk) {
      float4 w4 = wbuf4[(3 * 64 + d) * 17 + kk];
#pragma unroll
      for (int rr = 0; rr < RPB; ++rr) {
        float4 ov = *(const float4*)&kvb[rr][tk][4 * kk];
        ao[rr] += ov.x * w4.x + ov.y * w4.y + ov.z * w4.z + ov.w * w4.w;
      }
    }
    float g1 = fln1s[f * DD + d], b1 = fln1b[f * DD + d];
#pragma unroll
    for (int rr = 0; rr < RPB; ++rr) {
      float t = tok[rr][tk][d] + ao[rr];
      float s = t;
      for (int m = 1; m < 64; m <<= 1) s += __shfl_xor(s, m);
      float mean = s * (1.f / 64.f);
      float cv = t - mean;
      float v = cv * cv;
      for (int m = 1; m < 64; m <<= 1) v += __shfl_xor(v, m);
      v *= (1.f / 64.f);
      t1[rr] = cv * __frsqrt_rn(v + LN_EPS) * g1 + b1;
      tok[rr][tk][d] = t1[rr];
    }
    __syncthreads();
    // ---- stage ffw1 [256][68] ----
    {
      const float4* s4 = (const float4*)(ffw1 + (size_t)f * NFFN * DD);
      for (int idx = tid; idx < 4096; idx += 192) {
        int rrow = idx >> 4, c4 = idx & 15;
        wbuf4[rrow * 17 + c4] = s4[idx];
      }
    }
    __syncthreads();
    // ---- FFN1: 4 hidden units x 4 rows per thread ----
    float h[4][RPB];
#pragma unroll
    for (int uu = 0; uu < 4; ++uu) {
      float bb = ffb1[f * NFFN + d + 64 * uu];
#pragma unroll
      for (int rr = 0; rr < RPB; ++rr) h[uu][rr] = bb;
    }
#pragma unroll
    for (int kk = 0; kk < 16; ++kk) {
      float4 w0 = wbuf4[(d + 0) * 17 + kk];
      float4 w1 = wbuf4[(d + 64) * 17 + kk];
      float4 w2 = wbuf4[(d + 128) * 17 + kk];
      float4 w3 = wbuf4[(d + 192) * 17 + kk];
#pragma unroll
      for (int rr = 0; rr < RPB; ++rr) {
        float4 tv = *(const float4*)&tok[rr][tk][4 * kk];
        h[0][rr] += tv.x * w0.x + tv.y * w0.y + tv.z * w0.z + tv.w * w0.w;
        h[1][rr] += tv.x * w1.x + tv.y * w1.y + tv.z * w1.z + tv.w * w1.w;
        h[2][rr] += tv.x * w2.x + tv.y * w2.y + tv.z * w2.z + tv.w * w2.w;
        h[3][rr] += tv.x * w3.x + tv.y * w3.y + tv.z * w3.z + tv.w * w3.w;
      }
    }
#pragma unroll
    for (int uu = 0; uu < 4; ++uu)
#pragma unroll
      for (int rr = 0; rr < RPB; ++rr)
        hbuf[rr][tk][d + 64 * uu] = fmaxf(h[uu][rr], 0.f);
    __syncthreads();
    // ---- stage ffw2 [64][260] ----
    {
      const float4* s4 = (const float4*)(ffw2 + (size_t)f * DD * NFFN);
      for (int idx = tid; idx < 4096; idx += 192) {
        int rrow = idx >> 6, c4 = idx & 63;
        wbuf4[rrow * 65 + c4] = s4[idx];
      }
    }
    __syncthreads();
    // ---- FFN2 ----
    float ff[RPB];
    float fb2 = ffb2[f * DD + d];
#pragma unroll
    for (int rr = 0; rr < RPB; ++rr) ff[rr] = fb2;
#pragma unroll 8
    for (int kk = 0; kk < 64; ++kk) {
      float4 w4 = wbuf4[d * 65 + kk];
#pragma unroll
      for (int rr = 0; rr < RPB; ++rr) {
        float4 hv = *(const float4*)&hbuf[rr][tk][4 * kk];
        ff[rr] += hv.x * w4.x + hv.y * w4.y + hv.z * w4.z + hv.w * w4.w;
      }
    }
    float g2 = fln2s[f * DD + d], b2 = fln2b[f * DD + d];
#pragma unroll
    for (int rr = 0; rr < RPB; ++rr) {
      float t = t1[rr] + ff[rr];
      float s = t;
      for (int m = 1; m < 64; m <<= 1) s += __shfl_xor(s, m);
      float mean = s * (1.f / 64.f);
      float cv = t - mean;
      float v = cv * cv;
      for (int m = 1; m < 64; m <<= 1) v += __shfl_xor(v, m);
      v *= (1.f / 64.f);
      tok[rr][tk][d] = cv * __frsqrt_rn(v + LN_EPS) * g2 + b2;
    }
    __syncthreads();
  }
  // ---- final MLP ----
  if (tk == 2) {
#pragma unroll
    for (int rr = 0; rr < RPB; ++rr) {
      int b = (row0 + rr) / NNEG;
      feat[rr][d] = tok[rr][2][d];
      feat[rr][DD + d] = ws[OFF_QUERY + b * DD + d];
    }
  }
  {
    const float4* s4 = (const float4*)m1w;
    for (int idx = tid; idx < 4096; idx += 192) {
      int rrow = idx >> 5, c4 = idx & 31;
      wbuf4[rrow * 33 + c4] = s4[idx];
    }
  }
  __syncthreads();
  float partial[RPB];
#pragma unroll
  for (int rr = 0; rr < RPB; ++rr) partial[rr] = 0.f;
  if (tid < 2 * DD) {
    int hh = tid;
    float mb = m1b[hh], mw = m2w[hh];
#pragma unroll
    for (int rr = 0; rr < RPB; ++rr) {
      float acc = mb;
#pragma unroll
      for (int kk = 0; kk < 32; ++kk) {
        float4 fv = *(const float4*)&feat[rr][4 * kk];
        float4 w4 = wbuf4[hh * 33 + kk];
        acc += fv.x * w4.x + fv.y * w4.y + fv.z * w4.z + fv.w * w4.w;
      }
      partial[rr] = fmaxf(acc, 0.f) * mw;
    }
  }
#pragma unroll
  for (int rr = 0; rr < RPB; ++rr) {
    float p = partial[rr];
    for (int m = 1; m < 64; m <<= 1) p += __shfl_xor(p, m);
    if (d == 0 && tk < 2) red[rr][tk] = p;
  }
  __syncthreads();
  if (tid < RPB) out[row0 + tid] = red[tid][0] + red[tid][1] + m2b[0];
}

extern "C" void kernel_launch(void* const* d_in, const int* in_sizes, int n_in,
                              void* d_out, int out_size, void* d_ws, size_t ws_size,
                              hipStream_t stream) {
  const int* qt = (const int*)d_in[0];
  const int* eidx = (const int*)d_in[1];
  const int* etype = (const int*)d_in[2];
  const int* etime = (const int*)d_in[3];
  const float* qemb = (const float*)d_in[4];
  const float* ew = (const float*)d_in[5];
  const float* rlw = (const float*)d_in[6];
  const float* rlb = (const float*)d_in[7];
  const float* tw = (const float*)d_in[8];
  const float* tb = (const float*)d_in[9];
  const float* linw = (const float*)d_in[10];
  const float* linb = (const float*)d_in[11];
  const float* lns = (const float*)d_in[12];
  const float* lnb = (const float*)d_in[13];
  const float* pe = (const float*)d_in[14];
  const float* wq = (const float*)d_in[15];
  const float* wk = (const float*)d_in[16];
  const float* wv = (const float*)d_in[17];
  const float* wo = (const float*)d_in[18];
  const float* ffw1 = (const float*)d_in[19];
  const float* ffb1 = (const float*)d_in[20];
  const float* ffw2 = (const float*)d_in[21];
  const float* ffb2 = (const float*)d_in[22];
  const float* fln1s = (const float*)d_in[23];
  const float* fln1b = (const float*)d_in[24];
  const float* fln2s = (const float*)d_in[25];
  const float* fln2b = (const float*)d_in[26];
  const float* m1w = (const float*)d_in[27];
  const float* m1b = (const float*)d_in[28];
  const float* m2w = (const float*)d_in[29];
  const float* m2b = (const float*)d_in[30];
  float* ws = (float*)d_ws;
  float* out = (float*)d_out;

  k_prep<<<1, 256, 0, stream>>>(qt, qemb, ws);
  k_mint<<<(NE + 255) / 256, 256, 0, stream>>>(etime, ws);
  k_zero_ptr<<<(NW * (NN + 1) + 255) / 256, 256, 0, stream>>>(ws);
  k_twprep<<<(NL * NR * NB * DD + 255) / 256, 256, 0, stream>>>(tw, tb, ws);
  k_transpose<<<(NL * 2 * DD * DD + 255) / 256, 256, 0, stream>>>(linw, ws);
  k_rel<<<dim3(NR * DD / 256, NL), 256, 0, stream>>>(rlw, rlb, ws);
  k_hist<<<dim3((NE + 255) / 256, NW), 256, 0, stream>>>(eidx, ws);
  k_scan<<<NW, 256, 0, stream>>>(ws);
  k_curinit<<<(NW * NN + 255) / 256, 256, 0, stream>>>(ws);
  k_scatter<<<dim3((NE + 255) / 256, NW), 256, 0, stream>>>(eidx, etype, etime, ew, ws);

  float* X = ws + OFF_X;
  float* X2 = ws + OFF_X2;
  for (int w = 0; w < NW; ++w) {
    float* cur = X;
    float* nxt = X2;
    for (int l = 0; l < NL; ++l) {
      int init0 = (l == 0) ? 1 : 0;
      k_aggemm<<<NN / 4, 256, 0, stream>>>(cur, nxt, linb, lns, lnb, ws, w, l, init0);
      float* t = cur; cur = nxt; nxt = t;
    }
    k_gather<<<(NB * NNEG * DD + 255) / 256, 256, 0, stream>>>(pe, cur, ws, w);
  }
  k_xform<<<NB * NNEG / RPB, 192, 0, stream>>>(wq, wk, wv, wo, ffw1, ffb1, ffw2, ffb2,
                                                fln1s, fln1b, fln2s, fln2b, m1w, m1b, m2w,
                                                m2b, ws, out);
}

// Round 8
// 648.022 us; speedup vs baseline: 1.9044x; 1.9044x over previous
//
#include <hip/hip_runtime.h>
#include <hip/hip_bf16.h>
#include <cmath>

#define NB 4
#define NNEG 33
#define NN 10000
#define NE 100000
#define NW 3
#define DD 64
#define NL 3
#define NR 200
#define NFL 2
#define NFFN 256
#define LN_EPS 1e-5f
#define RPB 4   // rows per k_xform block (132 = 33*4)

// ---- ws layout (float offsets) ----
// Interleaved state layout: XI[n][b][d] (node-major).
#define OFF_QUERY 0                                   // NB*DD
#define OFF_H0    256                                 // NB ints
#define OFF_TSW   288                                 // NB*NNEG ints
#define OFF_MINT  448                                 // 1 int
#define OFF_RELI  512                                 // NL*NR*NB*DD  relI[l][et][b][d]
#define OFF_LINT  (OFF_RELI + NL*NR*NB*DD)            // NL*2*DD*DD  linT[l][k][c]
#define OFF_X     (OFF_LINT + NL*2*DD*DD)             // NN*NB*DD (interleaved)
#define OFF_AGG   (OFF_X + NB*NN*DD)                  // NN*NB*DD
#define OFF_TOK   (OFF_AGG + NB*NN*DD)                // NB*NNEG*NW*DD
#define OFF_X2    (OFF_TOK + NB*NNEG*NW*DD)           // NN*NB*DD
// int offsets (4B units)
#define IOFF_PTR  (OFF_X2 + NB*NN*DD)                 // NW*(NN+1) ints
#define IOFF_CUR  (IOFF_PTR + NW*(NN+1))              // NW*NN ints
#define IOFF_REC  ((IOFF_CUR + NW*NN + 3) & ~3)       // NW*NE*4 ints, 16B aligned

// ---------------- prep ----------------
__global__ void k_prep(const int* __restrict__ qt, const float* __restrict__ qemb,
                       float* __restrict__ ws) {
  int tid = threadIdx.x;
  if (tid < NB * DD) {
    int b = tid / DD, d = tid % DD;
    int h0 = qt[(b * NNEG + 0) * 3 + 0];
    bool itn = true;
    for (int j = 1; j < NNEG; ++j) itn = itn && (qt[(b * NNEG + j) * 3 + 0] == h0);
    int r0 = qt[(b * NNEG + 0) * 3 + 1] + (itn ? 0 : NR / 2);
    ws[OFF_QUERY + b * DD + d] = qemb[r0 * DD + d];
    if (d == 0) {
      int t0 = qt[(b * NNEG + 0) * 3 + 2];
      ((int*)ws)[OFF_H0 + b] = itn ? h0 : t0;
    }
  }
  if (tid < NB * NNEG) {
    int b = tid / NNEG, j = tid % NNEG;
    int h0 = qt[(b * NNEG + 0) * 3 + 0];
    bool itn = true;
    for (int jj = 1; jj < NNEG; ++jj) itn = itn && (qt[(b * NNEG + jj) * 3 + 0] == h0);
    int h = qt[(b * NNEG + j) * 3 + 0], t = qt[(b * NNEG + j) * 3 + 2];
    ((int*)ws)[OFF_TSW + tid] = itn ? t : h;
  }
  if (tid == 0) ((int*)ws)[OFF_MINT] = 0x7fffffff;
}

// ---------------- min over edge_time[0] ----------------
__global__ void k_mint(const int* __restrict__ etime, float* __restrict__ ws) {
  int i = blockIdx.x * blockDim.x + threadIdx.x;
  int v = (i < NE) ? etime[i] : 0x7fffffff;
  for (int m = 1; m < 64; m <<= 1) v = min(v, __shfl_xor(v, m));
  if ((threadIdx.x & 63) == 0) atomicMin(&((int*)ws)[OFF_MINT], v);
}

// ---------------- zero ptr array ----------------
__global__ void k_zero_ptr(float* __restrict__ ws) {
  int i = blockIdx.x * 256 + threadIdx.x;
  if (i < NW * (NN + 1)) ((int*)ws)[IOFF_PTR + i] = 0;
}

// ---------------- transpose lin_w: linT[l][k][c] = lin_w[l][c][k] ----------------
__global__ void k_transpose(const float* __restrict__ lin_w, float* __restrict__ ws) {
  int idx = blockIdx.x * blockDim.x + threadIdx.x;
  if (idx < NL * 2 * DD * DD) {
    int l = idx / (2 * DD * DD), r = idx % (2 * DD * DD), k = r / DD, c = r % DD;
    ws[OFF_LINT + idx] = lin_w[(l * DD + c) * 2 * DD + k];
  }
}

// ---------------- histogram of dst ----------------
__global__ void k_hist(const int* __restrict__ eidx, float* __restrict__ ws) {
  int e = blockIdx.x * 256 + threadIdx.x, w = blockIdx.y;
  if (e >= NE) return;
  int dst = eidx[(w * 2 + 1) * NE + e];
  atomicAdd(&((int*)ws)[IOFF_PTR + w * (NN + 1) + dst + 1], 1);
}

// ---------------- inclusive scan -> ptr (one block per w) ----------------
__global__ void k_scan(float* __restrict__ ws) {
  int w = blockIdx.x;
  int* p = (int*)ws + IOFF_PTR + w * (NN + 1);
  __shared__ int wsum[4];
  __shared__ int runv;
  if (threadIdx.x == 0) runv = 0;
  __syncthreads();
  int lane = threadIdx.x & 63, wv = threadIdx.x >> 6;
  for (int base = 0; base < NN + 1; base += 256) {
    int i = base + threadIdx.x;
    int v = (i <= NN) ? p[i] : 0;
    for (int off = 1; off < 64; off <<= 1) {
      int t = __shfl_up(v, off);
      if (lane >= off) v += t;
    }
    if (lane == 63) wsum[wv] = v;
    __syncthreads();
    int add = runv;
    for (int u = 0; u < wv; ++u) add += wsum[u];
    v += add;
    if (i <= NN) p[i] = v;
    __syncthreads();
    if (threadIdx.x == 255) runv = v;
    __syncthreads();
  }
}

// ---------------- cursor init ----------------
__global__ void k_curinit(float* __restrict__ ws) {
  int i = blockIdx.x * 256 + threadIdx.x;
  if (i >= NW * NN) return;
  int w = i / NN, n = i % NN;
  ((int*)ws)[IOFF_CUR + i] = ((int*)ws)[IOFF_PTR + w * (NN + 1) + n];
}

// ---------------- scatter edges into CSR records {src, et, dt, weight} ----------------
__global__ void k_scatter(const int* __restrict__ eidx, const int* __restrict__ etype,
                          const int* __restrict__ etime, const float* __restrict__ eweight,
                          float* __restrict__ ws) {
  int e = blockIdx.x * 256 + threadIdx.x, w = blockIdx.y;
  if (e >= NE) return;
  int* wsi = (int*)ws;
  int dst = eidx[(w * 2 + 1) * NE + e];
  int pos = atomicAdd(&wsi[IOFF_CUR + w * NN + dst], 1);
  float dt = (float)etime[w * NE + e] - (float)wsi[OFF_MINT];
  int4 rec;
  rec.x = eidx[(w * 2 + 0) * NE + e];
  rec.y = etype[w * NE + e];
  rec.z = __float_as_int(dt);
  rec.w = __float_as_int(eweight[w * NE + e]);
  ((int4*)(wsi + IOFF_REC))[(size_t)w * NE + pos] = rec;
}

// ---------------- rel = query @ rel_lin_w.T + b (written interleaved) ----------------
__global__ void k_rel(const float* __restrict__ rlw, const float* __restrict__ rlb,
                      float* __restrict__ ws) {
  int l = blockIdx.y;
  int rd = blockIdx.x * blockDim.x + threadIdx.x;
  const float4* wrow = (const float4*)(rlw + ((size_t)(l * NR * DD + rd)) * DD);
  float4 wreg[16];
#pragma unroll
  for (int kk = 0; kk < 16; ++kk) wreg[kk] = wrow[kk];
  float bias = rlb[l * NR * DD + rd];
  int r = rd >> 6, d = rd & 63;
  for (int b = 0; b < NB; ++b) {
    const float4* q4 = (const float4*)(ws + OFF_QUERY + b * DD);
    float acc = 0.f;
#pragma unroll
    for (int kk = 0; kk < 16; ++kk) {
      float4 q = q4[kk];
      acc += q.x * wreg[kk].x + q.y * wreg[kk].y + q.z * wreg[kk].z + q.w * wreg[kk].w;
    }
    ws[OFF_RELI + (size_t)(l * NR + r) * (NB * DD) + b * DD + d] = acc + bias;
  }
}

// ---------------- CSR gather aggregation (interleaved): wave per node ----------------
// lane = b*16+q; tw/tb read directly (4-lane duplicate addresses coalesce to 256B).
__global__ __launch_bounds__(256) void k_agg(const float* __restrict__ xcur,
                                             const float* __restrict__ tw,
                                             const float* __restrict__ tb,
                                             float* __restrict__ ws, int w, int l,
                                             int init0) {
  int lane = threadIdx.x & 63;
  int wv = threadIdx.x >> 6;
  int n = blockIdx.x * 4 + wv;
  int b = lane >> 4;
  int q4i = lane & 15;
  const int* wsi = (const int*)ws;
  int p0 = __builtin_amdgcn_readfirstlane(wsi[IOFF_PTR + w * (NN + 1) + n]);
  int p1 = __builtin_amdgcn_readfirstlane(wsi[IOFF_PTR + w * (NN + 1) + n + 1]);
  const int4* recs = ((const int4*)(wsi + IOFF_REC)) + (size_t)w * NE;
  const float4* XI4 = (const float4*)xcur;
  const float4* RELI4 = (const float4*)(ws + OFF_RELI) + (size_t)l * NR * 64;
  const float4* TW4 = (const float4*)(tw + (size_t)l * NR * DD);  // [NR][16] f4
  const float4* TB4 = (const float4*)(tb + (size_t)l * NR * DD);
  int h00 = wsi[OFF_H0 + 0], h01 = wsi[OFF_H0 + 1];
  int h02 = wsi[OFF_H0 + 2], h03 = wsi[OFF_H0 + 3];
  int h0b = wsi[OFF_H0 + b];
  float4 q4b = ((const float4*)(ws + OFF_QUERY))[lane];
  float4 acc;
  if (n == h0b) acc = q4b;
  else { acc.x = 0.f; acc.y = 0.f; acc.z = 0.f; acc.w = 0.f; }

  if (init0) {
    for (int j = p0; j < p1; ++j) {
      int4 rec = recs[j];
      int src = rec.x;
      if (!((src == h00) | (src == h01) | (src == h02) | (src == h03))) continue;
      int et = rec.y;
      float dtf = __int_as_float(rec.z);
      float m = (src == h0b) ? __int_as_float(rec.w) : 0.f;
      float4 r4 = RELI4[et * 64 + lane];
      float4 w4 = TW4[et * 16 + q4i];
      float4 b4 = TB4[et * 16 + q4i];
      acc.x = fmaf(q4b.x * r4.x, __cosf(fmaf(dtf, w4.x, b4.x)) * m, acc.x);
      acc.y = fmaf(q4b.y * r4.y, __cosf(fmaf(dtf, w4.y, b4.y)) * m, acc.y);
      acc.z = fmaf(q4b.z * r4.z, __cosf(fmaf(dtf, w4.z, b4.z)) * m, acc.z);
      acc.w = fmaf(q4b.w * r4.w, __cosf(fmaf(dtf, w4.w, b4.w)) * m, acc.w);
    }
  } else {
#define EDGE_BODY(J)                                                           \
    {                                                                          \
      int4 rec = recs[J];                                                      \
      int src = rec.x, et = rec.y;                                             \
      float dtf = __int_as_float(rec.z), wgt = __int_as_float(rec.w);          \
      float4 x4 = XI4[(size_t)src * 64 + lane];                                \
      float4 r4 = RELI4[et * 64 + lane];                                       \
      float4 w4 = TW4[et * 16 + q4i];                                          \
      float4 b4 = TB4[et * 16 + q4i];                                          \
      acc.x = fmaf(x4.x * r4.x, __cosf(fmaf(dtf, w4.x, b4.x)) * wgt, acc.x);   \
      acc.y = fmaf(x4.y * r4.y, __cosf(fmaf(dtf, w4.y, b4.y)) * wgt, acc.y);   \
      acc.z = fmaf(x4.z * r4.z, __cosf(fmaf(dtf, w4.z, b4.z)) * wgt, acc.z);   \
      acc.w = fmaf(x4.w * r4.w, __cosf(fmaf(dtf, w4.w, b4.w)) * wgt, acc.w);   \
    }
    int j = p0;
    for (; j + 1 < p1; j += 2) {
      EDGE_BODY(j);
      EDGE_BODY(j + 1);
    }
    if (j < p1) EDGE_BODY(j);
#undef EDGE_BODY
  }
  ((float4*)(ws + OFF_AGG))[(size_t)n * 64 + lane] = acc;
}

// ---------------- node GEMM + LN + residual; wave = 16 rows x 64 cols ----------------
// rows (n,b) flat: row*64 floats contiguous; single base + immediate offsets.
__global__ __launch_bounds__(256) void k_gemm(const float* __restrict__ linb,
                                              const float* __restrict__ lns,
                                              const float* __restrict__ lnb,
                                              const float* __restrict__ xsrc,
                                              float* __restrict__ xdst,
                                              const float* __restrict__ ws, int l,
                                              int init0) {
  int wv = __builtin_amdgcn_readfirstlane(threadIdx.x >> 6);
  int c = threadIdx.x & 63;
  int row0 = blockIdx.x * 64 + wv * 16;
  const float* WT = ws + OFF_LINT + l * 2 * DD * DD;  // [128][64]
  const int* wsi = (const int*)ws;
  const float4* xr = (const float4*)xsrc + (size_t)row0 * 16;
  const float4* ar = (const float4*)(ws + OFF_AGG) + (size_t)row0 * 16;
  float bias = linb[l * DD + c];
  float acc[16];
#pragma unroll
  for (int r = 0; r < 16; ++r) acc[r] = bias;
  if (init0) {
#pragma unroll
    for (int r = 0; r < 16; ++r) {
      int nr = (row0 + r) >> 2, br = (row0 + r) & 3;
      if (nr == wsi[OFF_H0 + br]) {
        const float4* q4 = (const float4*)(ws + OFF_QUERY + br * DD);
        for (int kk = 0; kk < 16; ++kk) {
          float4 qv = q4[kk];
          acc[r] = fmaf(qv.x, WT[(4 * kk + 0) * DD + c], acc[r]);
          acc[r] = fmaf(qv.y, WT[(4 * kk + 1) * DD + c], acc[r]);
          acc[r] = fmaf(qv.z, WT[(4 * kk + 2) * DD + c], acc[r]);
          acc[r] = fmaf(qv.w, WT[(4 * kk + 3) * DD + c], acc[r]);
        }
      }
    }
  } else {
    for (int kk = 0; kk < 16; ++kk) {
      float w0 = WT[(4 * kk + 0) * DD + c];
      float w1 = WT[(4 * kk + 1) * DD + c];
      float w2 = WT[(4 * kk + 2) * DD + c];
      float w3 = WT[(4 * kk + 3) * DD + c];
#pragma unroll
      for (int r = 0; r < 16; ++r) {
        float4 xv = xr[r * 16 + kk];  // lane-uniform broadcast
        acc[r] = fmaf(xv.x, w0, acc[r]);
        acc[r] = fmaf(xv.y, w1, acc[r]);
        acc[r] = fmaf(xv.z, w2, acc[r]);
        acc[r] = fmaf(xv.w, w3, acc[r]);
      }
    }
  }
  for (int kk = 0; kk < 16; ++kk) {
    float w0 = WT[(64 + 4 * kk + 0) * DD + c];
    float w1 = WT[(64 + 4 * kk + 1) * DD + c];
    float w2 = WT[(64 + 4 * kk + 2) * DD + c];
    float w3 = WT[(64 + 4 * kk + 3) * DD + c];
#pragma unroll
    for (int r = 0; r < 16; ++r) {
      float4 av = ar[r * 16 + kk];  // broadcast
      acc[r] = fmaf(av.x, w0, acc[r]);
      acc[r] = fmaf(av.y, w1, acc[r]);
      acc[r] = fmaf(av.z, w2, acc[r]);
      acc[r] = fmaf(av.w, w3, acc[r]);
    }
  }
  float sc = lns[l * DD + c], bc = lnb[l * DD + c];
#pragma unroll
  for (int r = 0; r < 16; ++r) {
    float v = acc[r];
    float s = v;
    for (int m = 1; m < 64; m <<= 1) s += __shfl_xor(s, m);
    float mean = s * (1.f / 64.f);
    float cv = v - mean;
    float vv = cv * cv;
    for (int m = 1; m < 64; m <<= 1) vv += __shfl_xor(vv, m);
    vv *= (1.f / 64.f);
    float y = cv * __frsqrt_rn(vv + LN_EPS) * sc + bc;
    y = fmaxf(y, 0.f);
    float xo;
    if (init0) {
      int nr = (row0 + r) >> 2, br = (row0 + r) & 3;
      xo = (nr == wsi[OFF_H0 + br]) ? ws[OFF_QUERY + br * DD + c] : 0.f;
    } else {
      xo = xsrc[(size_t)(row0 + r) * DD + c];
    }
    xdst[(size_t)(row0 + r) * DD + c] = xo + y;
  }
}

// ---------------- gather tail features into tokens (+pe) ----------------
__global__ void k_gather(const float* __restrict__ pe, const float* __restrict__ xfin,
                         float* __restrict__ ws, int w) {
  int i = blockIdx.x * 256 + threadIdx.x;
  if (i >= NB * NNEG * DD) return;
  int bj = i / DD, d = i % DD;
  int b = bj / NNEG;
  int t = ((const int*)ws)[OFF_TSW + bj];
  ws[OFF_TOK + bj * NW * DD + w * DD + d] =
      xfin[(size_t)t * (NB * DD) + b * DD + d] + pe[w * DD + d];
}

// ---------------- transformer + final MLP: LDS weights, 4 rows/thread ----------------
__global__ __launch_bounds__(192) void k_xform(
    const float* __restrict__ wq, const float* __restrict__ wk,
    const float* __restrict__ wv, const float* __restrict__ wo,
    const float* __restrict__ ffw1, const float* __restrict__ ffb1,
    const float* __restrict__ ffw2, const float* __restrict__ ffb2,
    const float* __restrict__ fln1s, const float* __restrict__ fln1b,
    const float* __restrict__ fln2s, const float* __restrict__ fln2b,
    const float* __restrict__ m1w, const float* __restrict__ m1b,
    const float* __restrict__ m2w, const float* __restrict__ m2b,
    float* __restrict__ ws, float* __restrict__ out) {
  __shared__ float tok[RPB][NW][DD], kvb[RPB][NW][DD], vvb[RPB][NW][DD];
  __shared__ float hbuf[RPB][NW][NFFN];
  __shared__ float feat[RPB][2 * DD];
  __shared__ float red[RPB][2];
  __shared__ float4 wbuf4[4352];  // 68 KB padded staging buffer
  int tid = threadIdx.x;          // 0..191
  int tk = tid >> 6, d = tid & 63;
  int row0 = blockIdx.x * RPB;
#pragma unroll
  for (int rr = 0; rr < RPB; ++rr)
    tok[rr][tk][d] = ws[OFF_TOK + (row0 + rr) * NW * DD + tk * DD + d];
  float t1[RPB];
  for (int f = 0; f < NFL; ++f) {
    // ---- stage wq,wk,wv,wo as 4x [64][68] ----
    {
      const float4* s0 = (const float4*)(wq + (size_t)f * DD * DD);
      const float4* s1 = (const float4*)(wk + (size_t)f * DD * DD);
      const float4* s2 = (const float4*)(wv + (size_t)f * DD * DD);
      const float4* s3 = (const float4*)(wo + (size_t)f * DD * DD);
      for (int idx = tid; idx < 4096; idx += 192) {
        int m = idx >> 10, rem = idx & 1023;
        int rrow = rem >> 4, c4 = rem & 15;
        const float4* s = (m == 0) ? s0 : (m == 1) ? s1 : (m == 2) ? s2 : s3;
        wbuf4[(m * 64 + rrow) * 17 + c4] = s[rem];
      }
    }
    __syncthreads();
    // ---- QKV: weights read once, applied to 4 rows ----
    float qd[RPB], kd[RPB], vd[RPB];
#pragma unroll
    for (int rr = 0; rr < RPB; ++rr) { qd[rr] = 0.f; kd[rr] = 0.f; vd[rr] = 0.f; }
#pragma unroll
    for (int kk = 0; kk < 16; ++kk) {
      float4 aq = wbuf4[(0 * 64 + d) * 17 + kk];
      float4 ak = wbuf4[(1 * 64 + d) * 17 + kk];
      float4 av = wbuf4[(2 * 64 + d) * 17 + kk];
#pragma unroll
      for (int rr = 0; rr < RPB; ++rr) {
        float4 tv = *(const float4*)&tok[rr][tk][4 * kk];
        qd[rr] += tv.x * aq.x + tv.y * aq.y + tv.z * aq.z + tv.w * aq.w;
        kd[rr] += tv.x * ak.x + tv.y * ak.y + tv.z * ak.z + tv.w * ak.w;
        vd[rr] += tv.x * av.x + tv.y * av.y + tv.z * av.z + tv.w * av.w;
      }
    }
#pragma unroll
    for (int rr = 0; rr < RPB; ++rr) {
      kvb[rr][tk][d] = kd[rr];
      vvb[rr][tk][d] = vd[rr];
    }
    __syncthreads();
    // ---- attention (head = d>>4) ----
    float od[RPB];
#pragma unroll
    for (int rr = 0; rr < RPB; ++rr) {
      float sc[NW];
#pragma unroll
      for (int j = 0; j < NW; ++j) {
        float p = qd[rr] * kvb[rr][j][d];
        p += __shfl_xor(p, 1);
        p += __shfl_xor(p, 2);
        p += __shfl_xor(p, 4);
        p += __shfl_xor(p, 8);
        sc[j] = p * 0.25f;  // 1/sqrt(16)
      }
      float mx = fmaxf(sc[0], fmaxf(sc[1], sc[2]));
      float e0 = expf(sc[0] - mx), e1 = expf(sc[1] - mx), e2 = expf(sc[2] - mx);
      float inv = 1.f / (e0 + e1 + e2);
      od[rr] = (e0 * vvb[rr][0][d] + e1 * vvb[rr][1][d] + e2 * vvb[rr][2][d]) * inv;
    }
    __syncthreads();
#pragma unroll
    for (int rr = 0; rr < RPB; ++rr) kvb[rr][tk][d] = od[rr];  // o-buffer (wave rows)
    // ---- o @ wo.T ----
    float ao[RPB];
#pragma unroll
    for (int rr = 0; rr < RPB; ++rr) ao[rr] = 0.f;
#pragma unroll
    for (int kk = 0; kk < 16; ++kk) {
      float4 w4 = wbuf4[(3 * 64 + d) * 17 + kk];
#pragma unroll
      for (int rr = 0; rr < RPB; ++rr) {
        float4 ov = *(const float4*)&kvb[rr][tk][4 * kk];
        ao[rr] += ov.x * w4.x + ov.y * w4.y + ov.z * w4.z + ov.w * w4.w;
      }
    }
    float g1 = fln1s[f * DD + d], b1 = fln1b[f * DD + d];
#pragma unroll
    for (int rr = 0; rr < RPB; ++rr) {
      float t = tok[rr][tk][d] + ao[rr];
      float s = t;
      for (int m = 1; m < 64; m <<= 1) s += __shfl_xor(s, m);
      float mean = s * (1.f / 64.f);
      float cv = t - mean;
      float v = cv * cv;
      for (int m = 1; m < 64; m <<= 1) v += __shfl_xor(v, m);
      v *= (1.f / 64.f);
      t1[rr] = cv * __frsqrt_rn(v + LN_EPS) * g1 + b1;
      tok[rr][tk][d] = t1[rr];
    }
    __syncthreads();
    // ---- stage ffw1 [256][68] ----
    {
      const float4* s4 = (const float4*)(ffw1 + (size_t)f * NFFN * DD);
      for (int idx = tid; idx < 4096; idx += 192) {
        int rrow = idx >> 4, c4 = idx & 15;
        wbuf4[rrow * 17 + c4] = s4[idx];
      }
    }
    __syncthreads();
    // ---- FFN1: 4 hidden units x 4 rows per thread ----
    float h[4][RPB];
#pragma unroll
    for (int uu = 0; uu < 4; ++uu) {
      float bb = ffb1[f * NFFN + d + 64 * uu];
#pragma unroll
      for (int rr = 0; rr < RPB; ++rr) h[uu][rr] = bb;
    }
#pragma unroll
    for (int kk = 0; kk < 16; ++kk) {
      float4 w0 = wbuf4[(d + 0) * 17 + kk];
      float4 w1 = wbuf4[(d + 64) * 17 + kk];
      float4 w2 = wbuf4[(d + 128) * 17 + kk];
      float4 w3 = wbuf4[(d + 192) * 17 + kk];
#pragma unroll
      for (int rr = 0; rr < RPB; ++rr) {
        float4 tv = *(const float4*)&tok[rr][tk][4 * kk];
        h[0][rr] += tv.x * w0.x + tv.y * w0.y + tv.z * w0.z + tv.w * w0.w;
        h[1][rr] += tv.x * w1.x + tv.y * w1.y + tv.z * w1.z + tv.w * w1.w;
        h[2][rr] += tv.x * w2.x + tv.y * w2.y + tv.z * w2.z + tv.w * w2.w;
        h[3][rr] += tv.x * w3.x + tv.y * w3.y + tv.z * w3.z + tv.w * w3.w;
      }
    }
#pragma unroll
    for (int uu = 0; uu < 4; ++uu)
#pragma unroll
      for (int rr = 0; rr < RPB; ++rr)
        hbuf[rr][tk][d + 64 * uu] = fmaxf(h[uu][rr], 0.f);
    __syncthreads();
    // ---- stage ffw2 [64][260] ----
    {
      const float4* s4 = (const float4*)(ffw2 + (size_t)f * DD * NFFN);
      for (int idx = tid; idx < 4096; idx += 192) {
        int rrow = idx >> 6, c4 = idx & 63;
        wbuf4[rrow * 65 + c4] = s4[idx];
      }
    }
    __syncthreads();
    // ---- FFN2 ----
    float ff[RPB];
    float fb2 = ffb2[f * DD + d];
#pragma unroll
    for (int rr = 0; rr < RPB; ++rr) ff[rr] = fb2;
#pragma unroll 8
    for (int kk = 0; kk < 64; ++kk) {
      float4 w4 = wbuf4[d * 65 + kk];
#pragma unroll
      for (int rr = 0; rr < RPB; ++rr) {
        float4 hv = *(const float4*)&hbuf[rr][tk][4 * kk];
        ff[rr] += hv.x * w4.x + hv.y * w4.y + hv.z * w4.z + hv.w * w4.w;
      }
    }
    float g2 = fln2s[f * DD + d], b2 = fln2b[f * DD + d];
#pragma unroll
    for (int rr = 0; rr < RPB; ++rr) {
      float t = t1[rr] + ff[rr];
      float s = t;
      for (int m = 1; m < 64; m <<= 1) s += __shfl_xor(s, m);
      float mean = s * (1.f / 64.f);
      float cv = t - mean;
      float v = cv * cv;
      for (int m = 1; m < 64; m <<= 1) v += __shfl_xor(v, m);
      v *= (1.f / 64.f);
      tok[rr][tk][d] = cv * __frsqrt_rn(v + LN_EPS) * g2 + b2;
    }
    __syncthreads();
  }
  // ---- final MLP ----
  if (tk == 2) {
#pragma unroll
    for (int rr = 0; rr < RPB; ++rr) {
      int b = (row0 + rr) / NNEG;
      feat[rr][d] = tok[rr][2][d];
      feat[rr][DD + d] = ws[OFF_QUERY + b * DD + d];
    }
  }
  {
    const float4* s4 = (const float4*)m1w;
    for (int idx = tid; idx < 4096; idx += 192) {
      int rrow = idx >> 5, c4 = idx & 31;
      wbuf4[rrow * 33 + c4] = s4[idx];
    }
  }
  __syncthreads();
  float partial[RPB];
#pragma unroll
  for (int rr = 0; rr < RPB; ++rr) partial[rr] = 0.f;
  if (tid < 2 * DD) {
    int hh = tid;
    float mb = m1b[hh], mw = m2w[hh];
#pragma unroll
    for (int rr = 0; rr < RPB; ++rr) {
      float acc = mb;
#pragma unroll
      for (int kk = 0; kk < 32; ++kk) {
        float4 fv = *(const float4*)&feat[rr][4 * kk];
        float4 w4 = wbuf4[hh * 33 + kk];
        acc += fv.x * w4.x + fv.y * w4.y + fv.z * w4.z + fv.w * w4.w;
      }
      partial[rr] = fmaxf(acc, 0.f) * mw;
    }
  }
#pragma unroll
  for (int rr = 0; rr < RPB; ++rr) {
    float p = partial[rr];
    for (int m = 1; m < 64; m <<= 1) p += __shfl_xor(p, m);
    if (d == 0 && tk < 2) red[rr][tk] = p;
  }
  __syncthreads();
  if (tid < RPB) out[row0 + tid] = red[tid][0] + red[tid][1] + m2b[0];
}

extern "C" void kernel_launch(void* const* d_in, const int* in_sizes, int n_in,
                              void* d_out, int out_size, void* d_ws, size_t ws_size,
                              hipStream_t stream) {
  const int* qt = (const int*)d_in[0];
  const int* eidx = (const int*)d_in[1];
  const int* etype = (const int*)d_in[2];
  const int* etime = (const int*)d_in[3];
  const float* qemb = (const float*)d_in[4];
  const float* ew = (const float*)d_in[5];
  const float* rlw = (const float*)d_in[6];
  const float* rlb = (const float*)d_in[7];
  const float* tw = (const float*)d_in[8];
  const float* tb = (const float*)d_in[9];
  const float* linw = (const float*)d_in[10];
  const float* linb = (const float*)d_in[11];
  const float* lns = (const float*)d_in[12];
  const float* lnb = (const float*)d_in[13];
  const float* pe = (const float*)d_in[14];
  const float* wq = (const float*)d_in[15];
  const float* wk = (const float*)d_in[16];
  const float* wv = (const float*)d_in[17];
  const float* wo = (const float*)d_in[18];
  const float* ffw1 = (const float*)d_in[19];
  const float* ffb1 = (const float*)d_in[20];
  const float* ffw2 = (const float*)d_in[21];
  const float* ffb2 = (const float*)d_in[22];
  const float* fln1s = (const float*)d_in[23];
  const float* fln1b = (const float*)d_in[24];
  const float* fln2s = (const float*)d_in[25];
  const float* fln2b = (const float*)d_in[26];
  const float* m1w = (const float*)d_in[27];
  const float* m1b = (const float*)d_in[28];
  const float* m2w = (const float*)d_in[29];
  const float* m2b = (const float*)d_in[30];
  float* ws = (float*)d_ws;
  float* out = (float*)d_out;

  k_prep<<<1, 256, 0, stream>>>(qt, qemb, ws);
  k_mint<<<(NE + 255) / 256, 256, 0, stream>>>(etime, ws);
  k_zero_ptr<<<(NW * (NN + 1) + 255) / 256, 256, 0, stream>>>(ws);
  k_transpose<<<(NL * 2 * DD * DD + 255) / 256, 256, 0, stream>>>(linw, ws);
  k_rel<<<dim3(NR * DD / 256, NL), 256, 0, stream>>>(rlw, rlb, ws);
  k_hist<<<dim3((NE + 255) / 256, NW), 256, 0, stream>>>(eidx, ws);
  k_scan<<<NW, 256, 0, stream>>>(ws);
  k_curinit<<<(NW * NN + 255) / 256, 256, 0, stream>>>(ws);
  k_scatter<<<dim3((NE + 255) / 256, NW), 256, 0, stream>>>(eidx, etype, etime, ew, ws);

  float* X = ws + OFF_X;
  float* X2 = ws + OFF_X2;
  for (int w = 0; w < NW; ++w) {
    float* cur = X;
    float* nxt = X2;
    for (int l = 0; l < NL; ++l) {
      int init0 = (l == 0) ? 1 : 0;
      k_agg<<<NN / 4, 256, 0, stream>>>(cur, tw, tb, ws, w, l, init0);
      k_gemm<<<NB * NN / 64, 256, 0, stream>>>(linb, lns, lnb, cur, nxt, ws, l, init0);
      float* t = cur; cur = nxt; nxt = t;
    }
    k_gather<<<(NB * NNEG * DD + 255) / 256, 256, 0, stream>>>(pe, cur, ws, w);
  }
  k_xform<<<NB * NNEG / RPB, 192, 0, stream>>>(wq, wk, wv, wo, ffw1, ffb1, ffw2, ffb2,
                                                fln1s, fln1b, fln2s, fln2b, m1w, m1b, m2w,
                                                m2b, ws, out);
}

// Round 9
// 489.773 us; speedup vs baseline: 2.5198x; 1.3231x over previous
//
#include <hip/hip_runtime.h>
#include <hip/hip_bf16.h>
#include <cmath>

#define NB 4
#define NNEG 33
#define NN 10000
#define NE 100000
#define NW 3
#define DD 64
#define NL 3
#define NR 200
#define NFL 2
#define NFFN 256
#define LN_EPS 1e-5f
#define RPB 4   // rows per k_xform block (132 = 33*4)
#define XSZ (NB*NN*DD)

// ---- ws layout (float offsets) ----
// Interleaved state layout: XI[n][b][d] (node-major), one copy per window w.
#define OFF_QUERY 0                                   // NB*DD
#define OFF_H0    256                                 // NB ints
#define OFF_TSW   288                                 // NB*NNEG ints
#define OFF_MINT  448                                 // 1 int
#define OFF_RELI  512                                 // NL*NR*NB*DD  relI[l][et][b][d]
#define OFF_LINT  (OFF_RELI + NL*NR*NB*DD)            // NL*2*DD*DD  linT[l][k][c]
#define OFF_X     (OFF_LINT + NL*2*DD*DD)             // NW*XSZ
#define OFF_X2    (OFF_X + NW*XSZ)                    // NW*XSZ
#define OFF_AGG   (OFF_X2 + NW*XSZ)                   // NW*XSZ
#define OFF_TOK   (OFF_AGG + NW*XSZ)                  // NB*NNEG*NW*DD
// int offsets (4B units)
#define IOFF_PTR  (OFF_TOK + NB*NNEG*NW*DD)           // NW*(NN+1) ints
#define IOFF_CUR  (IOFF_PTR + NW*(NN+1))              // NW*NN ints
#define IOFF_REC  ((IOFF_CUR + NW*NN + 3) & ~3)       // NW*NE*4 ints, 16B aligned

// ---------------- prep ----------------
__global__ void k_prep(const int* __restrict__ qt, const float* __restrict__ qemb,
                       float* __restrict__ ws) {
  int tid = threadIdx.x;
  if (tid < NB * DD) {
    int b = tid / DD, d = tid % DD;
    int h0 = qt[(b * NNEG + 0) * 3 + 0];
    bool itn = true;
    for (int j = 1; j < NNEG; ++j) itn = itn && (qt[(b * NNEG + j) * 3 + 0] == h0);
    int r0 = qt[(b * NNEG + 0) * 3 + 1] + (itn ? 0 : NR / 2);
    ws[OFF_QUERY + b * DD + d] = qemb[r0 * DD + d];
    if (d == 0) {
      int t0 = qt[(b * NNEG + 0) * 3 + 2];
      ((int*)ws)[OFF_H0 + b] = itn ? h0 : t0;
    }
  }
  if (tid < NB * NNEG) {
    int b = tid / NNEG, j = tid % NNEG;
    int h0 = qt[(b * NNEG + 0) * 3 + 0];
    bool itn = true;
    for (int jj = 1; jj < NNEG; ++jj) itn = itn && (qt[(b * NNEG + jj) * 3 + 0] == h0);
    int h = qt[(b * NNEG + j) * 3 + 0], t = qt[(b * NNEG + j) * 3 + 2];
    ((int*)ws)[OFF_TSW + tid] = itn ? t : h;
  }
  if (tid == 0) ((int*)ws)[OFF_MINT] = 0x7fffffff;
}

// ---------------- min over edge_time[0] ----------------
__global__ void k_mint(const int* __restrict__ etime, float* __restrict__ ws) {
  int i = blockIdx.x * blockDim.x + threadIdx.x;
  int v = (i < NE) ? etime[i] : 0x7fffffff;
  for (int m = 1; m < 64; m <<= 1) v = min(v, __shfl_xor(v, m));
  if ((threadIdx.x & 63) == 0) atomicMin(&((int*)ws)[OFF_MINT], v);
}

// ---------------- zero ptr array ----------------
__global__ void k_zero_ptr(float* __restrict__ ws) {
  int i = blockIdx.x * 256 + threadIdx.x;
  if (i < NW * (NN + 1)) ((int*)ws)[IOFF_PTR + i] = 0;
}

// ---------------- transpose lin_w: linT[l][k][c] = lin_w[l][c][k] ----------------
__global__ void k_transpose(const float* __restrict__ lin_w, float* __restrict__ ws) {
  int idx = blockIdx.x * blockDim.x + threadIdx.x;
  if (idx < NL * 2 * DD * DD) {
    int l = idx / (2 * DD * DD), r = idx % (2 * DD * DD), k = r / DD, c = r % DD;
    ws[OFF_LINT + idx] = lin_w[(l * DD + c) * 2 * DD + k];
  }
}

// ---------------- histogram of dst ----------------
__global__ void k_hist(const int* __restrict__ eidx, float* __restrict__ ws) {
  int e = blockIdx.x * 256 + threadIdx.x, w = blockIdx.y;
  if (e >= NE) return;
  int dst = eidx[(w * 2 + 1) * NE + e];
  atomicAdd(&((int*)ws)[IOFF_PTR + w * (NN + 1) + dst + 1], 1);
}

// ---------------- inclusive scan -> ptr (one block per w) ----------------
__global__ void k_scan(float* __restrict__ ws) {
  int w = blockIdx.x;
  int* p = (int*)ws + IOFF_PTR + w * (NN + 1);
  __shared__ int wsum[4];
  __shared__ int runv;
  if (threadIdx.x == 0) runv = 0;
  __syncthreads();
  int lane = threadIdx.x & 63, wv = threadIdx.x >> 6;
  for (int base = 0; base < NN + 1; base += 256) {
    int i = base + threadIdx.x;
    int v = (i <= NN) ? p[i] : 0;
    for (int off = 1; off < 64; off <<= 1) {
      int t = __shfl_up(v, off);
      if (lane >= off) v += t;
    }
    if (lane == 63) wsum[wv] = v;
    __syncthreads();
    int add = runv;
    for (int u = 0; u < wv; ++u) add += wsum[u];
    v += add;
    if (i <= NN) p[i] = v;
    __syncthreads();
    if (threadIdx.x == 255) runv = v;
    __syncthreads();
  }
}

// ---------------- cursor init ----------------
__global__ void k_curinit(float* __restrict__ ws) {
  int i = blockIdx.x * 256 + threadIdx.x;
  if (i >= NW * NN) return;
  int w = i / NN, n = i % NN;
  ((int*)ws)[IOFF_CUR + i] = ((int*)ws)[IOFF_PTR + w * (NN + 1) + n];
}

// ---------------- scatter edges into CSR records {src, et, dt, weight} ----------------
__global__ void k_scatter(const int* __restrict__ eidx, const int* __restrict__ etype,
                          const int* __restrict__ etime, const float* __restrict__ eweight,
                          float* __restrict__ ws) {
  int e = blockIdx.x * 256 + threadIdx.x, w = blockIdx.y;
  if (e >= NE) return;
  int* wsi = (int*)ws;
  int dst = eidx[(w * 2 + 1) * NE + e];
  int pos = atomicAdd(&wsi[IOFF_CUR + w * NN + dst], 1);
  float dt = (float)etime[w * NE + e] - (float)wsi[OFF_MINT];
  int4 rec;
  rec.x = eidx[(w * 2 + 0) * NE + e];
  rec.y = etype[w * NE + e];
  rec.z = __float_as_int(dt);
  rec.w = __float_as_int(eweight[w * NE + e]);
  ((int4*)(wsi + IOFF_REC))[(size_t)w * NE + pos] = rec;
}

// ---------------- rel = query @ rel_lin_w.T + b (written interleaved) ----------------
__global__ void k_rel(const float* __restrict__ rlw, const float* __restrict__ rlb,
                      float* __restrict__ ws) {
  int l = blockIdx.y;
  int rd = blockIdx.x * blockDim.x + threadIdx.x;
  const float4* wrow = (const float4*)(rlw + ((size_t)(l * NR * DD + rd)) * DD);
  float4 wreg[16];
#pragma unroll
  for (int kk = 0; kk < 16; ++kk) wreg[kk] = wrow[kk];
  float bias = rlb[l * NR * DD + rd];
  int r = rd >> 6, d = rd & 63;
  for (int b = 0; b < NB; ++b) {
    const float4* q4 = (const float4*)(ws + OFF_QUERY + b * DD);
    float acc = 0.f;
#pragma unroll
    for (int kk = 0; kk < 16; ++kk) {
      float4 q = q4[kk];
      acc += q.x * wreg[kk].x + q.y * wreg[kk].y + q.z * wreg[kk].z + q.w * wreg[kk].w;
    }
    ws[OFF_RELI + (size_t)(l * NR + r) * (NB * DD) + b * DD + d] = acc + bias;
  }
}

// ---------------- CSR gather aggregation: grid.y = w (windows run concurrently) -------
__global__ __launch_bounds__(256) void k_agg(const float* __restrict__ xbase,
                                             const float* __restrict__ tw,
                                             const float* __restrict__ tb,
                                             float* __restrict__ ws, int l, int init0) {
  int w = blockIdx.y;
  int lane = threadIdx.x & 63;
  int wv = threadIdx.x >> 6;
  int n = blockIdx.x * 4 + wv;
  int b = lane >> 4;
  int q4i = lane & 15;
  const int* wsi = (const int*)ws;
  int p0 = __builtin_amdgcn_readfirstlane(wsi[IOFF_PTR + w * (NN + 1) + n]);
  int p1 = __builtin_amdgcn_readfirstlane(wsi[IOFF_PTR + w * (NN + 1) + n + 1]);
  const int4* recs = ((const int4*)(wsi + IOFF_REC)) + (size_t)w * NE;
  const float4* XI4 = (const float4*)(xbase + (size_t)w * XSZ);
  const float4* RELI4 = (const float4*)(ws + OFF_RELI) + (size_t)l * NR * 64;
  const float4* TW4 = (const float4*)(tw + (size_t)l * NR * DD);  // [NR][16] f4
  const float4* TB4 = (const float4*)(tb + (size_t)l * NR * DD);
  int h00 = wsi[OFF_H0 + 0], h01 = wsi[OFF_H0 + 1];
  int h02 = wsi[OFF_H0 + 2], h03 = wsi[OFF_H0 + 3];
  int h0b = wsi[OFF_H0 + b];
  float4 q4b = ((const float4*)(ws + OFF_QUERY))[lane];
  float4 acc;
  if (n == h0b) acc = q4b;
  else { acc.x = 0.f; acc.y = 0.f; acc.z = 0.f; acc.w = 0.f; }

  if (init0) {
    for (int j = p0; j < p1; ++j) {
      int4 rec = recs[j];
      int src = rec.x;
      if (!((src == h00) | (src == h01) | (src == h02) | (src == h03))) continue;
      int et = rec.y;
      float dtf = __int_as_float(rec.z);
      float m = (src == h0b) ? __int_as_float(rec.w) : 0.f;
      float4 r4 = RELI4[et * 64 + lane];
      float4 w4 = TW4[et * 16 + q4i];
      float4 b4 = TB4[et * 16 + q4i];
      acc.x = fmaf(q4b.x * r4.x, __cosf(fmaf(dtf, w4.x, b4.x)) * m, acc.x);
      acc.y = fmaf(q4b.y * r4.y, __cosf(fmaf(dtf, w4.y, b4.y)) * m, acc.y);
      acc.z = fmaf(q4b.z * r4.z, __cosf(fmaf(dtf, w4.z, b4.z)) * m, acc.z);
      acc.w = fmaf(q4b.w * r4.w, __cosf(fmaf(dtf, w4.w, b4.w)) * m, acc.w);
    }
  } else {
#define EDGE_BODY(J)                                                           \
    {                                                                          \
      int4 rec = recs[J];                                                      \
      int src = rec.x, et = rec.y;                                             \
      float dtf = __int_as_float(rec.z), wgt = __int_as_float(rec.w);          \
      float4 x4 = XI4[(size_t)src * 64 + lane];                                \
      float4 r4 = RELI4[et * 64 + lane];                                       \
      float4 w4 = TW4[et * 16 + q4i];                                          \
      float4 b4 = TB4[et * 16 + q4i];                                          \
      acc.x = fmaf(x4.x * r4.x, __cosf(fmaf(dtf, w4.x, b4.x)) * wgt, acc.x);   \
      acc.y = fmaf(x4.y * r4.y, __cosf(fmaf(dtf, w4.y, b4.y)) * wgt, acc.y);   \
      acc.z = fmaf(x4.z * r4.z, __cosf(fmaf(dtf, w4.z, b4.z)) * wgt, acc.z);   \
      acc.w = fmaf(x4.w * r4.w, __cosf(fmaf(dtf, w4.w, b4.w)) * wgt, acc.w);   \
    }
    int j = p0;
    for (; j + 1 < p1; j += 2) {
      EDGE_BODY(j);
      EDGE_BODY(j + 1);
    }
    if (j < p1) EDGE_BODY(j);
#undef EDGE_BODY
  }
  ((float4*)(ws + OFF_AGG + (size_t)w * XSZ))[(size_t)n * 64 + lane] = acc;
}

// ---------------- node GEMM + LN + residual; wave = 16 rows x 64 cols; grid.y = w ------
__global__ __launch_bounds__(256) void k_gemm(const float* __restrict__ linb,
                                              const float* __restrict__ lns,
                                              const float* __restrict__ lnb,
                                              const float* __restrict__ xbase,
                                              float* __restrict__ xdstbase,
                                              const float* __restrict__ ws, int l,
                                              int init0) {
  int w = blockIdx.y;
  const float* xsrc = xbase + (size_t)w * XSZ;
  float* xdst = xdstbase + (size_t)w * XSZ;
  int wv = __builtin_amdgcn_readfirstlane(threadIdx.x >> 6);
  int c = threadIdx.x & 63;
  int row0 = blockIdx.x * 64 + wv * 16;
  const float* WT = ws + OFF_LINT + l * 2 * DD * DD;  // [128][64]
  const int* wsi = (const int*)ws;
  const float4* xr = (const float4*)xsrc + (size_t)row0 * 16;
  const float4* ar = (const float4*)(ws + OFF_AGG + (size_t)w * XSZ) + (size_t)row0 * 16;
  float bias = linb[l * DD + c];
  float acc[16];
#pragma unroll
  for (int r = 0; r < 16; ++r) acc[r] = bias;
  if (init0) {
#pragma unroll
    for (int r = 0; r < 16; ++r) {
      int nr = (row0 + r) >> 2, br = (row0 + r) & 3;
      if (nr == wsi[OFF_H0 + br]) {
        const float4* q4 = (const float4*)(ws + OFF_QUERY + br * DD);
        for (int kk = 0; kk < 16; ++kk) {
          float4 qv = q4[kk];
          acc[r] = fmaf(qv.x, WT[(4 * kk + 0) * DD + c], acc[r]);
          acc[r] = fmaf(qv.y, WT[(4 * kk + 1) * DD + c], acc[r]);
          acc[r] = fmaf(qv.z, WT[(4 * kk + 2) * DD + c], acc[r]);
          acc[r] = fmaf(qv.w, WT[(4 * kk + 3) * DD + c], acc[r]);
        }
      }
    }
  } else {
    for (int kk = 0; kk < 16; ++kk) {
      float w0 = WT[(4 * kk + 0) * DD + c];
      float w1 = WT[(4 * kk + 1) * DD + c];
      float w2 = WT[(4 * kk + 2) * DD + c];
      float w3 = WT[(4 * kk + 3) * DD + c];
#pragma unroll
      for (int r = 0; r < 16; ++r) {
        float4 xv = xr[r * 16 + kk];  // lane-uniform broadcast
        acc[r] = fmaf(xv.x, w0, acc[r]);
        acc[r] = fmaf(xv.y, w1, acc[r]);
        acc[r] = fmaf(xv.z, w2, acc[r]);
        acc[r] = fmaf(xv.w, w3, acc[r]);
      }
    }
  }
  for (int kk = 0; kk < 16; ++kk) {
    float w0 = WT[(64 + 4 * kk + 0) * DD + c];
    float w1 = WT[(64 + 4 * kk + 1) * DD + c];
    float w2 = WT[(64 + 4 * kk + 2) * DD + c];
    float w3 = WT[(64 + 4 * kk + 3) * DD + c];
#pragma unroll
    for (int r = 0; r < 16; ++r) {
      float4 av = ar[r * 16 + kk];  // broadcast
      acc[r] = fmaf(av.x, w0, acc[r]);
      acc[r] = fmaf(av.y, w1, acc[r]);
      acc[r] = fmaf(av.z, w2, acc[r]);
      acc[r] = fmaf(av.w, w3, acc[r]);
    }
  }
  float sc = lns[l * DD + c], bc = lnb[l * DD + c];
#pragma unroll
  for (int r = 0; r < 16; ++r) {
    float v = acc[r];
    float s = v;
    for (int m = 1; m < 64; m <<= 1) s += __shfl_xor(s, m);
    float mean = s * (1.f / 64.f);
    float cv = v - mean;
    float vv = cv * cv;
    for (int m = 1; m < 64; m <<= 1) vv += __shfl_xor(vv, m);
    vv *= (1.f / 64.f);
    float y = cv * __frsqrt_rn(vv + LN_EPS) * sc + bc;
    y = fmaxf(y, 0.f);
    float xo;
    if (init0) {
      int nr = (row0 + r) >> 2, br = (row0 + r) & 3;
      xo = (nr == wsi[OFF_H0 + br]) ? ws[OFF_QUERY + br * DD + c] : 0.f;
    } else {
      xo = xsrc[(size_t)(row0 + r) * DD + c];
    }
    xdst[(size_t)(row0 + r) * DD + c] = xo + y;
  }
}

// ---------------- gather tail features into tokens (+pe), all w at once ----------------
__global__ void k_gather(const float* __restrict__ pe, const float* __restrict__ xfinbase,
                         float* __restrict__ ws) {
  int w = blockIdx.y;
  int i = blockIdx.x * 256 + threadIdx.x;
  if (i >= NB * NNEG * DD) return;
  int bj = i / DD, d = i % DD;
  int b = bj / NNEG;
  int t = ((const int*)ws)[OFF_TSW + bj];
  ws[OFF_TOK + bj * NW * DD + w * DD + d] =
      xfinbase[(size_t)w * XSZ + (size_t)t * (NB * DD) + b * DD + d] + pe[w * DD + d];
}

// ---------------- transformer + final MLP: round-4 structure (best measured) ----------
__global__ __launch_bounds__(768) void k_xform(
    const float* __restrict__ wq, const float* __restrict__ wk,
    const float* __restrict__ wv, const float* __restrict__ wo,
    const float* __restrict__ ffw1, const float* __restrict__ ffb1,
    const float* __restrict__ ffw2, const float* __restrict__ ffb2,
    const float* __restrict__ fln1s, const float* __restrict__ fln1b,
    const float* __restrict__ fln2s, const float* __restrict__ fln2b,
    const float* __restrict__ m1w, const float* __restrict__ m1b,
    const float* __restrict__ m2w, const float* __restrict__ m2b,
    float* __restrict__ ws, float* __restrict__ out) {
  __shared__ float tok[RPB][NW][DD], kvb[RPB][NW][DD], vvb[RPB][NW][DD];
  __shared__ float hbuf[RPB][NW][NFFN];
  __shared__ float feat[RPB][2 * DD];
  __shared__ float red[RPB][2];
  __shared__ float4 wbuf4[4352];  // 68 KB padded staging buffer
  int tid = threadIdx.x;
  int rr = tid / 192;
  int t192 = tid - rr * 192;
  int tk = t192 >> 6, d = t192 & 63;
  int row = blockIdx.x * RPB + rr, b = row / NNEG;
  tok[rr][tk][d] = ws[OFF_TOK + row * NW * DD + tk * DD + d];
  for (int f = 0; f < NFL; ++f) {
    // ---- stage wq,wk,wv,wo as 4x [64][68] ----
    {
      const float4* s0 = (const float4*)(wq + (size_t)f * DD * DD);
      const float4* s1 = (const float4*)(wk + (size_t)f * DD * DD);
      const float4* s2 = (const float4*)(wv + (size_t)f * DD * DD);
      const float4* s3 = (const float4*)(wo + (size_t)f * DD * DD);
      for (int idx = tid; idx < 4096; idx += 768) {
        int m = idx >> 10, rem = idx & 1023;
        int rrow = rem >> 4, c4 = rem & 15;
        const float4* s = (m == 0) ? s0 : (m == 1) ? s1 : (m == 2) ? s2 : s3;
        wbuf4[(m * 64 + rrow) * 17 + c4] = s[rem];
      }
    }
    __syncthreads();
    // ---- QKV from LDS ----
    float qd = 0.f, kd = 0.f, vd = 0.f;
#pragma unroll
    for (int kk = 0; kk < 16; ++kk) {
      float4 tv = *(const float4*)&tok[rr][tk][4 * kk];
      float4 aq = wbuf4[(0 * 64 + d) * 17 + kk];
      float4 ak = wbuf4[(1 * 64 + d) * 17 + kk];
      float4 av = wbuf4[(2 * 64 + d) * 17 + kk];
      qd += tv.x * aq.x + tv.y * aq.y + tv.z * aq.z + tv.w * aq.w;
      kd += tv.x * ak.x + tv.y * ak.y + tv.z * ak.z + tv.w * ak.w;
      vd += tv.x * av.x + tv.y * av.y + tv.z * av.z + tv.w * av.w;
    }
    kvb[rr][tk][d] = kd;
    vvb[rr][tk][d] = vd;
    __syncthreads();
    // ---- attention (head = d>>4) ----
    float sc[NW];
#pragma unroll
    for (int j = 0; j < NW; ++j) {
      float p = qd * kvb[rr][j][d];
      p += __shfl_xor(p, 1);
      p += __shfl_xor(p, 2);
      p += __shfl_xor(p, 4);
      p += __shfl_xor(p, 8);
      sc[j] = p * 0.25f;  // 1/sqrt(16)
    }
    float mx = fmaxf(sc[0], fmaxf(sc[1], sc[2]));
    float e0 = expf(sc[0] - mx), e1 = expf(sc[1] - mx), e2 = expf(sc[2] - mx);
    float inv = 1.f / (e0 + e1 + e2);
    float od = (e0 * vvb[rr][0][d] + e1 * vvb[rr][1][d] + e2 * vvb[rr][2][d]) * inv;
    __syncthreads();
    kvb[rr][tk][d] = od;  // reuse as o-buffer
    // ---- o @ wo.T ----
    float ao = 0.f;
#pragma unroll
    for (int kk = 0; kk < 16; ++kk) {
      float4 ov = *(const float4*)&kvb[rr][tk][4 * kk];
      float4 w4 = wbuf4[(3 * 64 + d) * 17 + kk];
      ao += ov.x * w4.x + ov.y * w4.y + ov.z * w4.z + ov.w * w4.w;
    }
    float t1 = tok[rr][tk][d] + ao;
    // ---- LN1 ----
    float s = t1;
    for (int m = 1; m < 64; m <<= 1) s += __shfl_xor(s, m);
    float mean = s * (1.f / 64.f);
    float cv = t1 - mean;
    float v = cv * cv;
    for (int m = 1; m < 64; m <<= 1) v += __shfl_xor(v, m);
    v *= (1.f / 64.f);
    t1 = cv * __frsqrt_rn(v + LN_EPS) * fln1s[f * DD + d] + fln1b[f * DD + d];
    tok[rr][tk][d] = t1;
    __syncthreads();
    // ---- stage ffw1 [256][68] ----
    {
      const float4* s4 = (const float4*)(ffw1 + (size_t)f * NFFN * DD);
      for (int idx = tid; idx < 4096; idx += 768) {
        int rrow = idx >> 4, c4 = idx & 15;
        wbuf4[rrow * 17 + c4] = s4[idx];
      }
    }
    __syncthreads();
    // ---- FFN1 ----
    float h[4];
#pragma unroll
    for (int uu = 0; uu < 4; ++uu) h[uu] = ffb1[f * NFFN + d + 64 * uu];
#pragma unroll
    for (int kk = 0; kk < 16; ++kk) {
      float4 tv = *(const float4*)&tok[rr][tk][4 * kk];
      float4 w0 = wbuf4[(d + 0) * 17 + kk];
      float4 w1 = wbuf4[(d + 64) * 17 + kk];
      float4 w2 = wbuf4[(d + 128) * 17 + kk];
      float4 w3 = wbuf4[(d + 192) * 17 + kk];
      h[0] += tv.x * w0.x + tv.y * w0.y + tv.z * w0.z + tv.w * w0.w;
      h[1] += tv.x * w1.x + tv.y * w1.y + tv.z * w1.z + tv.w * w1.w;
      h[2] += tv.x * w2.x + tv.y * w2.y + tv.z * w2.z + tv.w * w2.w;
      h[3] += tv.x * w3.x + tv.y * w3.y + tv.z * w3.z + tv.w * w3.w;
    }
#pragma unroll
    for (int uu = 0; uu < 4; ++uu) hbuf[rr][tk][d + 64 * uu] = fmaxf(h[uu], 0.f);
    __syncthreads();
    // ---- stage ffw2 [64][260] ----
    {
      const float4* s4 = (const float4*)(ffw2 + (size_t)f * DD * NFFN);
      for (int idx = tid; idx < 4096; idx += 768) {
        int rrow = idx >> 6, c4 = idx & 63;
        wbuf4[rrow * 65 + c4] = s4[idx];
      }
    }
    __syncthreads();
    // ---- FFN2 ----
    float ff = ffb2[f * DD + d];
#pragma unroll 8
    for (int kk = 0; kk < 64; ++kk) {
      float4 hv = *(const float4*)&hbuf[rr][tk][4 * kk];
      float4 w4 = wbuf4[d * 65 + kk];
      ff += hv.x * w4.x + hv.y * w4.y + hv.z * w4.z + hv.w * w4.w;
    }
    float t2 = t1 + ff;
    // ---- LN2 ----
    s = t2;
    for (int m = 1; m < 64; m <<= 1) s += __shfl_xor(s, m);
    mean = s * (1.f / 64.f);
    cv = t2 - mean;
    v = cv * cv;
    for (int m = 1; m < 64; m <<= 1) v += __shfl_xor(v, m);
    v *= (1.f / 64.f);
    t2 = cv * __frsqrt_rn(v + LN_EPS) * fln2s[f * DD + d] + fln2b[f * DD + d];
    tok[rr][tk][d] = t2;
    __syncthreads();
  }
  // ---- final MLP ----
  if (tk == 2) {
    feat[rr][d] = tok[rr][2][d];
    feat[rr][DD + d] = ws[OFF_QUERY + b * DD + d];
  }
  {
    const float4* s4 = (const float4*)m1w;
    for (int idx = tid; idx < 4096; idx += 768) {
      int rrow = idx >> 5, c4 = idx & 31;
      wbuf4[rrow * 33 + c4] = s4[idx];
    }
  }
  __syncthreads();
  float partial = 0.f;
  if (t192 < 2 * DD) {
    int hh = t192;
    float acc = m1b[hh];
#pragma unroll
    for (int kk = 0; kk < 32; ++kk) {
      float4 fv = *(const float4*)&feat[rr][4 * kk];
      float4 w4 = wbuf4[hh * 33 + kk];
      acc += fv.x * w4.x + fv.y * w4.y + fv.z * w4.z + fv.w * w4.w;
    }
    acc = fmaxf(acc, 0.f);
    partial = acc * m2w[hh];
  }
  for (int m = 1; m < 64; m <<= 1) partial += __shfl_xor(partial, m);
  if (d == 0 && tk < 2) red[rr][tk] = partial;
  __syncthreads();
  if (t192 == 0) out[row] = red[rr][0] + red[rr][1] + m2b[0];
}

extern "C" void kernel_launch(void* const* d_in, const int* in_sizes, int n_in,
                              void* d_out, int out_size, void* d_ws, size_t ws_size,
                              hipStream_t stream) {
  const int* qt = (const int*)d_in[0];
  const int* eidx = (const int*)d_in[1];
  const int* etype = (const int*)d_in[2];
  const int* etime = (const int*)d_in[3];
  const float* qemb = (const float*)d_in[4];
  const float* ew = (const float*)d_in[5];
  const float* rlw = (const float*)d_in[6];
  const float* rlb = (const float*)d_in[7];
  const float* tw = (const float*)d_in[8];
  const float* tb = (const float*)d_in[9];
  const float* linw = (const float*)d_in[10];
  const float* linb = (const float*)d_in[11];
  const float* lns = (const float*)d_in[12];
  const float* lnb = (const float*)d_in[13];
  const float* pe = (const float*)d_in[14];
  const float* wq = (const float*)d_in[15];
  const float* wk = (const float*)d_in[16];
  const float* wv = (const float*)d_in[17];
  const float* wo = (const float*)d_in[18];
  const float* ffw1 = (const float*)d_in[19];
  const float* ffb1 = (const float*)d_in[20];
  const float* ffw2 = (const float*)d_in[21];
  const float* ffb2 = (const float*)d_in[22];
  const float* fln1s = (const float*)d_in[23];
  const float* fln1b = (const float*)d_in[24];
  const float* fln2s = (const float*)d_in[25];
  const float* fln2b = (const float*)d_in[26];
  const float* m1w = (const float*)d_in[27];
  const float* m1b = (const float*)d_in[28];
  const float* m2w = (const float*)d_in[29];
  const float* m2b = (const float*)d_in[30];
  float* ws = (float*)d_ws;
  float* out = (float*)d_out;

  k_prep<<<1, 256, 0, stream>>>(qt, qemb, ws);
  k_mint<<<(NE + 255) / 256, 256, 0, stream>>>(etime, ws);
  k_zero_ptr<<<(NW * (NN + 1) + 255) / 256, 256, 0, stream>>>(ws);
  k_transpose<<<(NL * 2 * DD * DD + 255) / 256, 256, 0, stream>>>(linw, ws);
  k_rel<<<dim3(NR * DD / 256, NL), 256, 0, stream>>>(rlw, rlb, ws);
  k_hist<<<dim3((NE + 255) / 256, NW), 256, 0, stream>>>(eidx, ws);
  k_scan<<<NW, 256, 0, stream>>>(ws);
  k_curinit<<<(NW * NN + 255) / 256, 256, 0, stream>>>(ws);
  k_scatter<<<dim3((NE + 255) / 256, NW), 256, 0, stream>>>(eidx, etype, etime, ew, ws);

  // l-loop with all 3 windows in flight per dispatch
  float* cur = ws + OFF_X;
  float* nxt = ws + OFF_X2;
  for (int l = 0; l < NL; ++l) {
    int init0 = (l == 0) ? 1 : 0;
    k_agg<<<dim3(NN / 4, NW), 256, 0, stream>>>(cur, tw, tb, ws, l, init0);
    k_gemm<<<dim3(NB * NN / 64, NW), 256, 0, stream>>>(linb, lns, lnb, cur, nxt, ws, l,
                                                       init0);
    float* t = cur; cur = nxt; nxt = t;
  }
  k_gather<<<dim3((NB * NNEG * DD + 255) / 256, NW), 256, 0, stream>>>(pe, cur, ws);
  k_xform<<<NB * NNEG / RPB, 768, 0, stream>>>(wq, wk, wv, wo, ffw1, ffb1, ffw2, ffb2,
                                                fln1s, fln1b, fln2s, fln2b, m1w, m1b, m2w,
                                                m2b, ws, out);
}

// Round 10
// 409.535 us; speedup vs baseline: 3.0135x; 1.1959x over previous
//
#include <hip/hip_runtime.h>
#include <hip/hip_bf16.h>
#include <cmath>

#define NB 4
#define NNEG 33
#define NN 10000
#define NE 100000
#define NW 3
#define DD 64
#define NL 3
#define NR 200
#define NFL 2
#define NFFN 256
#define LN_EPS 1e-5f
#define RPB 4   // rows per k_xform block (132 = 33*4)
#define XSZ (NB*NN*DD)

// ---- ws layout (float offsets) ----
// Interleaved state layout: XI[n][b][d] (node-major), one copy per window w.
#define OFF_QUERY 0                                   // NB*DD
#define OFF_H0    256                                 // NB ints
#define OFF_TSW   288                                 // NB*NNEG ints
#define OFF_MINT  448                                 // 1 int
#define OFF_RELI  512                                 // NL*NR*NB*DD  relI[l][et][b][d]
#define OFF_LINT  (OFF_RELI + NL*NR*NB*DD)            // NL*2*DD*DD  linT[l][k][c]
#define OFF_X     (OFF_LINT + NL*2*DD*DD)             // NW*XSZ
#define OFF_X2    (OFF_X + NW*XSZ)                    // NW*XSZ
#define OFF_AGG   (OFF_X2 + NW*XSZ)                   // NW*XSZ
#define OFF_TOK   (OFF_AGG + NW*XSZ)                  // NB*NNEG*NW*DD
// int offsets (4B units)
#define IOFF_PTR  (OFF_TOK + NB*NNEG*NW*DD)           // NW*(NN+1) ints
#define IOFF_CUR  (IOFF_PTR + NW*(NN+1))              // NW*NN ints
#define IOFF_REC  ((IOFF_CUR + NW*NN + 3) & ~3)       // NW*NE*4 ints, 16B aligned

// ---------------- prep ----------------
__global__ void k_prep(const int* __restrict__ qt, const float* __restrict__ qemb,
                       float* __restrict__ ws) {
  int tid = threadIdx.x;
  if (tid < NB * DD) {
    int b = tid / DD, d = tid % DD;
    int h0 = qt[(b * NNEG + 0) * 3 + 0];
    bool itn = true;
    for (int j = 1; j < NNEG; ++j) itn = itn && (qt[(b * NNEG + j) * 3 + 0] == h0);
    int r0 = qt[(b * NNEG + 0) * 3 + 1] + (itn ? 0 : NR / 2);
    ws[OFF_QUERY + b * DD + d] = qemb[r0 * DD + d];
    if (d == 0) {
      int t0 = qt[(b * NNEG + 0) * 3 + 2];
      ((int*)ws)[OFF_H0 + b] = itn ? h0 : t0;
    }
  }
  if (tid < NB * NNEG) {
    int b = tid / NNEG, j = tid % NNEG;
    int h0 = qt[(b * NNEG + 0) * 3 + 0];
    bool itn = true;
    for (int jj = 1; jj < NNEG; ++jj) itn = itn && (qt[(b * NNEG + jj) * 3 + 0] == h0);
    int h = qt[(b * NNEG + j) * 3 + 0], t = qt[(b * NNEG + j) * 3 + 2];
    ((int*)ws)[OFF_TSW + tid] = itn ? t : h;
  }
  if (tid == 0) ((int*)ws)[OFF_MINT] = 0x7fffffff;
}

// ---------------- min over edge_time[0] ----------------
__global__ void k_mint(const int* __restrict__ etime, float* __restrict__ ws) {
  int i = blockIdx.x * blockDim.x + threadIdx.x;
  int v = (i < NE) ? etime[i] : 0x7fffffff;
  for (int m = 1; m < 64; m <<= 1) v = min(v, __shfl_xor(v, m));
  if ((threadIdx.x & 63) == 0) atomicMin(&((int*)ws)[OFF_MINT], v);
}

// ---------------- zero ptr array ----------------
__global__ void k_zero_ptr(float* __restrict__ ws) {
  int i = blockIdx.x * 256 + threadIdx.x;
  if (i < NW * (NN + 1)) ((int*)ws)[IOFF_PTR + i] = 0;
}

// ---------------- transpose lin_w: linT[l][k][c] = lin_w[l][c][k] ----------------
__global__ void k_transpose(const float* __restrict__ lin_w, float* __restrict__ ws) {
  int idx = blockIdx.x * blockDim.x + threadIdx.x;
  if (idx < NL * 2 * DD * DD) {
    int l = idx / (2 * DD * DD), r = idx % (2 * DD * DD), k = r / DD, c = r % DD;
    ws[OFF_LINT + idx] = lin_w[(l * DD + c) * 2 * DD + k];
  }
}

// ---------------- histogram of dst ----------------
__global__ void k_hist(const int* __restrict__ eidx, float* __restrict__ ws) {
  int e = blockIdx.x * 256 + threadIdx.x, w = blockIdx.y;
  if (e >= NE) return;
  int dst = eidx[(w * 2 + 1) * NE + e];
  atomicAdd(&((int*)ws)[IOFF_PTR + w * (NN + 1) + dst + 1], 1);
}

// ---------------- inclusive scan -> ptr (one block per w) ----------------
__global__ void k_scan(float* __restrict__ ws) {
  int w = blockIdx.x;
  int* p = (int*)ws + IOFF_PTR + w * (NN + 1);
  __shared__ int wsum[4];
  __shared__ int runv;
  if (threadIdx.x == 0) runv = 0;
  __syncthreads();
  int lane = threadIdx.x & 63, wv = threadIdx.x >> 6;
  for (int base = 0; base < NN + 1; base += 256) {
    int i = base + threadIdx.x;
    int v = (i <= NN) ? p[i] : 0;
    for (int off = 1; off < 64; off <<= 1) {
      int t = __shfl_up(v, off);
      if (lane >= off) v += t;
    }
    if (lane == 63) wsum[wv] = v;
    __syncthreads();
    int add = runv;
    for (int u = 0; u < wv; ++u) add += wsum[u];
    v += add;
    if (i <= NN) p[i] = v;
    __syncthreads();
    if (threadIdx.x == 255) runv = v;
    __syncthreads();
  }
}

// ---------------- cursor init ----------------
__global__ void k_curinit(float* __restrict__ ws) {
  int i = blockIdx.x * 256 + threadIdx.x;
  if (i >= NW * NN) return;
  int w = i / NN, n = i % NN;
  ((int*)ws)[IOFF_CUR + i] = ((int*)ws)[IOFF_PTR + w * (NN + 1) + n];
}

// ---------------- scatter edges into CSR records {src, et, dt, weight} ----------------
__global__ void k_scatter(const int* __restrict__ eidx, const int* __restrict__ etype,
                          const int* __restrict__ etime, const float* __restrict__ eweight,
                          float* __restrict__ ws) {
  int e = blockIdx.x * 256 + threadIdx.x, w = blockIdx.y;
  if (e >= NE) return;
  int* wsi = (int*)ws;
  int dst = eidx[(w * 2 + 1) * NE + e];
  int pos = atomicAdd(&wsi[IOFF_CUR + w * NN + dst], 1);
  float dt = (float)etime[w * NE + e] - (float)wsi[OFF_MINT];
  int4 rec;
  rec.x = eidx[(w * 2 + 0) * NE + e];
  rec.y = etype[w * NE + e];
  rec.z = __float_as_int(dt);
  rec.w = __float_as_int(eweight[w * NE + e]);
  ((int4*)(wsi + IOFF_REC))[(size_t)w * NE + pos] = rec;
}

// ---------------- rel = query @ rel_lin_w.T + b (written interleaved) ----------------
__global__ void k_rel(const float* __restrict__ rlw, const float* __restrict__ rlb,
                      float* __restrict__ ws) {
  int l = blockIdx.y;
  int rd = blockIdx.x * blockDim.x + threadIdx.x;
  const float4* wrow = (const float4*)(rlw + ((size_t)(l * NR * DD + rd)) * DD);
  float4 wreg[16];
#pragma unroll
  for (int kk = 0; kk < 16; ++kk) wreg[kk] = wrow[kk];
  float bias = rlb[l * NR * DD + rd];
  int r = rd >> 6, d = rd & 63;
  for (int b = 0; b < NB; ++b) {
    const float4* q4 = (const float4*)(ws + OFF_QUERY + b * DD);
    float acc = 0.f;
#pragma unroll
    for (int kk = 0; kk < 16; ++kk) {
      float4 q = q4[kk];
      acc += q.x * wreg[kk].x + q.y * wreg[kk].y + q.z * wreg[kk].z + q.w * wreg[kk].w;
    }
    ws[OFF_RELI + (size_t)(l * NR + r) * (NB * DD) + b * DD + d] = acc + bias;
  }
}

// ---------------- CSR gather aggregation: grid.y = w (windows run concurrently) -------
__global__ __launch_bounds__(256) void k_agg(const float* __restrict__ xbase,
                                             const float* __restrict__ tw,
                                             const float* __restrict__ tb,
                                             float* __restrict__ ws, int l, int init0) {
  int w = blockIdx.y;
  int lane = threadIdx.x & 63;
  int wv = threadIdx.x >> 6;
  int n = blockIdx.x * 4 + wv;
  int b = lane >> 4;
  int q4i = lane & 15;
  const int* wsi = (const int*)ws;
  int p0 = __builtin_amdgcn_readfirstlane(wsi[IOFF_PTR + w * (NN + 1) + n]);
  int p1 = __builtin_amdgcn_readfirstlane(wsi[IOFF_PTR + w * (NN + 1) + n + 1]);
  const int4* recs = ((const int4*)(wsi + IOFF_REC)) + (size_t)w * NE;
  const float4* XI4 = (const float4*)(xbase + (size_t)w * XSZ);
  const float4* RELI4 = (const float4*)(ws + OFF_RELI) + (size_t)l * NR * 64;
  const float4* TW4 = (const float4*)(tw + (size_t)l * NR * DD);  // [NR][16] f4
  const float4* TB4 = (const float4*)(tb + (size_t)l * NR * DD);
  int h00 = wsi[OFF_H0 + 0], h01 = wsi[OFF_H0 + 1];
  int h02 = wsi[OFF_H0 + 2], h03 = wsi[OFF_H0 + 3];
  int h0b = wsi[OFF_H0 + b];
  float4 q4b = ((const float4*)(ws + OFF_QUERY))[lane];
  float4 acc;
  if (n == h0b) acc = q4b;
  else { acc.x = 0.f; acc.y = 0.f; acc.z = 0.f; acc.w = 0.f; }

  if (init0) {
    for (int j = p0; j < p1; ++j) {
      int4 rec = recs[j];
      int src = rec.x;
      if (!((src == h00) | (src == h01) | (src == h02) | (src == h03))) continue;
      int et = rec.y;
      float dtf = __int_as_float(rec.z);
      float m = (src == h0b) ? __int_as_float(rec.w) : 0.f;
      float4 r4 = RELI4[et * 64 + lane];
      float4 w4 = TW4[et * 16 + q4i];
      float4 b4 = TB4[et * 16 + q4i];
      acc.x = fmaf(q4b.x * r4.x, __cosf(fmaf(dtf, w4.x, b4.x)) * m, acc.x);
      acc.y = fmaf(q4b.y * r4.y, __cosf(fmaf(dtf, w4.y, b4.y)) * m, acc.y);
      acc.z = fmaf(q4b.z * r4.z, __cosf(fmaf(dtf, w4.z, b4.z)) * m, acc.z);
      acc.w = fmaf(q4b.w * r4.w, __cosf(fmaf(dtf, w4.w, b4.w)) * m, acc.w);
    }
  } else {
#define EDGE_BODY(J)                                                           \
    {                                                                          \
      int4 rec = recs[J];                                                      \
      int src = rec.x, et = rec.y;                                             \
      float dtf = __int_as_float(rec.z), wgt = __int_as_float(rec.w);          \
      float4 x4 = XI4[(size_t)src * 64 + lane];                                \
      float4 r4 = RELI4[et * 64 + lane];                                       \
      float4 w4 = TW4[et * 16 + q4i];                                          \
      float4 b4 = TB4[et * 16 + q4i];                                          \
      acc.x = fmaf(x4.x * r4.x, __cosf(fmaf(dtf, w4.x, b4.x)) * wgt, acc.x);   \
      acc.y = fmaf(x4.y * r4.y, __cosf(fmaf(dtf, w4.y, b4.y)) * wgt, acc.y);   \
      acc.z = fmaf(x4.z * r4.z, __cosf(fmaf(dtf, w4.z, b4.z)) * wgt, acc.z);   \
      acc.w = fmaf(x4.w * r4.w, __cosf(fmaf(dtf, w4.w, b4.w)) * wgt, acc.w);   \
    }
    int j = p0;
    for (; j + 1 < p1; j += 2) {
      EDGE_BODY(j);
      EDGE_BODY(j + 1);
    }
    if (j < p1) EDGE_BODY(j);
#undef EDGE_BODY
  }
  ((float4*)(ws + OFF_AGG + (size_t)w * XSZ))[(size_t)n * 64 + lane] = acc;
}

// ---------------- node GEMM + LN + residual; LDS-staged rows; grid.y = w --------------
// Block stages its 64 rows of x and agg into LDS (coalesced), then wave wv computes
// rows wv*16..wv*16+15 with lane = output col c and broadcast LDS row reads.
__global__ __launch_bounds__(256) void k_gemm(const float* __restrict__ linb,
                                              const float* __restrict__ lns,
                                              const float* __restrict__ lnb,
                                              const float* __restrict__ xbase,
                                              float* __restrict__ xdstbase,
                                              const float* __restrict__ ws, int l,
                                              int init0) {
  __shared__ float4 xs4[64 * 16];  // 64 rows x 64 floats (x)
  __shared__ float4 as4[64 * 16];  // 64 rows x 64 floats (agg)
  int w = blockIdx.y;
  int tid = threadIdx.x;
  const float* xsrc = xbase + (size_t)w * XSZ;
  float* xdst = xdstbase + (size_t)w * XSZ;
  int rowblk = blockIdx.x * 64;
  const float4* xr = (const float4*)xsrc + (size_t)rowblk * 16;
  const float4* ar = (const float4*)(ws + OFF_AGG + (size_t)w * XSZ) + (size_t)rowblk * 16;
  if (!init0) {
#pragma unroll
    for (int u = 0; u < 4; ++u) xs4[tid + 256 * u] = xr[tid + 256 * u];
  }
#pragma unroll
  for (int u = 0; u < 4; ++u) as4[tid + 256 * u] = ar[tid + 256 * u];
  __syncthreads();

  int wv = __builtin_amdgcn_readfirstlane(tid >> 6);
  int c = tid & 63;
  int lr0 = wv * 16;               // local row base within block
  int row0 = rowblk + lr0;
  const float* WT = ws + OFF_LINT + l * 2 * DD * DD;  // [128][64]
  const int* wsi = (const int*)ws;
  float bias = linb[l * DD + c];
  float acc[16];
#pragma unroll
  for (int r = 0; r < 16; ++r) acc[r] = bias;
  if (init0) {
#pragma unroll
    for (int r = 0; r < 16; ++r) {
      int nr = (row0 + r) >> 2, br = (row0 + r) & 3;
      if (nr == wsi[OFF_H0 + br]) {
        const float4* q4 = (const float4*)(ws + OFF_QUERY + br * DD);
        for (int kk = 0; kk < 16; ++kk) {
          float4 qv = q4[kk];
          acc[r] = fmaf(qv.x, WT[(4 * kk + 0) * DD + c], acc[r]);
          acc[r] = fmaf(qv.y, WT[(4 * kk + 1) * DD + c], acc[r]);
          acc[r] = fmaf(qv.z, WT[(4 * kk + 2) * DD + c], acc[r]);
          acc[r] = fmaf(qv.w, WT[(4 * kk + 3) * DD + c], acc[r]);
        }
      }
    }
  } else {
    for (int kk = 0; kk < 16; ++kk) {
      float w0 = WT[(4 * kk + 0) * DD + c];
      float w1 = WT[(4 * kk + 1) * DD + c];
      float w2 = WT[(4 * kk + 2) * DD + c];
      float w3 = WT[(4 * kk + 3) * DD + c];
#pragma unroll
      for (int r = 0; r < 16; ++r) {
        float4 xv = xs4[(lr0 + r) * 16 + kk];  // LDS broadcast
        acc[r] = fmaf(xv.x, w0, acc[r]);
        acc[r] = fmaf(xv.y, w1, acc[r]);
        acc[r] = fmaf(xv.z, w2, acc[r]);
        acc[r] = fmaf(xv.w, w3, acc[r]);
      }
    }
  }
  for (int kk = 0; kk < 16; ++kk) {
    float w0 = WT[(64 + 4 * kk + 0) * DD + c];
    float w1 = WT[(64 + 4 * kk + 1) * DD + c];
    float w2 = WT[(64 + 4 * kk + 2) * DD + c];
    float w3 = WT[(64 + 4 * kk + 3) * DD + c];
#pragma unroll
    for (int r = 0; r < 16; ++r) {
      float4 av = as4[(lr0 + r) * 16 + kk];  // LDS broadcast
      acc[r] = fmaf(av.x, w0, acc[r]);
      acc[r] = fmaf(av.y, w1, acc[r]);
      acc[r] = fmaf(av.z, w2, acc[r]);
      acc[r] = fmaf(av.w, w3, acc[r]);
    }
  }
  float sc = lns[l * DD + c], bc = lnb[l * DD + c];
#pragma unroll
  for (int r = 0; r < 16; ++r) {
    float v = acc[r];
    float s = v;
    for (int m = 1; m < 64; m <<= 1) s += __shfl_xor(s, m);
    float mean = s * (1.f / 64.f);
    float cv = v - mean;
    float vv = cv * cv;
    for (int m = 1; m < 64; m <<= 1) vv += __shfl_xor(vv, m);
    vv *= (1.f / 64.f);
    float y = cv * __frsqrt_rn(vv + LN_EPS) * sc + bc;
    y = fmaxf(y, 0.f);
    float xo;
    if (init0) {
      int nr = (row0 + r) >> 2, br = (row0 + r) & 3;
      xo = (nr == wsi[OFF_H0 + br]) ? ws[OFF_QUERY + br * DD + c] : 0.f;
    } else {
      xo = ((const float*)xs4)[(lr0 + r) * 64 + c];  // LDS, coalesced
    }
    xdst[(size_t)(row0 + r) * DD + c] = xo + y;
  }
}

// ---------------- gather tail features into tokens (+pe), all w at once ----------------
__global__ void k_gather(const float* __restrict__ pe, const float* __restrict__ xfinbase,
                         float* __restrict__ ws) {
  int w = blockIdx.y;
  int i = blockIdx.x * 256 + threadIdx.x;
  if (i >= NB * NNEG * DD) return;
  int bj = i / DD, d = i % DD;
  int b = bj / NNEG;
  int t = ((const int*)ws)[OFF_TSW + bj];
  ws[OFF_TOK + bj * NW * DD + w * DD + d] =
      xfinbase[(size_t)w * XSZ + (size_t)t * (NB * DD) + b * DD + d] + pe[w * DD + d];
}

// ---------------- transformer + final MLP: round-4 structure (best measured) ----------
__global__ __launch_bounds__(768) void k_xform(
    const float* __restrict__ wq, const float* __restrict__ wk,
    const float* __restrict__ wv, const float* __restrict__ wo,
    const float* __restrict__ ffw1, const float* __restrict__ ffb1,
    const float* __restrict__ ffw2, const float* __restrict__ ffb2,
    const float* __restrict__ fln1s, const float* __restrict__ fln1b,
    const float* __restrict__ fln2s, const float* __restrict__ fln2b,
    const float* __restrict__ m1w, const float* __restrict__ m1b,
    const float* __restrict__ m2w, const float* __restrict__ m2b,
    float* __restrict__ ws, float* __restrict__ out) {
  __shared__ float tok[RPB][NW][DD], kvb[RPB][NW][DD], vvb[RPB][NW][DD];
  __shared__ float hbuf[RPB][NW][NFFN];
  __shared__ float feat[RPB][2 * DD];
  __shared__ float red[RPB][2];
  __shared__ float4 wbuf4[4352];  // 68 KB padded staging buffer
  int tid = threadIdx.x;
  int rr = tid / 192;
  int t192 = tid - rr * 192;
  int tk = t192 >> 6, d = t192 & 63;
  int row = blockIdx.x * RPB + rr, b = row / NNEG;
  tok[rr][tk][d] = ws[OFF_TOK + row * NW * DD + tk * DD + d];
  for (int f = 0; f < NFL; ++f) {
    // ---- stage wq,wk,wv,wo as 4x [64][68] ----
    {
      const float4* s0 = (const float4*)(wq + (size_t)f * DD * DD);
      const float4* s1 = (const float4*)(wk + (size_t)f * DD * DD);
      const float4* s2 = (const float4*)(wv + (size_t)f * DD * DD);
      const float4* s3 = (const float4*)(wo + (size_t)f * DD * DD);
      for (int idx = tid; idx < 4096; idx += 768) {
        int m = idx >> 10, rem = idx & 1023;
        int rrow = rem >> 4, c4 = rem & 15;
        const float4* s = (m == 0) ? s0 : (m == 1) ? s1 : (m == 2) ? s2 : s3;
        wbuf4[(m * 64 + rrow) * 17 + c4] = s[rem];
      }
    }
    __syncthreads();
    // ---- QKV from LDS ----
    float qd = 0.f, kd = 0.f, vd = 0.f;
#pragma unroll
    for (int kk = 0; kk < 16; ++kk) {
      float4 tv = *(const float4*)&tok[rr][tk][4 * kk];
      float4 aq = wbuf4[(0 * 64 + d) * 17 + kk];
      float4 ak = wbuf4[(1 * 64 + d) * 17 + kk];
      float4 av = wbuf4[(2 * 64 + d) * 17 + kk];
      qd += tv.x * aq.x + tv.y * aq.y + tv.z * aq.z + tv.w * aq.w;
      kd += tv.x * ak.x + tv.y * ak.y + tv.z * ak.z + tv.w * ak.w;
      vd += tv.x * av.x + tv.y * av.y + tv.z * av.z + tv.w * av.w;
    }
    kvb[rr][tk][d] = kd;
    vvb[rr][tk][d] = vd;
    __syncthreads();
    // ---- attention (head = d>>4) ----
    float sc[NW];
#pragma unroll
    for (int j = 0; j < NW; ++j) {
      float p = qd * kvb[rr][j][d];
      p += __shfl_xor(p, 1);
      p += __shfl_xor(p, 2);
      p += __shfl_xor(p, 4);
      p += __shfl_xor(p, 8);
      sc[j] = p * 0.25f;  // 1/sqrt(16)
    }
    float mx = fmaxf(sc[0], fmaxf(sc[1], sc[2]));
    float e0 = expf(sc[0] - mx), e1 = expf(sc[1] - mx), e2 = expf(sc[2] - mx);
    float inv = 1.f / (e0 + e1 + e2);
    float od = (e0 * vvb[rr][0][d] + e1 * vvb[rr][1][d] + e2 * vvb[rr][2][d]) * inv;
    __syncthreads();
    kvb[rr][tk][d] = od;  // reuse as o-buffer
    // ---- o @ wo.T ----
    float ao = 0.f;
#pragma unroll
    for (int kk = 0; kk < 16; ++kk) {
      float4 ov = *(const float4*)&kvb[rr][tk][4 * kk];
      float4 w4 = wbuf4[(3 * 64 + d) * 17 + kk];
      ao += ov.x * w4.x + ov.y * w4.y + ov.z * w4.z + ov.w * w4.w;
    }
    float t1 = tok[rr][tk][d] + ao;
    // ---- LN1 ----
    float s = t1;
    for (int m = 1; m < 64; m <<= 1) s += __shfl_xor(s, m);
    float mean = s * (1.f / 64.f);
    float cv = t1 - mean;
    float v = cv * cv;
    for (int m = 1; m < 64; m <<= 1) v += __shfl_xor(v, m);
    v *= (1.f / 64.f);
    t1 = cv * __frsqrt_rn(v + LN_EPS) * fln1s[f * DD + d] + fln1b[f * DD + d];
    tok[rr][tk][d] = t1;
    __syncthreads();
    // ---- stage ffw1 [256][68] ----
    {
      const float4* s4 = (const float4*)(ffw1 + (size_t)f * NFFN * DD);
      for (int idx = tid; idx < 4096; idx += 768) {
        int rrow = idx >> 4, c4 = idx & 15;
        wbuf4[rrow * 17 + c4] = s4[idx];
      }
    }
    __syncthreads();
    // ---- FFN1 ----
    float h[4];
#pragma unroll
    for (int uu = 0; uu < 4; ++uu) h[uu] = ffb1[f * NFFN + d + 64 * uu];
#pragma unroll
    for (int kk = 0; kk < 16; ++kk) {
      float4 tv = *(const float4*)&tok[rr][tk][4 * kk];
      float4 w0 = wbuf4[(d + 0) * 17 + kk];
      float4 w1 = wbuf4[(d + 64) * 17 + kk];
      float4 w2 = wbuf4[(d + 128) * 17 + kk];
      float4 w3 = wbuf4[(d + 192) * 17 + kk];
      h[0] += tv.x * w0.x + tv.y * w0.y + tv.z * w0.z + tv.w * w0.w;
      h[1] += tv.x * w1.x + tv.y * w1.y + tv.z * w1.z + tv.w * w1.w;
      h[2] += tv.x * w2.x + tv.y * w2.y + tv.z * w2.z + tv.w * w2.w;
      h[3] += tv.x * w3.x + tv.y * w3.y + tv.z * w3.z + tv.w * w3.w;
    }
#pragma unroll
    for (int uu = 0; uu < 4; ++uu) hbuf[rr][tk][d + 64 * uu] = fmaxf(h[uu], 0.f);
    __syncthreads();
    // ---- stage ffw2 [64][260] ----
    {
      const float4* s4 = (const float4*)(ffw2 + (size_t)f * DD * NFFN);
      for (int idx = tid; idx < 4096; idx += 768) {
        int rrow = idx >> 6, c4 = idx & 63;
        wbuf4[rrow * 65 + c4] = s4[idx];
      }
    }
    __syncthreads();
    // ---- FFN2 ----
    float ff = ffb2[f * DD + d];
#pragma unroll 8
    for (int kk = 0; kk < 64; ++kk) {
      float4 hv = *(const float4*)&hbuf[rr][tk][4 * kk];
      float4 w4 = wbuf4[d * 65 + kk];
      ff += hv.x * w4.x + hv.y * w4.y + hv.z * w4.z + hv.w * w4.w;
    }
    float t2 = t1 + ff;
    // ---- LN2 ----
    s = t2;
    for (int m = 1; m < 64; m <<= 1) s += __shfl_xor(s, m);
    mean = s * (1.f / 64.f);
    cv = t2 - mean;
    v = cv * cv;
    for (int m = 1; m < 64; m <<= 1) v += __shfl_xor(v, m);
    v *= (1.f / 64.f);
    t2 = cv * __frsqrt_rn(v + LN_EPS) * fln2s[f * DD + d] + fln2b[f * DD + d];
    tok[rr][tk][d] = t2;
    __syncthreads();
  }
  // ---- final MLP ----
  if (tk == 2) {
    feat[rr][d] = tok[rr][2][d];
    feat[rr][DD + d] = ws[OFF_QUERY + b * DD + d];
  }
  {
    const float4* s4 = (const float4*)m1w;
    for (int idx = tid; idx < 4096; idx += 768) {
      int rrow = idx >> 5, c4 = idx & 31;
      wbuf4[rrow * 33 + c4] = s4[idx];
    }
  }
  __syncthreads();
  float partial = 0.f;
  if (t192 < 2 * DD) {
    int hh = t192;
    float acc = m1b[hh];
#pragma unroll
    for (int kk = 0; kk < 32; ++kk) {
      float4 fv = *(const float4*)&feat[rr][4 * kk];
      float4 w4 = wbuf4[hh * 33 + kk];
      acc += fv.x * w4.x + fv.y * w4.y + fv.z * w4.z + fv.w * w4.w;
    }
    acc = fmaxf(acc, 0.f);
    partial = acc * m2w[hh];
  }
  for (int m = 1; m < 64; m <<= 1) partial += __shfl_xor(partial, m);
  if (d == 0 && tk < 2) red[rr][tk] = partial;
  __syncthreads();
  if (t192 == 0) out[row] = red[rr][0] + red[rr][1] + m2b[0];
}

extern "C" void kernel_launch(void* const* d_in, const int* in_sizes, int n_in,
                              void* d_out, int out_size, void* d_ws, size_t ws_size,
                              hipStream_t stream) {
  const int* qt = (const int*)d_in[0];
  const int* eidx = (const int*)d_in[1];
  const int* etype = (const int*)d_in[2];
  const int* etime = (const int*)d_in[3];
  const float* qemb = (const float*)d_in[4];
  const float* ew = (const float*)d_in[5];
  const float* rlw = (const float*)d_in[6];
  const float* rlb = (const float*)d_in[7];
  const float* tw = (const float*)d_in[8];
  const float* tb = (const float*)d_in[9];
  const float* linw = (const float*)d_in[10];
  const float* linb = (const float*)d_in[11];
  const float* lns = (const float*)d_in[12];
  const float* lnb = (const float*)d_in[13];
  const float* pe = (const float*)d_in[14];
  const float* wq = (const float*)d_in[15];
  const float* wk = (const float*)d_in[16];
  const float* wv = (const float*)d_in[17];
  const float* wo = (const float*)d_in[18];
  const float* ffw1 = (const float*)d_in[19];
  const float* ffb1 = (const float*)d_in[20];
  const float* ffw2 = (const float*)d_in[21];
  const float* ffb2 = (const float*)d_in[22];
  const float* fln1s = (const float*)d_in[23];
  const float* fln1b = (const float*)d_in[24];
  const float* fln2s = (const float*)d_in[25];
  const float* fln2b = (const float*)d_in[26];
  const float* m1w = (const float*)d_in[27];
  const float* m1b = (const float*)d_in[28];
  const float* m2w = (const float*)d_in[29];
  const float* m2b = (const float*)d_in[30];
  float* ws = (float*)d_ws;
  float* out = (float*)d_out;

  k_prep<<<1, 256, 0, stream>>>(qt, qemb, ws);
  k_mint<<<(NE + 255) / 256, 256, 0, stream>>>(etime, ws);
  k_zero_ptr<<<(NW * (NN + 1) + 255) / 256, 256, 0, stream>>>(ws);
  k_transpose<<<(NL * 2 * DD * DD + 255) / 256, 256, 0, stream>>>(linw, ws);
  k_rel<<<dim3(NR * DD / 256, NL), 256, 0, stream>>>(rlw, rlb, ws);
  k_hist<<<dim3((NE + 255) / 256, NW), 256, 0, stream>>>(eidx, ws);
  k_scan<<<NW, 256, 0, stream>>>(ws);
  k_curinit<<<(NW * NN + 255) / 256, 256, 0, stream>>>(ws);
  k_scatter<<<dim3((NE + 255) / 256, NW), 256, 0, stream>>>(eidx, etype, etime, ew, ws);

  // l-loop with all 3 windows in flight per dispatch
  float* cur = ws + OFF_X;
  float* nxt = ws + OFF_X2;
  for (int l = 0; l < NL; ++l) {
    int init0 = (l == 0) ? 1 : 0;
    k_agg<<<dim3(NN / 4, NW), 256, 0, stream>>>(cur, tw, tb, ws, l, init0);
    k_gemm<<<dim3(NB * NN / 64, NW), 256, 0, stream>>>(linb, lns, lnb, cur, nxt, ws, l,
                                                       init0);
    float* t = cur; cur = nxt; nxt = t;
  }
  k_gather<<<dim3((NB * NNEG * DD + 255) / 256, NW), 256, 0, stream>>>(pe, cur, ws);
  k_xform<<<NB * NNEG / RPB, 768, 0, stream>>>(wq, wk, wv, wo, ffw1, ffb1, ffw2, ffb2,
                                                fln1s, fln1b, fln2s, fln2b, m1w, m1b, m2w,
                                                m2b, ws, out);
}

// Round 11
// 322.386 us; speedup vs baseline: 3.8281x; 1.2703x over previous
//
#include <hip/hip_runtime.h>
#include <hip/hip_bf16.h>
#include <cmath>

#define NB 4
#define NNEG 33
#define NN 10000
#define NE 100000
#define NW 3
#define DD 64
#define NL 3
#define NR 200
#define NFL 2
#define NFFN 256
#define LN_EPS 1e-5f
#define RPB 4   // rows per k_xform block (132 = 33*4)
#define XSZ (NB*NN*DD)

// ---- ws layout (float offsets) ----
#define OFF_QUERY 0                                   // NB*DD
#define OFF_H0    256                                 // NB ints
#define OFF_TSW   288                                 // NB*NNEG ints
#define OFF_MINT  448                                 // 1 int
#define OFF_RELI  512                                 // NL*NR*NB*DD  relI[l][et][b][d]
#define OFF_LINT  (OFF_RELI + NL*NR*NB*DD)            // NL*2*DD*DD  linT[l][k][c]
#define OFF_X     (OFF_LINT + NL*2*DD*DD)             // NW*XSZ
#define OFF_X2    (OFF_X + NW*XSZ)                    // NW*XSZ
#define OFF_AGG   (OFF_X2 + NW*XSZ)                   // NW*XSZ
#define OFF_TOK   (OFF_AGG + NW*XSZ)                  // NB*NNEG*NW*DD
#define OFF_YC    (OFF_TOK + NB*NNEG*NW*DD)           // DD (l0 constant row)
// int offsets (4B units)
#define IOFF_PTR  (OFF_YC + DD)                       // NW*(NN+1) ints
#define IOFF_CUR  (IOFF_PTR + NW*(NN+1))              // NW*NN ints
#define IOFF_REC  ((IOFF_CUR + NW*NN + 3) & ~3)       // NW*NE*4 ints, 16B aligned
#define IOFF_FLG  (IOFF_REC + NW*NE*4)                // NW*NN*4 bytes (flag per w,n,b)

// ---------------- prep ----------------
__global__ void k_prep(const int* __restrict__ qt, const float* __restrict__ qemb,
                       float* __restrict__ ws) {
  int tid = threadIdx.x;
  if (tid < NB * DD) {
    int b = tid / DD, d = tid % DD;
    int h0 = qt[(b * NNEG + 0) * 3 + 0];
    bool itn = true;
    for (int j = 1; j < NNEG; ++j) itn = itn && (qt[(b * NNEG + j) * 3 + 0] == h0);
    int r0 = qt[(b * NNEG + 0) * 3 + 1] + (itn ? 0 : NR / 2);
    ws[OFF_QUERY + b * DD + d] = qemb[r0 * DD + d];
    if (d == 0) {
      int t0 = qt[(b * NNEG + 0) * 3 + 2];
      ((int*)ws)[OFF_H0 + b] = itn ? h0 : t0;
    }
  }
  if (tid < NB * NNEG) {
    int b = tid / NNEG, j = tid % NNEG;
    int h0 = qt[(b * NNEG + 0) * 3 + 0];
    bool itn = true;
    for (int jj = 1; jj < NNEG; ++jj) itn = itn && (qt[(b * NNEG + jj) * 3 + 0] == h0);
    int h = qt[(b * NNEG + j) * 3 + 0], t = qt[(b * NNEG + j) * 3 + 2];
    ((int*)ws)[OFF_TSW + tid] = itn ? t : h;
  }
  if (tid == 0) ((int*)ws)[OFF_MINT] = 0x7fffffff;
}

// ---------------- min over edge_time[0] ----------------
__global__ void k_mint(const int* __restrict__ etime, float* __restrict__ ws) {
  int i = blockIdx.x * blockDim.x + threadIdx.x;
  int v = (i < NE) ? etime[i] : 0x7fffffff;
  for (int m = 1; m < 64; m <<= 1) v = min(v, __shfl_xor(v, m));
  if ((threadIdx.x & 63) == 0) atomicMin(&((int*)ws)[OFF_MINT], v);
}

// ---------------- zero ptr array ----------------
__global__ void k_zero_ptr(float* __restrict__ ws) {
  int i = blockIdx.x * 256 + threadIdx.x;
  if (i < NW * (NN + 1)) ((int*)ws)[IOFF_PTR + i] = 0;
}

// ---------------- yconst: l0 output row for generic (zero-input) nodes ----------------
__global__ void k_yconst(const float* __restrict__ linb, const float* __restrict__ lns,
                         const float* __restrict__ lnb, float* __restrict__ ws) {
  int d = threadIdx.x;  // 64 threads
  float v = linb[d];    // l = 0 bias
  float s = v;
  for (int m = 1; m < 64; m <<= 1) s += __shfl_xor(s, m);
  float mean = s * (1.f / 64.f);
  float cv = v - mean;
  float vv = cv * cv;
  for (int m = 1; m < 64; m <<= 1) vv += __shfl_xor(vv, m);
  vv *= (1.f / 64.f);
  float y = cv * __frsqrt_rn(vv + LN_EPS) * lns[d] + lnb[d];
  ws[OFF_YC + d] = fmaxf(y, 0.f);
}

// ---------------- transpose lin_w: linT[l][k][c] = lin_w[l][c][k] ----------------
__global__ void k_transpose(const float* __restrict__ lin_w, float* __restrict__ ws) {
  int idx = blockIdx.x * blockDim.x + threadIdx.x;
  if (idx < NL * 2 * DD * DD) {
    int l = idx / (2 * DD * DD), r = idx % (2 * DD * DD), k = r / DD, c = r % DD;
    ws[OFF_LINT + idx] = lin_w[(l * DD + c) * 2 * DD + k];
  }
}

// ---------------- histogram of dst ----------------
__global__ void k_hist(const int* __restrict__ eidx, float* __restrict__ ws) {
  int e = blockIdx.x * 256 + threadIdx.x, w = blockIdx.y;
  if (e >= NE) return;
  int dst = eidx[(w * 2 + 1) * NE + e];
  atomicAdd(&((int*)ws)[IOFF_PTR + w * (NN + 1) + dst + 1], 1);
}

// ---------------- inclusive scan -> ptr (one block per w) ----------------
__global__ void k_scan(float* __restrict__ ws) {
  int w = blockIdx.x;
  int* p = (int*)ws + IOFF_PTR + w * (NN + 1);
  __shared__ int wsum[4];
  __shared__ int runv;
  if (threadIdx.x == 0) runv = 0;
  __syncthreads();
  int lane = threadIdx.x & 63, wv = threadIdx.x >> 6;
  for (int base = 0; base < NN + 1; base += 256) {
    int i = base + threadIdx.x;
    int v = (i <= NN) ? p[i] : 0;
    for (int off = 1; off < 64; off <<= 1) {
      int t = __shfl_up(v, off);
      if (lane >= off) v += t;
    }
    if (lane == 63) wsum[wv] = v;
    __syncthreads();
    int add = runv;
    for (int u = 0; u < wv; ++u) add += wsum[u];
    v += add;
    if (i <= NN) p[i] = v;
    __syncthreads();
    if (threadIdx.x == 255) runv = v;
    __syncthreads();
  }
}

// ---------------- cursor init ----------------
__global__ void k_curinit(float* __restrict__ ws) {
  int i = blockIdx.x * 256 + threadIdx.x;
  if (i >= NW * NN) return;
  int w = i / NN, n = i % NN;
  ((int*)ws)[IOFF_CUR + i] = ((int*)ws)[IOFF_PTR + w * (NN + 1) + n];
}

// ---------------- scatter edges into CSR records {src, et, dt, weight} ----------------
__global__ void k_scatter(const int* __restrict__ eidx, const int* __restrict__ etype,
                          const int* __restrict__ etime, const float* __restrict__ eweight,
                          float* __restrict__ ws) {
  int e = blockIdx.x * 256 + threadIdx.x, w = blockIdx.y;
  if (e >= NE) return;
  int* wsi = (int*)ws;
  int dst = eidx[(w * 2 + 1) * NE + e];
  int pos = atomicAdd(&wsi[IOFF_CUR + w * NN + dst], 1);
  float dt = (float)etime[w * NE + e] - (float)wsi[OFF_MINT];
  int4 rec;
  rec.x = eidx[(w * 2 + 0) * NE + e];
  rec.y = etype[w * NE + e];
  rec.z = __float_as_int(dt);
  rec.w = __float_as_int(eweight[w * NE + e]);
  ((int4*)(wsi + IOFF_REC))[(size_t)w * NE + pos] = rec;
}

// ---------------- rel = query @ rel_lin_w.T + b (written interleaved) ----------------
__global__ void k_rel(const float* __restrict__ rlw, const float* __restrict__ rlb,
                      float* __restrict__ ws) {
  int l = blockIdx.y;
  int rd = blockIdx.x * blockDim.x + threadIdx.x;
  const float4* wrow = (const float4*)(rlw + ((size_t)(l * NR * DD + rd)) * DD);
  float4 wreg[16];
#pragma unroll
  for (int kk = 0; kk < 16; ++kk) wreg[kk] = wrow[kk];
  float bias = rlb[l * NR * DD + rd];
  int r = rd >> 6, d = rd & 63;
  for (int b = 0; b < NB; ++b) {
    const float4* q4 = (const float4*)(ws + OFF_QUERY + b * DD);
    float acc = 0.f;
#pragma unroll
    for (int kk = 0; kk < 16; ++kk) {
      float4 q = q4[kk];
      acc += q.x * wreg[kk].x + q.y * wreg[kk].y + q.z * wreg[kk].z + q.w * wreg[kk].w;
    }
    ws[OFF_RELI + (size_t)(l * NR + r) * (NB * DD) + b * DD + d] = acc + bias;
  }
}

// ---------------- CSR gather aggregation: grid.y = w -------------------------------
// init0: flags[w][n][b] = row has nonzero agg/init; agg stored only when flagged.
__global__ __launch_bounds__(256) void k_agg(const float* __restrict__ xbase,
                                             const float* __restrict__ tw,
                                             const float* __restrict__ tb,
                                             float* __restrict__ ws, int l, int init0) {
  int w = blockIdx.y;
  int lane = threadIdx.x & 63;
  int wv = threadIdx.x >> 6;
  int n = blockIdx.x * 4 + wv;
  int b = lane >> 4;
  int q4i = lane & 15;
  const int* wsi = (const int*)ws;
  int p0 = __builtin_amdgcn_readfirstlane(wsi[IOFF_PTR + w * (NN + 1) + n]);
  int p1 = __builtin_amdgcn_readfirstlane(wsi[IOFF_PTR + w * (NN + 1) + n + 1]);
  const int4* recs = ((const int4*)(wsi + IOFF_REC)) + (size_t)w * NE;
  const float4* XI4 = (const float4*)(xbase + (size_t)w * XSZ);
  const float4* RELI4 = (const float4*)(ws + OFF_RELI) + (size_t)l * NR * 64;
  const float4* TW4 = (const float4*)(tw + (size_t)l * NR * DD);  // [NR][16] f4
  const float4* TB4 = (const float4*)(tb + (size_t)l * NR * DD);
  int h00 = wsi[OFF_H0 + 0], h01 = wsi[OFF_H0 + 1];
  int h02 = wsi[OFF_H0 + 2], h03 = wsi[OFF_H0 + 3];
  int h0b = wsi[OFF_H0 + b];
  float4 q4b = ((const float4*)(ws + OFF_QUERY))[lane];
  float4 acc;
  if (n == h0b) acc = q4b;
  else { acc.x = 0.f; acc.y = 0.f; acc.z = 0.f; acc.w = 0.f; }

  if (init0) {
    bool cb = (n == h0b);
    for (int j = p0; j < p1; ++j) {
      int4 rec = recs[j];
      int src = rec.x;
      if (!((src == h00) | (src == h01) | (src == h02) | (src == h03))) continue;
      cb |= (src == h0b);
      int et = rec.y;
      float dtf = __int_as_float(rec.z);
      float m = (src == h0b) ? __int_as_float(rec.w) : 0.f;
      float4 r4 = RELI4[et * 64 + lane];
      float4 w4 = TW4[et * 16 + q4i];
      float4 b4 = TB4[et * 16 + q4i];
      acc.x = fmaf(q4b.x * r4.x, __cosf(fmaf(dtf, w4.x, b4.x)) * m, acc.x);
      acc.y = fmaf(q4b.y * r4.y, __cosf(fmaf(dtf, w4.y, b4.y)) * m, acc.y);
      acc.z = fmaf(q4b.z * r4.z, __cosf(fmaf(dtf, w4.z, b4.z)) * m, acc.z);
      acc.w = fmaf(q4b.w * r4.w, __cosf(fmaf(dtf, w4.w, b4.w)) * m, acc.w);
    }
    // per-(w,n,b) flag byte (always written -> deterministic)
    char* flg = (char*)(wsi + IOFF_FLG);
    if (q4i == 0) flg[((size_t)w * NN + n) * 4 + b] = cb ? 1 : 0;
    if (cb)
      ((float4*)(ws + OFF_AGG + (size_t)w * XSZ))[(size_t)n * 64 + lane] = acc;
    return;
  }
#define EDGE_BODY(J)                                                           \
    {                                                                          \
      int4 rec = recs[J];                                                      \
      int src = rec.x, et = rec.y;                                             \
      float dtf = __int_as_float(rec.z), wgt = __int_as_float(rec.w);          \
      float4 x4 = XI4[(size_t)src * 64 + lane];                                \
      float4 r4 = RELI4[et * 64 + lane];                                       \
      float4 w4 = TW4[et * 16 + q4i];                                          \
      float4 b4 = TB4[et * 16 + q4i];                                          \
      acc.x = fmaf(x4.x * r4.x, __cosf(fmaf(dtf, w4.x, b4.x)) * wgt, acc.x);   \
      acc.y = fmaf(x4.y * r4.y, __cosf(fmaf(dtf, w4.y, b4.y)) * wgt, acc.y);   \
      acc.z = fmaf(x4.z * r4.z, __cosf(fmaf(dtf, w4.z, b4.z)) * wgt, acc.z);   \
      acc.w = fmaf(x4.w * r4.w, __cosf(fmaf(dtf, w4.w, b4.w)) * wgt, acc.w);   \
    }
  {
    int j = p0;
    for (; j + 1 < p1; j += 2) {
      EDGE_BODY(j);
      EDGE_BODY(j + 1);
    }
    if (j < p1) EDGE_BODY(j);
  }
#undef EDGE_BODY
  ((float4*)(ws + OFF_AGG + (size_t)w * XSZ))[(size_t)n * 64 + lane] = acc;
}

// ---------------- node GEMM + LN + residual; LDS-staged rows; grid.y = w --------------
__global__ __launch_bounds__(256) void k_gemm(const float* __restrict__ linb,
                                              const float* __restrict__ lns,
                                              const float* __restrict__ lnb,
                                              const float* __restrict__ xbase,
                                              float* __restrict__ xdstbase,
                                              const float* __restrict__ ws, int l,
                                              int init0) {
  __shared__ float4 xs4[64 * 16];
  __shared__ float4 as4[64 * 16];
  int w = blockIdx.y;
  int tid = threadIdx.x;
  const float* xsrc = xbase + (size_t)w * XSZ;
  float* xdst = xdstbase + (size_t)w * XSZ;
  int rowblk = blockIdx.x * 64;
  if (!init0) {
    const float4* xr = (const float4*)xsrc + (size_t)rowblk * 16;
    const float4* arr =
        (const float4*)(ws + OFF_AGG + (size_t)w * XSZ) + (size_t)rowblk * 16;
#pragma unroll
    for (int u = 0; u < 4; ++u) xs4[tid + 256 * u] = xr[tid + 256 * u];
#pragma unroll
    for (int u = 0; u < 4; ++u) as4[tid + 256 * u] = arr[tid + 256 * u];
    __syncthreads();
  }
  int wv = __builtin_amdgcn_readfirstlane(tid >> 6);
  int c = tid & 63;
  int lr0 = wv * 16;
  int row0 = rowblk + lr0;
  const int* wsi = (const int*)ws;

  if (init0) {
    // flags for this wave's 16 rows (row-indexed byte array)
    const unsigned char* flg =
        (const unsigned char*)(wsi + IOFF_FLG) + (size_t)w * NN * 4;
    uint4 fw = *(const uint4*)(flg + row0);
    float yc = ws[OFF_YC + c];
    if ((fw.x | fw.y | fw.z | fw.w) == 0u) {
#pragma unroll
      for (int r = 0; r < 16; ++r) xdst[(size_t)(row0 + r) * DD + c] = yc;
      return;
    }
    const unsigned char* fb = (const unsigned char*)&fw;
    const float4* ar =
        (const float4*)(ws + OFF_AGG + (size_t)w * XSZ) + (size_t)row0 * 16;
    const float* WT = ws + OFF_LINT;  // l = 0
    float sc = lns[c], bc = lnb[c];
#pragma unroll 1
    for (int r = 0; r < 16; ++r) {
      if (!fb[r]) {
        xdst[(size_t)(row0 + r) * DD + c] = yc;
        continue;
      }
      int nr = (row0 + r) >> 2, br = (row0 + r) & 3;
      int h0b = wsi[OFF_H0 + br];
      float a = linb[c];
      if (nr == h0b) {
        const float4* q4 = (const float4*)(ws + OFF_QUERY + br * DD);
        for (int kk = 0; kk < 16; ++kk) {
          float4 qv = q4[kk];
          a = fmaf(qv.x, WT[(4 * kk + 0) * DD + c], a);
          a = fmaf(qv.y, WT[(4 * kk + 1) * DD + c], a);
          a = fmaf(qv.z, WT[(4 * kk + 2) * DD + c], a);
          a = fmaf(qv.w, WT[(4 * kk + 3) * DD + c], a);
        }
      }
      for (int kk = 0; kk < 16; ++kk) {
        float4 av = ar[r * 16 + kk];
        a = fmaf(av.x, WT[(64 + 4 * kk + 0) * DD + c], a);
        a = fmaf(av.y, WT[(64 + 4 * kk + 1) * DD + c], a);
        a = fmaf(av.z, WT[(64 + 4 * kk + 2) * DD + c], a);
        a = fmaf(av.w, WT[(64 + 4 * kk + 3) * DD + c], a);
      }
      float s = a;
      for (int m = 1; m < 64; m <<= 1) s += __shfl_xor(s, m);
      float mean = s * (1.f / 64.f);
      float cv = a - mean;
      float vv = cv * cv;
      for (int m = 1; m < 64; m <<= 1) vv += __shfl_xor(vv, m);
      vv *= (1.f / 64.f);
      float y = cv * __frsqrt_rn(vv + LN_EPS) * sc + bc;
      y = fmaxf(y, 0.f);
      float xo = (nr == h0b) ? ws[OFF_QUERY + br * DD + c] : 0.f;
      xdst[(size_t)(row0 + r) * DD + c] = xo + y;
    }
    return;
  }

  const float* WT = ws + OFF_LINT + l * 2 * DD * DD;  // [128][64]
  float bias = linb[l * DD + c];
  float acc[16];
#pragma unroll
  for (int r = 0; r < 16; ++r) acc[r] = bias;
  for (int kk = 0; kk < 16; ++kk) {
    float w0 = WT[(4 * kk + 0) * DD + c];
    float w1 = WT[(4 * kk + 1) * DD + c];
    float w2 = WT[(4 * kk + 2) * DD + c];
    float w3 = WT[(4 * kk + 3) * DD + c];
#pragma unroll
    for (int r = 0; r < 16; ++r) {
      float4 xv = xs4[(lr0 + r) * 16 + kk];
      acc[r] = fmaf(xv.x, w0, acc[r]);
      acc[r] = fmaf(xv.y, w1, acc[r]);
      acc[r] = fmaf(xv.z, w2, acc[r]);
      acc[r] = fmaf(xv.w, w3, acc[r]);
    }
  }
  for (int kk = 0; kk < 16; ++kk) {
    float w0 = WT[(64 + 4 * kk + 0) * DD + c];
    float w1 = WT[(64 + 4 * kk + 1) * DD + c];
    float w2 = WT[(64 + 4 * kk + 2) * DD + c];
    float w3 = WT[(64 + 4 * kk + 3) * DD + c];
#pragma unroll
    for (int r = 0; r < 16; ++r) {
      float4 av = as4[(lr0 + r) * 16 + kk];
      acc[r] = fmaf(av.x, w0, acc[r]);
      acc[r] = fmaf(av.y, w1, acc[r]);
      acc[r] = fmaf(av.z, w2, acc[r]);
      acc[r] = fmaf(av.w, w3, acc[r]);
    }
  }
  float sc = lns[l * DD + c], bc = lnb[l * DD + c];
#pragma unroll
  for (int r = 0; r < 16; ++r) {
    float v = acc[r];
    float s = v;
    for (int m = 1; m < 64; m <<= 1) s += __shfl_xor(s, m);
    float mean = s * (1.f / 64.f);
    float cv = v - mean;
    float vv = cv * cv;
    for (int m = 1; m < 64; m <<= 1) vv += __shfl_xor(vv, m);
    vv *= (1.f / 64.f);
    float y = cv * __frsqrt_rn(vv + LN_EPS) * sc + bc;
    y = fmaxf(y, 0.f);
    float xo = ((const float*)xs4)[(lr0 + r) * 64 + c];
    xdst[(size_t)(row0 + r) * DD + c] = xo + y;
  }
}

// ---------------- l=2 tail-only: agg + gemm + LN + residual + pe -> TOK ---------------
// grid (NNEG, NW), 4 waves = 4 batches; wave computes one (b, j, w) token row.
__global__ __launch_bounds__(256) void k_ltail(const float* __restrict__ xcur,
                                               const float* __restrict__ tw,
                                               const float* __restrict__ tb,
                                               const float* __restrict__ pe,
                                               const float* __restrict__ linb,
                                               const float* __restrict__ lns,
                                               const float* __restrict__ lnb,
                                               float* __restrict__ ws) {
  __shared__ float rowx[4][DD], rowa[4][DD];
  int b = threadIdx.x >> 6, d = threadIdx.x & 63;
  int j = blockIdx.x, w = blockIdx.y;
  const int* wsi = (const int*)ws;
  int t = wsi[OFF_TSW + b * NNEG + j];
  int h0b = wsi[OFF_H0 + b];
  int p0 = wsi[IOFF_PTR + w * (NN + 1) + t];
  int p1 = wsi[IOFF_PTR + w * (NN + 1) + t + 1];
  const int4* recs = ((const int4*)(wsi + IOFF_REC)) + (size_t)w * NE;
  const float* rell = ws + OFF_RELI + (size_t)2 * NR * NB * DD;
  const float* twl = tw + 2 * NR * DD;
  const float* tbl = tb + 2 * NR * DD;
  const float* xw = xcur + (size_t)w * XSZ;
  float acc = (t == h0b) ? ws[OFF_QUERY + b * DD + d] : 0.f;
  for (int e = p0; e < p1; ++e) {
    int4 rec = recs[e];
    int src = rec.x, et = rec.y;
    float dtf = __int_as_float(rec.z), wgt = __int_as_float(rec.w);
    float xv = xw[(size_t)src * (NB * DD) + b * DD + d];
    float rv = rell[(size_t)et * (NB * DD) + b * DD + d];
    float te = __cosf(fmaf(dtf, twl[et * DD + d], tbl[et * DD + d]));
    acc = fmaf(xv * rv, te * wgt, acc);
  }
  float xo = xw[(size_t)t * (NB * DD) + b * DD + d];
  rowa[b][d] = acc;
  rowx[b][d] = xo;  // intra-wave LDS handoff (compiler inserts lgkmcnt)
  int c = d;
  const float* WT = ws + OFF_LINT + 2 * 2 * DD * DD;  // l = 2
  float hid = linb[2 * DD + c];
#pragma unroll 8
  for (int k = 0; k < DD; ++k) hid = fmaf(rowx[b][k], WT[k * DD + c], hid);
#pragma unroll 8
  for (int k = 0; k < DD; ++k) hid = fmaf(rowa[b][k], WT[(DD + k) * DD + c], hid);
  float s = hid;
  for (int m = 1; m < 64; m <<= 1) s += __shfl_xor(s, m);
  float mean = s * (1.f / 64.f);
  float cv = hid - mean;
  float vv = cv * cv;
  for (int m = 1; m < 64; m <<= 1) vv += __shfl_xor(vv, m);
  vv *= (1.f / 64.f);
  float y = cv * __frsqrt_rn(vv + LN_EPS) * lns[2 * DD + c] + lnb[2 * DD + c];
  y = fmaxf(y, 0.f);
  ws[OFF_TOK + (b * NNEG + j) * NW * DD + w * DD + c] = xo + y + pe[w * DD + c];
}

// ---------------- transformer + final MLP: round-4 structure (best measured) ----------
__global__ __launch_bounds__(768) void k_xform(
    const float* __restrict__ wq, const float* __restrict__ wk,
    const float* __restrict__ wv, const float* __restrict__ wo,
    const float* __restrict__ ffw1, const float* __restrict__ ffb1,
    const float* __restrict__ ffw2, const float* __restrict__ ffb2,
    const float* __restrict__ fln1s, const float* __restrict__ fln1b,
    const float* __restrict__ fln2s, const float* __restrict__ fln2b,
    const float* __restrict__ m1w, const float* __restrict__ m1b,
    const float* __restrict__ m2w, const float* __restrict__ m2b,
    float* __restrict__ ws, float* __restrict__ out) {
  __shared__ float tok[RPB][NW][DD], kvb[RPB][NW][DD], vvb[RPB][NW][DD];
  __shared__ float hbuf[RPB][NW][NFFN];
  __shared__ float feat[RPB][2 * DD];
  __shared__ float red[RPB][2];
  __shared__ float4 wbuf4[4352];
  int tid = threadIdx.x;
  int rr = tid / 192;
  int t192 = tid - rr * 192;
  int tk = t192 >> 6, d = t192 & 63;
  int row = blockIdx.x * RPB + rr, b = row / NNEG;
  tok[rr][tk][d] = ws[OFF_TOK + row * NW * DD + tk * DD + d];
  for (int f = 0; f < NFL; ++f) {
    {
      const float4* s0 = (const float4*)(wq + (size_t)f * DD * DD);
      const float4* s1 = (const float4*)(wk + (size_t)f * DD * DD);
      const float4* s2 = (const float4*)(wv + (size_t)f * DD * DD);
      const float4* s3 = (const float4*)(wo + (size_t)f * DD * DD);
      for (int idx = tid; idx < 4096; idx += 768) {
        int m = idx >> 10, rem = idx & 1023;
        int rrow = rem >> 4, c4 = rem & 15;
        const float4* s = (m == 0) ? s0 : (m == 1) ? s1 : (m == 2) ? s2 : s3;
        wbuf4[(m * 64 + rrow) * 17 + c4] = s[rem];
      }
    }
    __syncthreads();
    float qd = 0.f, kd = 0.f, vd = 0.f;
#pragma unroll
    for (int kk = 0; kk < 16; ++kk) {
      float4 tv = *(const float4*)&tok[rr][tk][4 * kk];
      float4 aq = wbuf4[(0 * 64 + d) * 17 + kk];
      float4 ak = wbuf4[(1 * 64 + d) * 17 + kk];
      float4 av = wbuf4[(2 * 64 + d) * 17 + kk];
      qd += tv.x * aq.x + tv.y * aq.y + tv.z * aq.z + tv.w * aq.w;
      kd += tv.x * ak.x + tv.y * ak.y + tv.z * ak.z + tv.w * ak.w;
      vd += tv.x * av.x + tv.y * av.y + tv.z * av.z + tv.w * av.w;
    }
    kvb[rr][tk][d] = kd;
    vvb[rr][tk][d] = vd;
    __syncthreads();
    float sc[NW];
#pragma unroll
    for (int j = 0; j < NW; ++j) {
      float p = qd * kvb[rr][j][d];
      p += __shfl_xor(p, 1);
      p += __shfl_xor(p, 2);
      p += __shfl_xor(p, 4);
      p += __shfl_xor(p, 8);
      sc[j] = p * 0.25f;
    }
    float mx = fmaxf(sc[0], fmaxf(sc[1], sc[2]));
    float e0 = expf(sc[0] - mx), e1 = expf(sc[1] - mx), e2 = expf(sc[2] - mx);
    float inv = 1.f / (e0 + e1 + e2);
    float od = (e0 * vvb[rr][0][d] + e1 * vvb[rr][1][d] + e2 * vvb[rr][2][d]) * inv;
    __syncthreads();
    kvb[rr][tk][d] = od;
    float ao = 0.f;
#pragma unroll
    for (int kk = 0; kk < 16; ++kk) {
      float4 ov = *(const float4*)&kvb[rr][tk][4 * kk];
      float4 w4 = wbuf4[(3 * 64 + d) * 17 + kk];
      ao += ov.x * w4.x + ov.y * w4.y + ov.z * w4.z + ov.w * w4.w;
    }
    float t1 = tok[rr][tk][d] + ao;
    float s = t1;
    for (int m = 1; m < 64; m <<= 1) s += __shfl_xor(s, m);
    float mean = s * (1.f / 64.f);
    float cv = t1 - mean;
    float v = cv * cv;
    for (int m = 1; m < 64; m <<= 1) v += __shfl_xor(v, m);
    v *= (1.f / 64.f);
    t1 = cv * __frsqrt_rn(v + LN_EPS) * fln1s[f * DD + d] + fln1b[f * DD + d];
    tok[rr][tk][d] = t1;
    __syncthreads();
    {
      const float4* s4 = (const float4*)(ffw1 + (size_t)f * NFFN * DD);
      for (int idx = tid; idx < 4096; idx += 768) {
        int rrow = idx >> 4, c4 = idx & 15;
        wbuf4[rrow * 17 + c4] = s4[idx];
      }
    }
    __syncthreads();
    float h[4];
#pragma unroll
    for (int uu = 0; uu < 4; ++uu) h[uu] = ffb1[f * NFFN + d + 64 * uu];
#pragma unroll
    for (int kk = 0; kk < 16; ++kk) {
      float4 tv = *(const float4*)&tok[rr][tk][4 * kk];
      float4 w0 = wbuf4[(d + 0) * 17 + kk];
      float4 w1 = wbuf4[(d + 64) * 17 + kk];
      float4 w2 = wbuf4[(d + 128) * 17 + kk];
      float4 w3 = wbuf4[(d + 192) * 17 + kk];
      h[0] += tv.x * w0.x + tv.y * w0.y + tv.z * w0.z + tv.w * w0.w;
      h[1] += tv.x * w1.x + tv.y * w1.y + tv.z * w1.z + tv.w * w1.w;
      h[2] += tv.x * w2.x + tv.y * w2.y + tv.z * w2.z + tv.w * w2.w;
      h[3] += tv.x * w3.x + tv.y * w3.y + tv.z * w3.z + tv.w * w3.w;
    }
#pragma unroll
    for (int uu = 0; uu < 4; ++uu) hbuf[rr][tk][d + 64 * uu] = fmaxf(h[uu], 0.f);
    __syncthreads();
    {
      const float4* s4 = (const float4*)(ffw2 + (size_t)f * DD * NFFN);
      for (int idx = tid; idx < 4096; idx += 768) {
        int rrow = idx >> 6, c4 = idx & 63;
        wbuf4[rrow * 65 + c4] = s4[idx];
      }
    }
    __syncthreads();
    float ff = ffb2[f * DD + d];
#pragma unroll 8
    for (int kk = 0; kk < 64; ++kk) {
      float4 hv = *(const float4*)&hbuf[rr][tk][4 * kk];
      float4 w4 = wbuf4[d * 65 + kk];
      ff += hv.x * w4.x + hv.y * w4.y + hv.z * w4.z + hv.w * w4.w;
    }
    float t2 = t1 + ff;
    s = t2;
    for (int m = 1; m < 64; m <<= 1) s += __shfl_xor(s, m);
    mean = s * (1.f / 64.f);
    cv = t2 - mean;
    v = cv * cv;
    for (int m = 1; m < 64; m <<= 1) v += __shfl_xor(v, m);
    v *= (1.f / 64.f);
    t2 = cv * __frsqrt_rn(v + LN_EPS) * fln2s[f * DD + d] + fln2b[f * DD + d];
    tok[rr][tk][d] = t2;
    __syncthreads();
  }
  if (tk == 2) {
    feat[rr][d] = tok[rr][2][d];
    feat[rr][DD + d] = ws[OFF_QUERY + b * DD + d];
  }
  {
    const float4* s4 = (const float4*)m1w;
    for (int idx = tid; idx < 4096; idx += 768) {
      int rrow = idx >> 5, c4 = idx & 31;
      wbuf4[rrow * 33 + c4] = s4[idx];
    }
  }
  __syncthreads();
  float partial = 0.f;
  if (t192 < 2 * DD) {
    int hh = t192;
    float acc = m1b[hh];
#pragma unroll
    for (int kk = 0; kk < 32; ++kk) {
      float4 fv = *(const float4*)&feat[rr][4 * kk];
      float4 w4 = wbuf4[hh * 33 + kk];
      acc += fv.x * w4.x + fv.y * w4.y + fv.z * w4.z + fv.w * w4.w;
    }
    acc = fmaxf(acc, 0.f);
    partial = acc * m2w[hh];
  }
  for (int m = 1; m < 64; m <<= 1) partial += __shfl_xor(partial, m);
  if (d == 0 && tk < 2) red[rr][tk] = partial;
  __syncthreads();
  if (t192 == 0) out[row] = red[rr][0] + red[rr][1] + m2b[0];
}

extern "C" void kernel_launch(void* const* d_in, const int* in_sizes, int n_in,
                              void* d_out, int out_size, void* d_ws, size_t ws_size,
                              hipStream_t stream) {
  const int* qt = (const int*)d_in[0];
  const int* eidx = (const int*)d_in[1];
  const int* etype = (const int*)d_in[2];
  const int* etime = (const int*)d_in[3];
  const float* qemb = (const float*)d_in[4];
  const float* ew = (const float*)d_in[5];
  const float* rlw = (const float*)d_in[6];
  const float* rlb = (const float*)d_in[7];
  const float* tw = (const float*)d_in[8];
  const float* tb = (const float*)d_in[9];
  const float* linw = (const float*)d_in[10];
  const float* linb = (const float*)d_in[11];
  const float* lns = (const float*)d_in[12];
  const float* lnb = (const float*)d_in[13];
  const float* pe = (const float*)d_in[14];
  const float* wq = (const float*)d_in[15];
  const float* wk = (const float*)d_in[16];
  const float* wv = (const float*)d_in[17];
  const float* wo = (const float*)d_in[18];
  const float* ffw1 = (const float*)d_in[19];
  const float* ffb1 = (const float*)d_in[20];
  const float* ffw2 = (const float*)d_in[21];
  const float* ffb2 = (const float*)d_in[22];
  const float* fln1s = (const float*)d_in[23];
  const float* fln1b = (const float*)d_in[24];
  const float* fln2s = (const float*)d_in[25];
  const float* fln2b = (const float*)d_in[26];
  const float* m1w = (const float*)d_in[27];
  const float* m1b = (const float*)d_in[28];
  const float* m2w = (const float*)d_in[29];
  const float* m2b = (const float*)d_in[30];
  float* ws = (float*)d_ws;
  float* out = (float*)d_out;

  k_prep<<<1, 256, 0, stream>>>(qt, qemb, ws);
  k_mint<<<(NE + 255) / 256, 256, 0, stream>>>(etime, ws);
  k_zero_ptr<<<(NW * (NN + 1) + 255) / 256, 256, 0, stream>>>(ws);
  k_yconst<<<1, 64, 0, stream>>>(linb, lns, lnb, ws);
  k_transpose<<<(NL * 2 * DD * DD + 255) / 256, 256, 0, stream>>>(linw, ws);
  k_rel<<<dim3(NR * DD / 256, NL), 256, 0, stream>>>(rlw, rlb, ws);
  k_hist<<<dim3((NE + 255) / 256, NW), 256, 0, stream>>>(eidx, ws);
  k_scan<<<NW, 256, 0, stream>>>(ws);
  k_curinit<<<(NW * NN + 255) / 256, 256, 0, stream>>>(ws);
  k_scatter<<<dim3((NE + 255) / 256, NW), 256, 0, stream>>>(eidx, etype, etime, ew, ws);

  // l = 0,1 full-grid (l=0 sparse-flagged); l = 2 tail-only
  float* cur = ws + OFF_X;
  float* nxt = ws + OFF_X2;
  for (int l = 0; l < 2; ++l) {
    int init0 = (l == 0) ? 1 : 0;
    k_agg<<<dim3(NN / 4, NW), 256, 0, stream>>>(cur, tw, tb, ws, l, init0);
    k_gemm<<<dim3(NB * NN / 64, NW), 256, 0, stream>>>(linb, lns, lnb, cur, nxt, ws, l,
                                                       init0);
    float* t = cur; cur = nxt; nxt = t;
  }
  k_ltail<<<dim3(NNEG, NW), 256, 0, stream>>>(cur, tw, tb, pe, linb, lns, lnb, ws);
  k_xform<<<NB * NNEG / RPB, 768, 0, stream>>>(wq, wk, wv, wo, ffw1, ffb1, ffw2, ffb2,
                                                fln1s, fln1b, fln2s, fln2b, m1w, m1b, m2w,
                                                m2b, ws, out);
}

// Round 12
// 271.883 us; speedup vs baseline: 4.5392x; 1.1858x over previous
//
#include <hip/hip_runtime.h>
#include <hip/hip_bf16.h>
#include <cmath>

#define NB 4
#define NNEG 33
#define NN 10000
#define NE 100000
#define NW 3
#define DD 64
#define NL 3
#define NR 200
#define NFL 2
#define NFFN 256
#define LN_EPS 1e-5f
#define RPB 4
#define XSZ (NB*NN*DD)

// ---- ws layout (float offsets) ----
#define OFF_QUERY 0
#define OFF_H0    256
#define OFF_TSW   288
#define OFF_MINT  448
#define OFF_RELI  512                                 // NL*NR*NB*DD
#define OFF_LINT  (OFF_RELI + NL*NR*NB*DD)            // NL*2*DD*DD
#define OFF_X     (OFF_LINT + NL*2*DD*DD)             // NW*XSZ (x1, sparse-valid)
#define OFF_X2    (OFF_X + NW*XSZ)                    // NW*XSZ (x2, needed-valid)
#define OFF_AGG   (OFF_X2 + NW*XSZ)                   // NW*XSZ
#define OFF_TOK   (OFF_AGG + NW*XSZ)                  // NB*NNEG*NW*DD
#define OFF_YC    (OFF_TOK + NB*NNEG*NW*DD)           // 64 yc + 64 hcx
// int offsets
#define IOFF_PTR  (OFF_YC + 128)                      // NW*(NN+1)
#define IOFF_CUR  (IOFF_PTR + NW*(NN+1))              // NW*NN
#define IOFF_REC  ((IOFF_CUR + NW*NN + 3) & ~3)       // NW*NE*4, 16B aligned
#define IOFF_FLG  (IOFF_REC + NW*NE*4)                // NW*NN ints (byte per (n,b))
#define IOFF_NEED (IOFF_FLG + NW*NN)                  // NW*NN ints (byte per (n,b))

// ---------------- prep ----------------
__global__ void k_prep(const int* __restrict__ qt, const float* __restrict__ qemb,
                       float* __restrict__ ws) {
  int tid = threadIdx.x;
  if (tid < NB * DD) {
    int b = tid / DD, d = tid % DD;
    int h0 = qt[(b * NNEG + 0) * 3 + 0];
    bool itn = true;
    for (int j = 1; j < NNEG; ++j) itn = itn && (qt[(b * NNEG + j) * 3 + 0] == h0);
    int r0 = qt[(b * NNEG + 0) * 3 + 1] + (itn ? 0 : NR / 2);
    ws[OFF_QUERY + b * DD + d] = qemb[r0 * DD + d];
    if (d == 0) {
      int t0 = qt[(b * NNEG + 0) * 3 + 2];
      ((int*)ws)[OFF_H0 + b] = itn ? h0 : t0;
    }
  }
  if (tid < NB * NNEG) {
    int b = tid / NNEG, j = tid % NNEG;
    int h0 = qt[(b * NNEG + 0) * 3 + 0];
    bool itn = true;
    for (int jj = 1; jj < NNEG; ++jj) itn = itn && (qt[(b * NNEG + jj) * 3 + 0] == h0);
    int h = qt[(b * NNEG + j) * 3 + 0], t = qt[(b * NNEG + j) * 3 + 2];
    ((int*)ws)[OFF_TSW + tid] = itn ? t : h;
  }
  if (tid == 0) ((int*)ws)[OFF_MINT] = 0x7fffffff;
}

// ---------------- min over edge_time[0] ----------------
__global__ void k_mint(const int* __restrict__ etime, float* __restrict__ ws) {
  int i = blockIdx.x * blockDim.x + threadIdx.x;
  int v = (i < NE) ? etime[i] : 0x7fffffff;
  for (int m = 1; m < 64; m <<= 1) v = min(v, __shfl_xor(v, m));
  if ((threadIdx.x & 63) == 0) atomicMin(&((int*)ws)[OFF_MINT], v);
}

// ---------------- zero ptr + need arrays ----------------
__global__ void k_zero_ptr(float* __restrict__ ws) {
  int i = blockIdx.x * 256 + threadIdx.x;
  if (i < NW * (NN + 1)) ((int*)ws)[IOFF_PTR + i] = 0;
  if (i < NW * NN) ((int*)ws)[IOFF_NEED + i] = 0;
}

// ---------------- transpose lin_w: linT[l][k][c] = lin_w[l][c][k] ----------------
__global__ void k_transpose(const float* __restrict__ lin_w, float* __restrict__ ws) {
  int idx = blockIdx.x * blockDim.x + threadIdx.x;
  if (idx < NL * 2 * DD * DD) {
    int l = idx / (2 * DD * DD), r = idx % (2 * DD * DD), k = r / DD, c = r % DD;
    ws[OFF_LINT + idx] = lin_w[(l * DD + c) * 2 * DD + k];
  }
}

// ---------------- yconst (l0 generic row) + hcx = dot(yc, Wx_l1) ----------------
__global__ void k_yconst(const float* __restrict__ linb, const float* __restrict__ lns,
                         const float* __restrict__ lnb, float* __restrict__ ws) {
  int d = threadIdx.x;  // 64 threads, 1 wave
  float v = linb[d];    // l = 0 bias
  float s = v;
  for (int m = 1; m < 64; m <<= 1) s += __shfl_xor(s, m);
  float mean = s * (1.f / 64.f);
  float cv = v - mean;
  float vv = cv * cv;
  for (int m = 1; m < 64; m <<= 1) vv += __shfl_xor(vv, m);
  vv *= (1.f / 64.f);
  float y = cv * __frsqrt_rn(vv + LN_EPS) * lns[d] + lnb[d];
  y = fmaxf(y, 0.f);
  ws[OFF_YC + d] = y;
  const float* WT1 = ws + OFF_LINT + 2 * DD * DD;  // l = 1, x-half
  float acc = 0.f;
  for (int k = 0; k < 64; ++k) {
    float yk = __shfl(y, k);
    acc = fmaf(yk, WT1[k * DD + d], acc);
  }
  ws[OFF_YC + 64 + d] = acc;
}

// ---------------- histogram of dst ----------------
__global__ void k_hist(const int* __restrict__ eidx, float* __restrict__ ws) {
  int e = blockIdx.x * 256 + threadIdx.x, w = blockIdx.y;
  if (e >= NE) return;
  int dst = eidx[(w * 2 + 1) * NE + e];
  atomicAdd(&((int*)ws)[IOFF_PTR + w * (NN + 1) + dst + 1], 1);
}

// ---------------- inclusive scan -> ptr ----------------
__global__ void k_scan(float* __restrict__ ws) {
  int w = blockIdx.x;
  int* p = (int*)ws + IOFF_PTR + w * (NN + 1);
  __shared__ int wsum[4];
  __shared__ int runv;
  if (threadIdx.x == 0) runv = 0;
  __syncthreads();
  int lane = threadIdx.x & 63, wv = threadIdx.x >> 6;
  for (int base = 0; base < NN + 1; base += 256) {
    int i = base + threadIdx.x;
    int v = (i <= NN) ? p[i] : 0;
    for (int off = 1; off < 64; off <<= 1) {
      int t = __shfl_up(v, off);
      if (lane >= off) v += t;
    }
    if (lane == 63) wsum[wv] = v;
    __syncthreads();
    int add = runv;
    for (int u = 0; u < wv; ++u) add += wsum[u];
    v += add;
    if (i <= NN) p[i] = v;
    __syncthreads();
    if (threadIdx.x == 255) runv = v;
    __syncthreads();
  }
}

// ---------------- cursor init ----------------
__global__ void k_curinit(float* __restrict__ ws) {
  int i = blockIdx.x * 256 + threadIdx.x;
  if (i >= NW * NN) return;
  int w = i / NN, n = i % NN;
  ((int*)ws)[IOFF_CUR + i] = ((int*)ws)[IOFF_PTR + w * (NN + 1) + n];
}

// ---------------- scatter edges into CSR records ----------------
__global__ void k_scatter(const int* __restrict__ eidx, const int* __restrict__ etype,
                          const int* __restrict__ etime, const float* __restrict__ eweight,
                          float* __restrict__ ws) {
  int e = blockIdx.x * 256 + threadIdx.x, w = blockIdx.y;
  if (e >= NE) return;
  int* wsi = (int*)ws;
  int dst = eidx[(w * 2 + 1) * NE + e];
  int pos = atomicAdd(&wsi[IOFF_CUR + w * NN + dst], 1);
  float dt = (float)etime[w * NE + e] - (float)wsi[OFF_MINT];
  int4 rec;
  rec.x = eidx[(w * 2 + 0) * NE + e];
  rec.y = etype[w * NE + e];
  rec.z = __float_as_int(dt);
  rec.w = __float_as_int(eweight[w * NE + e]);
  ((int4*)(wsi + IOFF_REC))[(size_t)w * NE + pos] = rec;
}

// ---------------- need bitmap: tails + their in-edge srcs ----------------
__global__ void k_need(float* __restrict__ ws) {
  int j = blockIdx.x, w = blockIdx.y;
  int b = threadIdx.x >> 6, lane = threadIdx.x & 63;
  const int* wsi = (const int*)ws;
  int t = wsi[OFF_TSW + b * NNEG + j];
  unsigned char* need = (unsigned char*)((int*)ws + IOFF_NEED) + (size_t)w * NN * 4;
  if (lane == 0) need[(size_t)t * 4 + b] = 1;
  int p0 = wsi[IOFF_PTR + w * (NN + 1) + t];
  int p1 = wsi[IOFF_PTR + w * (NN + 1) + t + 1];
  const int4* recs = ((const int4*)(wsi + IOFF_REC)) + (size_t)w * NE;
  for (int e = p0 + lane; e < p1; e += 64) {
    int src = recs[e].x;
    need[(size_t)src * 4 + b] = 1;
  }
}

// ---------------- rel = query @ rel_lin_w.T + b (interleaved) ----------------
__global__ void k_rel(const float* __restrict__ rlw, const float* __restrict__ rlb,
                      float* __restrict__ ws) {
  int l = blockIdx.y;
  int rd = blockIdx.x * blockDim.x + threadIdx.x;
  const float4* wrow = (const float4*)(rlw + ((size_t)(l * NR * DD + rd)) * DD);
  float4 wreg[16];
#pragma unroll
  for (int kk = 0; kk < 16; ++kk) wreg[kk] = wrow[kk];
  float bias = rlb[l * NR * DD + rd];
  int r = rd >> 6, d = rd & 63;
  for (int b = 0; b < NB; ++b) {
    const float4* q4 = (const float4*)(ws + OFF_QUERY + b * DD);
    float acc = 0.f;
#pragma unroll
    for (int kk = 0; kk < 16; ++kk) {
      float4 q = q4[kk];
      acc += q.x * wreg[kk].x + q.y * wreg[kk].y + q.z * wreg[kk].z + q.w * wreg[kk].w;
    }
    ws[OFF_RELI + (size_t)(l * NR + r) * (NB * DD) + b * DD + d] = acc + bias;
  }
}

// ---------------- l0 aggregation: flag-producing sparse scan ----------------
__global__ __launch_bounds__(256) void k_agg0(const float* __restrict__ tw,
                                              const float* __restrict__ tb,
                                              float* __restrict__ ws) {
  int w = blockIdx.y;
  int lane = threadIdx.x & 63;
  int wv = threadIdx.x >> 6;
  int n = blockIdx.x * 4 + wv;
  int b = lane >> 4;
  int q4i = lane & 15;
  const int* wsi = (const int*)ws;
  int p0 = __builtin_amdgcn_readfirstlane(wsi[IOFF_PTR + w * (NN + 1) + n]);
  int p1 = __builtin_amdgcn_readfirstlane(wsi[IOFF_PTR + w * (NN + 1) + n + 1]);
  const int4* recs = ((const int4*)(wsi + IOFF_REC)) + (size_t)w * NE;
  const float4* RELI4 = (const float4*)(ws + OFF_RELI);  // l = 0
  const float4* TW4 = (const float4*)tw;
  const float4* TB4 = (const float4*)tb;
  int h00 = wsi[OFF_H0 + 0], h01 = wsi[OFF_H0 + 1];
  int h02 = wsi[OFF_H0 + 2], h03 = wsi[OFF_H0 + 3];
  int h0b = wsi[OFF_H0 + b];
  float4 q4b = ((const float4*)(ws + OFF_QUERY))[lane];
  float4 acc;
  if (n == h0b) acc = q4b;
  else { acc.x = 0.f; acc.y = 0.f; acc.z = 0.f; acc.w = 0.f; }
  bool cb = (n == h0b);
  for (int j = p0; j < p1; ++j) {
    int4 rec = recs[j];
    int src = rec.x;
    if (!((src == h00) | (src == h01) | (src == h02) | (src == h03))) continue;
    cb |= (src == h0b);
    int et = rec.y;
    float dtf = __int_as_float(rec.z);
    float m = (src == h0b) ? __int_as_float(rec.w) : 0.f;
    float4 r4 = RELI4[et * 64 + lane];
    float4 w4 = TW4[et * 16 + q4i];
    float4 b4 = TB4[et * 16 + q4i];
    acc.x = fmaf(q4b.x * r4.x, __cosf(fmaf(dtf, w4.x, b4.x)) * m, acc.x);
    acc.y = fmaf(q4b.y * r4.y, __cosf(fmaf(dtf, w4.y, b4.y)) * m, acc.y);
    acc.z = fmaf(q4b.z * r4.z, __cosf(fmaf(dtf, w4.z, b4.z)) * m, acc.z);
    acc.w = fmaf(q4b.w * r4.w, __cosf(fmaf(dtf, w4.w, b4.w)) * m, acc.w);
  }
  char* flg = (char*)(wsi + IOFF_FLG);
  if (q4i == 0) flg[((size_t)w * NN + n) * 4 + b] = cb ? 1 : 0;
  if (cb)
    ((float4*)(ws + OFF_AGG + (size_t)w * XSZ))[(size_t)n * 64 + lane] = acc;
}

// ---------------- l0 gemm: flagged rows only -> X1 ----------------
__global__ __launch_bounds__(256) void k_gemm0(const float* __restrict__ linb,
                                               const float* __restrict__ lns,
                                               const float* __restrict__ lnb,
                                               float* __restrict__ ws) {
  int w = blockIdx.y;
  int tid = threadIdx.x;
  int wv = __builtin_amdgcn_readfirstlane(tid >> 6);
  int c = tid & 63;
  int row0 = blockIdx.x * 64 + wv * 16;
  const int* wsi = (const int*)ws;
  const unsigned char* fb = (const unsigned char*)(wsi + IOFF_FLG) + (size_t)w * NN * 4;
  uint4 fw = *(const uint4*)(fb + row0);
  if ((fw.x | fw.y | fw.z | fw.w) == 0u) return;
  const unsigned char* fbb = (const unsigned char*)&fw;
  float* xdst = ws + OFF_X + (size_t)w * XSZ;
  const float4* ar = (const float4*)(ws + OFF_AGG + (size_t)w * XSZ) + (size_t)row0 * 16;
  const float* WT = ws + OFF_LINT;  // l = 0
  float sc = lns[c], bc = lnb[c];
#pragma unroll 1
  for (int r = 0; r < 16; ++r) {
    if (!fbb[r]) continue;
    int nr = (row0 + r) >> 2, br = (row0 + r) & 3;
    int h0b = wsi[OFF_H0 + br];
    float a = linb[c];
    if (nr == h0b) {
      const float4* q4 = (const float4*)(ws + OFF_QUERY + br * DD);
      for (int kk = 0; kk < 16; ++kk) {
        float4 qv = q4[kk];
        a = fmaf(qv.x, WT[(4 * kk + 0) * DD + c], a);
        a = fmaf(qv.y, WT[(4 * kk + 1) * DD + c], a);
        a = fmaf(qv.z, WT[(4 * kk + 2) * DD + c], a);
        a = fmaf(qv.w, WT[(4 * kk + 3) * DD + c], a);
      }
    }
    for (int kk = 0; kk < 16; ++kk) {
      float4 av = ar[r * 16 + kk];
      a = fmaf(av.x, WT[(64 + 4 * kk + 0) * DD + c], a);
      a = fmaf(av.y, WT[(64 + 4 * kk + 1) * DD + c], a);
      a = fmaf(av.z, WT[(64 + 4 * kk + 2) * DD + c], a);
      a = fmaf(av.w, WT[(64 + 4 * kk + 3) * DD + c], a);
    }
    float s = a;
    for (int m = 1; m < 64; m <<= 1) s += __shfl_xor(s, m);
    float mean = s * (1.f / 64.f);
    float cv = a - mean;
    float vv = cv * cv;
    for (int m = 1; m < 64; m <<= 1) vv += __shfl_xor(vv, m);
    vv *= (1.f / 64.f);
    float y = cv * __frsqrt_rn(vv + LN_EPS) * sc + bc;
    y = fmaxf(y, 0.f);
    float xo = (nr == h0b) ? ws[OFF_QUERY + br * DD + c] : 0.f;
    xdst[(size_t)(row0 + r) * DD + c] = xo + y;
  }
}

// ---------------- l1 aggregation: needed nodes only, flag-guarded x reads ------------
__global__ __launch_bounds__(256) void k_agg1(const float* __restrict__ tw,
                                              const float* __restrict__ tb,
                                              float* __restrict__ ws) {
  int w = blockIdx.y;
  int lane = threadIdx.x & 63;
  int wv = threadIdx.x >> 6;
  int n = blockIdx.x * 4 + wv;
  int b = lane >> 4;
  int q4i = lane & 15;
  const int* wsi = (const int*)ws;
  unsigned int needw =
      ((const unsigned int*)(wsi + IOFF_NEED))[(size_t)w * NN + n];
  if (needw == 0u) return;
  int p0 = __builtin_amdgcn_readfirstlane(wsi[IOFF_PTR + w * (NN + 1) + n]);
  int p1 = __builtin_amdgcn_readfirstlane(wsi[IOFF_PTR + w * (NN + 1) + n + 1]);
  const int4* recs = ((const int4*)(wsi + IOFF_REC)) + (size_t)w * NE;
  const float4* X14 = (const float4*)(ws + OFF_X + (size_t)w * XSZ);
  const float4* RELI4 = (const float4*)(ws + OFF_RELI) + (size_t)1 * NR * 64;
  const float4* TW4 = (const float4*)(tw + (size_t)1 * NR * DD);
  const float4* TB4 = (const float4*)(tb + (size_t)1 * NR * DD);
  const unsigned int* xflg = (const unsigned int*)(wsi + IOFF_FLG) + (size_t)w * NN;
  int h0b = wsi[OFF_H0 + b];
  float4 q4b = ((const float4*)(ws + OFF_QUERY))[lane];
  float4 yc4 = ((const float4*)(ws + OFF_YC))[q4i];
  float4 acc;
  if (n == h0b) acc = q4b;
  else { acc.x = 0.f; acc.y = 0.f; acc.z = 0.f; acc.w = 0.f; }
  for (int j = p0; j < p1; ++j) {
    int4 rec = recs[j];
    int src = rec.x, et = rec.y;
    float dtf = __int_as_float(rec.z), wgt = __int_as_float(rec.w);
    unsigned int fw = xflg[src];
    float4 x4;
    if (fw == 0u) {
      x4 = yc4;
    } else {
      int myf = (fw >> (b * 8)) & 0xff;
      if (myf) x4 = X14[(size_t)src * 64 + lane];
      else x4 = yc4;
    }
    float4 r4 = RELI4[et * 64 + lane];
    float4 w4 = TW4[et * 16 + q4i];
    float4 b4 = TB4[et * 16 + q4i];
    acc.x = fmaf(x4.x * r4.x, __cosf(fmaf(dtf, w4.x, b4.x)) * wgt, acc.x);
    acc.y = fmaf(x4.y * r4.y, __cosf(fmaf(dtf, w4.y, b4.y)) * wgt, acc.y);
    acc.z = fmaf(x4.z * r4.z, __cosf(fmaf(dtf, w4.z, b4.z)) * wgt, acc.z);
    acc.w = fmaf(x4.w * r4.w, __cosf(fmaf(dtf, w4.w, b4.w)) * wgt, acc.w);
  }
  ((float4*)(ws + OFF_AGG + (size_t)w * XSZ))[(size_t)n * 64 + lane] = acc;
}

// ---------------- l1 gemm: needed rows only -> X2 ----------------
__global__ __launch_bounds__(256) void k_gemm1(const float* __restrict__ linb,
                                               const float* __restrict__ lns,
                                               const float* __restrict__ lnb,
                                               float* __restrict__ ws) {
  int w = blockIdx.y;
  int tid = threadIdx.x;
  int wv = __builtin_amdgcn_readfirstlane(tid >> 6);
  int c = tid & 63;
  int row0 = blockIdx.x * 64 + wv * 16;
  const int* wsi = (const int*)ws;
  const unsigned char* nb = (const unsigned char*)(wsi + IOFF_NEED) + (size_t)w * NN * 4;
  uint4 nw4 = *(const uint4*)(nb + row0);
  if ((nw4.x | nw4.y | nw4.z | nw4.w) == 0u) return;
  const unsigned char* nbb = (const unsigned char*)&nw4;
  const unsigned char* fb = (const unsigned char*)(wsi + IOFF_FLG) + (size_t)w * NN * 4;
  const float* WT = ws + OFF_LINT + 2 * DD * DD;  // l = 1
  const float* X1 = ws + OFF_X + (size_t)w * XSZ;
  const float* AG = ws + OFF_AGG + (size_t)w * XSZ;
  float* X2 = ws + OFF_X2 + (size_t)w * XSZ;
  float sc = lns[DD + c], bc = lnb[DD + c];
  float hcx = ws[OFF_YC + 64 + c];
  float ycc = ws[OFF_YC + c];
#pragma unroll 1
  for (int r = 0; r < 16; ++r) {
    if (!nbb[r]) continue;
    int row = row0 + r;
    int f = fb[row];
    float a = linb[DD + c];
    if (f) {
      const float* xr = X1 + (size_t)row * DD;
#pragma unroll 8
      for (int k = 0; k < DD; ++k) a = fmaf(xr[k], WT[k * DD + c], a);
    } else {
      a += hcx;
    }
    const float* arow = AG + (size_t)row * DD;
#pragma unroll 8
    for (int k = 0; k < DD; ++k) a = fmaf(arow[k], WT[(DD + k) * DD + c], a);
    float s = a;
    for (int m = 1; m < 64; m <<= 1) s += __shfl_xor(s, m);
    float mean = s * (1.f / 64.f);
    float cv = a - mean;
    float vv = cv * cv;
    for (int m = 1; m < 64; m <<= 1) vv += __shfl_xor(vv, m);
    vv *= (1.f / 64.f);
    float y = cv * __frsqrt_rn(vv + LN_EPS) * sc + bc;
    y = fmaxf(y, 0.f);
    float xo = f ? X1[(size_t)row * DD + c] : ycc;
    X2[(size_t)row * DD + c] = xo + y;
  }
}

// ---------------- l=2 tail-only -> TOK ----------------
__global__ __launch_bounds__(256) void k_ltail(const float* __restrict__ tw,
                                               const float* __restrict__ tb,
                                               const float* __restrict__ pe,
                                               const float* __restrict__ linb,
                                               const float* __restrict__ lns,
                                               const float* __restrict__ lnb,
                                               float* __restrict__ ws) {
  __shared__ float rowx[4][DD], rowa[4][DD];
  int b = threadIdx.x >> 6, d = threadIdx.x & 63;
  int j = blockIdx.x, w = blockIdx.y;
  const int* wsi = (const int*)ws;
  int t = wsi[OFF_TSW + b * NNEG + j];
  int h0b = wsi[OFF_H0 + b];
  int p0 = wsi[IOFF_PTR + w * (NN + 1) + t];
  int p1 = wsi[IOFF_PTR + w * (NN + 1) + t + 1];
  const int4* recs = ((const int4*)(wsi + IOFF_REC)) + (size_t)w * NE;
  const float* rell = ws + OFF_RELI + (size_t)2 * NR * NB * DD;
  const float* twl = tw + 2 * NR * DD;
  const float* tbl = tb + 2 * NR * DD;
  const float* xw = ws + OFF_X2 + (size_t)w * XSZ;
  float acc = (t == h0b) ? ws[OFF_QUERY + b * DD + d] : 0.f;
  for (int e = p0; e < p1; ++e) {
    int4 rec = recs[e];
    int src = rec.x, et = rec.y;
    float dtf = __int_as_float(rec.z), wgt = __int_as_float(rec.w);
    float xv = xw[(size_t)src * (NB * DD) + b * DD + d];
    float rv = rell[(size_t)et * (NB * DD) + b * DD + d];
    float te = __cosf(fmaf(dtf, twl[et * DD + d], tbl[et * DD + d]));
    acc = fmaf(xv * rv, te * wgt, acc);
  }
  float xo = xw[(size_t)t * (NB * DD) + b * DD + d];
  rowa[b][d] = acc;
  rowx[b][d] = xo;
  int c = d;
  const float* WT = ws + OFF_LINT + 2 * 2 * DD * DD;  // l = 2
  float hid = linb[2 * DD + c];
#pragma unroll 8
  for (int k = 0; k < DD; ++k) hid = fmaf(rowx[b][k], WT[k * DD + c], hid);
#pragma unroll 8
  for (int k = 0; k < DD; ++k) hid = fmaf(rowa[b][k], WT[(DD + k) * DD + c], hid);
  float s = hid;
  for (int m = 1; m < 64; m <<= 1) s += __shfl_xor(s, m);
  float mean = s * (1.f / 64.f);
  float cv = hid - mean;
  float vv = cv * cv;
  for (int m = 1; m < 64; m <<= 1) vv += __shfl_xor(vv, m);
  vv *= (1.f / 64.f);
  float y = cv * __frsqrt_rn(vv + LN_EPS) * lns[2 * DD + c] + lnb[2 * DD + c];
  y = fmaxf(y, 0.f);
  ws[OFF_TOK + (b * NNEG + j) * NW * DD + w * DD + c] = xo + y + pe[w * DD + c];
}

// ---------------- transformer + final MLP (round-4 structure) ----------------
__global__ __launch_bounds__(768) void k_xform(
    const float* __restrict__ wq, const float* __restrict__ wk,
    const float* __restrict__ wv, const float* __restrict__ wo,
    const float* __restrict__ ffw1, const float* __restrict__ ffb1,
    const float* __restrict__ ffw2, const float* __restrict__ ffb2,
    const float* __restrict__ fln1s, const float* __restrict__ fln1b,
    const float* __restrict__ fln2s, const float* __restrict__ fln2b,
    const float* __restrict__ m1w, const float* __restrict__ m1b,
    const float* __restrict__ m2w, const float* __restrict__ m2b,
    float* __restrict__ ws, float* __restrict__ out) {
  __shared__ float tok[RPB][NW][DD], kvb[RPB][NW][DD], vvb[RPB][NW][DD];
  __shared__ float hbuf[RPB][NW][NFFN];
  __shared__ float feat[RPB][2 * DD];
  __shared__ float red[RPB][2];
  __shared__ float4 wbuf4[4352];
  int tid = threadIdx.x;
  int rr = tid / 192;
  int t192 = tid - rr * 192;
  int tk = t192 >> 6, d = t192 & 63;
  int row = blockIdx.x * RPB + rr, b = row / NNEG;
  tok[rr][tk][d] = ws[OFF_TOK + row * NW * DD + tk * DD + d];
  for (int f = 0; f < NFL; ++f) {
    {
      const float4* s0 = (const float4*)(wq + (size_t)f * DD * DD);
      const float4* s1 = (const float4*)(wk + (size_t)f * DD * DD);
      const float4* s2 = (const float4*)(wv + (size_t)f * DD * DD);
      const float4* s3 = (const float4*)(wo + (size_t)f * DD * DD);
      for (int idx = tid; idx < 4096; idx += 768) {
        int m = idx >> 10, rem = idx & 1023;
        int rrow = rem >> 4, c4 = rem & 15;
        const float4* s = (m == 0) ? s0 : (m == 1) ? s1 : (m == 2) ? s2 : s3;
        wbuf4[(m * 64 + rrow) * 17 + c4] = s[rem];
      }
    }
    __syncthreads();
    float qd = 0.f, kd = 0.f, vd = 0.f;
#pragma unroll
    for (int kk = 0; kk < 16; ++kk) {
      float4 tv = *(const float4*)&tok[rr][tk][4 * kk];
      float4 aq = wbuf4[(0 * 64 + d) * 17 + kk];
      float4 ak = wbuf4[(1 * 64 + d) * 17 + kk];
      float4 av = wbuf4[(2 * 64 + d) * 17 + kk];
      qd += tv.x * aq.x + tv.y * aq.y + tv.z * aq.z + tv.w * aq.w;
      kd += tv.x * ak.x + tv.y * ak.y + tv.z * ak.z + tv.w * ak.w;
      vd += tv.x * av.x + tv.y * av.y + tv.z * av.z + tv.w * av.w;
    }
    kvb[rr][tk][d] = kd;
    vvb[rr][tk][d] = vd;
    __syncthreads();
    float sc[NW];
#pragma unroll
    for (int j = 0; j < NW; ++j) {
      float p = qd * kvb[rr][j][d];
      p += __shfl_xor(p, 1);
      p += __shfl_xor(p, 2);
      p += __shfl_xor(p, 4);
      p += __shfl_xor(p, 8);
      sc[j] = p * 0.25f;
    }
    float mx = fmaxf(sc[0], fmaxf(sc[1], sc[2]));
    float e0 = expf(sc[0] - mx), e1 = expf(sc[1] - mx), e2 = expf(sc[2] - mx);
    float inv = 1.f / (e0 + e1 + e2);
    float od = (e0 * vvb[rr][0][d] + e1 * vvb[rr][1][d] + e2 * vvb[rr][2][d]) * inv;
    __syncthreads();
    kvb[rr][tk][d] = od;
    float ao = 0.f;
#pragma unroll
    for (int kk = 0; kk < 16; ++kk) {
      float4 ov = *(const float4*)&kvb[rr][tk][4 * kk];
      float4 w4 = wbuf4[(3 * 64 + d) * 17 + kk];
      ao += ov.x * w4.x + ov.y * w4.y + ov.z * w4.z + ov.w * w4.w;
    }
    float t1 = tok[rr][tk][d] + ao;
    float s = t1;
    for (int m = 1; m < 64; m <<= 1) s += __shfl_xor(s, m);
    float mean = s * (1.f / 64.f);
    float cv = t1 - mean;
    float v = cv * cv;
    for (int m = 1; m < 64; m <<= 1) v += __shfl_xor(v, m);
    v *= (1.f / 64.f);
    t1 = cv * __frsqrt_rn(v + LN_EPS) * fln1s[f * DD + d] + fln1b[f * DD + d];
    tok[rr][tk][d] = t1;
    __syncthreads();
    {
      const float4* s4 = (const float4*)(ffw1 + (size_t)f * NFFN * DD);
      for (int idx = tid; idx < 4096; idx += 768) {
        int rrow = idx >> 4, c4 = idx & 15;
        wbuf4[rrow * 17 + c4] = s4[idx];
      }
    }
    __syncthreads();
    float h[4];
#pragma unroll
    for (int uu = 0; uu < 4; ++uu) h[uu] = ffb1[f * NFFN + d + 64 * uu];
#pragma unroll
    for (int kk = 0; kk < 16; ++kk) {
      float4 tv = *(const float4*)&tok[rr][tk][4 * kk];
      float4 w0 = wbuf4[(d + 0) * 17 + kk];
      float4 w1 = wbuf4[(d + 64) * 17 + kk];
      float4 w2 = wbuf4[(d + 128) * 17 + kk];
      float4 w3 = wbuf4[(d + 192) * 17 + kk];
      h[0] += tv.x * w0.x + tv.y * w0.y + tv.z * w0.z + tv.w * w0.w;
      h[1] += tv.x * w1.x + tv.y * w1.y + tv.z * w1.z + tv.w * w1.w;
      h[2] += tv.x * w2.x + tv.y * w2.y + tv.z * w2.z + tv.w * w2.w;
      h[3] += tv.x * w3.x + tv.y * w3.y + tv.z * w3.z + tv.w * w3.w;
    }
#pragma unroll
    for (int uu = 0; uu < 4; ++uu) hbuf[rr][tk][d + 64 * uu] = fmaxf(h[uu], 0.f);
    __syncthreads();
    {
      const float4* s4 = (const float4*)(ffw2 + (size_t)f * DD * NFFN);
      for (int idx = tid; idx < 4096; idx += 768) {
        int rrow = idx >> 6, c4 = idx & 63;
        wbuf4[rrow * 65 + c4] = s4[idx];
      }
    }
    __syncthreads();
    float ff = ffb2[f * DD + d];
#pragma unroll 8
    for (int kk = 0; kk < 64; ++kk) {
      float4 hv = *(const float4*)&hbuf[rr][tk][4 * kk];
      float4 w4 = wbuf4[d * 65 + kk];
      ff += hv.x * w4.x + hv.y * w4.y + hv.z * w4.z + hv.w * w4.w;
    }
    float t2 = t1 + ff;
    s = t2;
    for (int m = 1; m < 64; m <<= 1) s += __shfl_xor(s, m);
    mean = s * (1.f / 64.f);
    cv = t2 - mean;
    v = cv * cv;
    for (int m = 1; m < 64; m <<= 1) v += __shfl_xor(v, m);
    v *= (1.f / 64.f);
    t2 = cv * __frsqrt_rn(v + LN_EPS) * fln2s[f * DD + d] + fln2b[f * DD + d];
    tok[rr][tk][d] = t2;
    __syncthreads();
  }
  if (tk == 2) {
    feat[rr][d] = tok[rr][2][d];
    feat[rr][DD + d] = ws[OFF_QUERY + b * DD + d];
  }
  {
    const float4* s4 = (const float4*)m1w;
    for (int idx = tid; idx < 4096; idx += 768) {
      int rrow = idx >> 5, c4 = idx & 31;
      wbuf4[rrow * 33 + c4] = s4[idx];
    }
  }
  __syncthreads();
  float partial = 0.f;
  if (t192 < 2 * DD) {
    int hh = t192;
    float acc = m1b[hh];
#pragma unroll
    for (int kk = 0; kk < 32; ++kk) {
      float4 fv = *(const float4*)&feat[rr][4 * kk];
      float4 w4 = wbuf4[hh * 33 + kk];
      acc += fv.x * w4.x + fv.y * w4.y + fv.z * w4.z + fv.w * w4.w;
    }
    acc = fmaxf(acc, 0.f);
    partial = acc * m2w[hh];
  }
  for (int m = 1; m < 64; m <<= 1) partial += __shfl_xor(partial, m);
  if (d == 0 && tk < 2) red[rr][tk] = partial;
  __syncthreads();
  if (t192 == 0) out[row] = red[rr][0] + red[rr][1] + m2b[0];
}

extern "C" void kernel_launch(void* const* d_in, const int* in_sizes, int n_in,
                              void* d_out, int out_size, void* d_ws, size_t ws_size,
                              hipStream_t stream) {
  const int* qt = (const int*)d_in[0];
  const int* eidx = (const int*)d_in[1];
  const int* etype = (const int*)d_in[2];
  const int* etime = (const int*)d_in[3];
  const float* qemb = (const float*)d_in[4];
  const float* ew = (const float*)d_in[5];
  const float* rlw = (const float*)d_in[6];
  const float* rlb = (const float*)d_in[7];
  const float* tw = (const float*)d_in[8];
  const float* tb = (const float*)d_in[9];
  const float* linw = (const float*)d_in[10];
  const float* linb = (const float*)d_in[11];
  const float* lns = (const float*)d_in[12];
  const float* lnb = (const float*)d_in[13];
  const float* pe = (const float*)d_in[14];
  const float* wq = (const float*)d_in[15];
  const float* wk = (const float*)d_in[16];
  const float* wv = (const float*)d_in[17];
  const float* wo = (const float*)d_in[18];
  const float* ffw1 = (const float*)d_in[19];
  const float* ffb1 = (const float*)d_in[20];
  const float* ffw2 = (const float*)d_in[21];
  const float* ffb2 = (const float*)d_in[22];
  const float* fln1s = (const float*)d_in[23];
  const float* fln1b = (const float*)d_in[24];
  const float* fln2s = (const float*)d_in[25];
  const float* fln2b = (const float*)d_in[26];
  const float* m1w = (const float*)d_in[27];
  const float* m1b = (const float*)d_in[28];
  const float* m2w = (const float*)d_in[29];
  const float* m2b = (const float*)d_in[30];
  float* ws = (float*)d_ws;
  float* out = (float*)d_out;

  k_prep<<<1, 256, 0, stream>>>(qt, qemb, ws);
  k_mint<<<(NE + 255) / 256, 256, 0, stream>>>(etime, ws);
  k_zero_ptr<<<(NW * (NN + 1) + 255) / 256, 256, 0, stream>>>(ws);
  k_transpose<<<(NL * 2 * DD * DD + 255) / 256, 256, 0, stream>>>(linw, ws);
  k_yconst<<<1, 64, 0, stream>>>(linb, lns, lnb, ws);
  k_rel<<<dim3(NR * DD / 256, NL), 256, 0, stream>>>(rlw, rlb, ws);
  k_hist<<<dim3((NE + 255) / 256, NW), 256, 0, stream>>>(eidx, ws);
  k_scan<<<NW, 256, 0, stream>>>(ws);
  k_curinit<<<(NW * NN + 255) / 256, 256, 0, stream>>>(ws);
  k_scatter<<<dim3((NE + 255) / 256, NW), 256, 0, stream>>>(eidx, etype, etime, ew, ws);
  k_need<<<dim3(NNEG, NW), 256, 0, stream>>>(ws);

  k_agg0<<<dim3(NN / 4, NW), 256, 0, stream>>>(tw, tb, ws);
  k_gemm0<<<dim3(NB * NN / 64, NW), 256, 0, stream>>>(linb, lns, lnb, ws);
  k_agg1<<<dim3(NN / 4, NW), 256, 0, stream>>>(tw, tb, ws);
  k_gemm1<<<dim3(NB * NN / 64, NW), 256, 0, stream>>>(linb, lns, lnb, ws);
  k_ltail<<<dim3(NNEG, NW), 256, 0, stream>>>(tw, tb, pe, linb, lns, lnb, ws);
  k_xform<<<NB * NNEG / RPB, 768, 0, stream>>>(wq, wk, wv, wo, ffw1, ffb1, ffw2, ffb2,
                                                fln1s, fln1b, fln2s, fln2b, m1w, m1b, m2w,
                                                m2b, ws, out);
}

// Round 13
// 205.662 us; speedup vs baseline: 6.0007x; 1.3220x over previous
//
#include <hip/hip_runtime.h>
#include <hip/hip_bf16.h>
#include <cmath>

#define NB 4
#define NNEG 33
#define NN 10000
#define NE 100000
#define NW 3
#define DD 64
#define NL 3
#define NR 200
#define NFL 2
#define NFFN 256
#define LN_EPS 1e-5f
#define RPB 4
#define XSZ (NB*NN*DD)

// ---- ws layout (float offsets) ----
#define OFF_QUERY 0
#define OFF_H0    256
#define OFF_TSW   288
#define OFF_MINT  448
#define OFF_RELI  512                                 // NL*NR*NB*DD
#define OFF_LINT  (OFF_RELI + NL*NR*NB*DD)            // NL*2*DD*DD
#define OFF_X     (OFF_LINT + NL*2*DD*DD)             // NW*XSZ (x1, sparse-valid)
#define OFF_X2    (OFF_X + NW*XSZ)                    // NW*XSZ (x2, needed-valid)
#define OFF_TOK   (OFF_X2 + NW*XSZ)                   // NB*NNEG*NW*DD
#define OFF_YC    (OFF_TOK + NB*NNEG*NW*DD)           // 64 yc + 64 hcx
// int offsets
#define IOFF_PTR  (OFF_YC + 128)                      // NW*(NN+1)
#define IOFF_CUR  (IOFF_PTR + NW*(NN+1))              // NW*NN
#define IOFF_REC  ((IOFF_CUR + NW*NN + 3) & ~3)       // NW*NE*4, 16B aligned
#define IOFF_FLG  (IOFF_REC + NW*NE*4)                // NW*NN ints (byte per (n,b))
#define IOFF_NEED (IOFF_FLG + NW*NN)                  // NW*NN ints (byte per (n,b))

// ---------------- prep ----------------
__global__ void k_prep(const int* __restrict__ qt, const float* __restrict__ qemb,
                       float* __restrict__ ws) {
  int tid = threadIdx.x;
  if (tid < NB * DD) {
    int b = tid / DD, d = tid % DD;
    int h0 = qt[(b * NNEG + 0) * 3 + 0];
    bool itn = true;
    for (int j = 1; j < NNEG; ++j) itn = itn && (qt[(b * NNEG + j) * 3 + 0] == h0);
    int r0 = qt[(b * NNEG + 0) * 3 + 1] + (itn ? 0 : NR / 2);
    ws[OFF_QUERY + b * DD + d] = qemb[r0 * DD + d];
    if (d == 0) {
      int t0 = qt[(b * NNEG + 0) * 3 + 2];
      ((int*)ws)[OFF_H0 + b] = itn ? h0 : t0;
    }
  }
  if (tid < NB * NNEG) {
    int b = tid / NNEG, j = tid % NNEG;
    int h0 = qt[(b * NNEG + 0) * 3 + 0];
    bool itn = true;
    for (int jj = 1; jj < NNEG; ++jj) itn = itn && (qt[(b * NNEG + jj) * 3 + 0] == h0);
    int h = qt[(b * NNEG + j) * 3 + 0], t = qt[(b * NNEG + j) * 3 + 2];
    ((int*)ws)[OFF_TSW + tid] = itn ? t : h;
  }
  if (tid == 0) ((int*)ws)[OFF_MINT] = 0x7fffffff;
}

// ---------------- min over edge_time[0] ----------------
__global__ void k_mint(const int* __restrict__ etime, float* __restrict__ ws) {
  int i = blockIdx.x * blockDim.x + threadIdx.x;
  int v = (i < NE) ? etime[i] : 0x7fffffff;
  for (int m = 1; m < 64; m <<= 1) v = min(v, __shfl_xor(v, m));
  if ((threadIdx.x & 63) == 0) atomicMin(&((int*)ws)[OFF_MINT], v);
}

// ---------------- zero ptr + need ----------------
__global__ void k_zero_ptr(float* __restrict__ ws) {
  int i = blockIdx.x * 256 + threadIdx.x;
  if (i < NW * (NN + 1)) ((int*)ws)[IOFF_PTR + i] = 0;
  if (i < NW * NN) ((int*)ws)[IOFF_NEED + i] = 0;
}

// ---------------- transpose lin_w: linT[l][k][c] = lin_w[l][c][k] ----------------
__global__ void k_transpose(const float* __restrict__ lin_w, float* __restrict__ ws) {
  int idx = blockIdx.x * blockDim.x + threadIdx.x;
  if (idx < NL * 2 * DD * DD) {
    int l = idx / (2 * DD * DD), r = idx % (2 * DD * DD), k = r / DD, c = r % DD;
    ws[OFF_LINT + idx] = lin_w[(l * DD + c) * 2 * DD + k];
  }
}

// ---------------- yconst (l0 generic row) + hcx = dot(yc, Wx_l1) ----------------
__global__ void k_yconst(const float* __restrict__ linb, const float* __restrict__ lns,
                         const float* __restrict__ lnb, float* __restrict__ ws) {
  int d = threadIdx.x;  // 64 threads, 1 wave
  float v = linb[d];    // l = 0 bias
  float s = v;
  for (int m = 1; m < 64; m <<= 1) s += __shfl_xor(s, m);
  float mean = s * (1.f / 64.f);
  float cv = v - mean;
  float vv = cv * cv;
  for (int m = 1; m < 64; m <<= 1) vv += __shfl_xor(vv, m);
  vv *= (1.f / 64.f);
  float y = cv * __frsqrt_rn(vv + LN_EPS) * lns[d] + lnb[d];
  y = fmaxf(y, 0.f);
  ws[OFF_YC + d] = y;
  const float* WT1 = ws + OFF_LINT + 2 * DD * DD;  // l = 1, x-half
  float acc = 0.f;
  for (int k = 0; k < 64; ++k) {
    float yk = __shfl(y, k);
    acc = fmaf(yk, WT1[k * DD + d], acc);
  }
  ws[OFF_YC + 64 + d] = acc;
}

// ---------------- histogram of dst ----------------
__global__ void k_hist(const int* __restrict__ eidx, float* __restrict__ ws) {
  int e = blockIdx.x * 256 + threadIdx.x, w = blockIdx.y;
  if (e >= NE) return;
  int dst = eidx[(w * 2 + 1) * NE + e];
  atomicAdd(&((int*)ws)[IOFF_PTR + w * (NN + 1) + dst + 1], 1);
}

// ---------------- inclusive scan -> ptr ----------------
__global__ void k_scan(float* __restrict__ ws) {
  int w = blockIdx.x;
  int* p = (int*)ws + IOFF_PTR + w * (NN + 1);
  __shared__ int wsum[4];
  __shared__ int runv;
  if (threadIdx.x == 0) runv = 0;
  __syncthreads();
  int lane = threadIdx.x & 63, wv = threadIdx.x >> 6;
  for (int base = 0; base < NN + 1; base += 256) {
    int i = base + threadIdx.x;
    int v = (i <= NN) ? p[i] : 0;
    for (int off = 1; off < 64; off <<= 1) {
      int t = __shfl_up(v, off);
      if (lane >= off) v += t;
    }
    if (lane == 63) wsum[wv] = v;
    __syncthreads();
    int add = runv;
    for (int u = 0; u < wv; ++u) add += wsum[u];
    v += add;
    if (i <= NN) p[i] = v;
    __syncthreads();
    if (threadIdx.x == 255) runv = v;
    __syncthreads();
  }
}

// ---------------- cursor init ----------------
__global__ void k_curinit(float* __restrict__ ws) {
  int i = blockIdx.x * 256 + threadIdx.x;
  if (i >= NW * NN) return;
  int w = i / NN, n = i % NN;
  ((int*)ws)[IOFF_CUR + i] = ((int*)ws)[IOFF_PTR + w * (NN + 1) + n];
}

// ---------------- scatter edges into CSR records ----------------
__global__ void k_scatter(const int* __restrict__ eidx, const int* __restrict__ etype,
                          const int* __restrict__ etime, const float* __restrict__ eweight,
                          float* __restrict__ ws) {
  int e = blockIdx.x * 256 + threadIdx.x, w = blockIdx.y;
  if (e >= NE) return;
  int* wsi = (int*)ws;
  int dst = eidx[(w * 2 + 1) * NE + e];
  int pos = atomicAdd(&wsi[IOFF_CUR + w * NN + dst], 1);
  float dt = (float)etime[w * NE + e] - (float)wsi[OFF_MINT];
  int4 rec;
  rec.x = eidx[(w * 2 + 0) * NE + e];
  rec.y = etype[w * NE + e];
  rec.z = __float_as_int(dt);
  rec.w = __float_as_int(eweight[w * NE + e]);
  ((int4*)(wsi + IOFF_REC))[(size_t)w * NE + pos] = rec;
}

// ---------------- need bitmap: tails + their in-edge srcs ----------------
__global__ void k_need(float* __restrict__ ws) {
  int j = blockIdx.x, w = blockIdx.y;
  int b = threadIdx.x >> 6, lane = threadIdx.x & 63;
  const int* wsi = (const int*)ws;
  int t = wsi[OFF_TSW + b * NNEG + j];
  unsigned char* need = (unsigned char*)((int*)ws + IOFF_NEED) + (size_t)w * NN * 4;
  if (lane == 0) need[(size_t)t * 4 + b] = 1;
  int p0 = wsi[IOFF_PTR + w * (NN + 1) + t];
  int p1 = wsi[IOFF_PTR + w * (NN + 1) + t + 1];
  const int4* recs = ((const int4*)(wsi + IOFF_REC)) + (size_t)w * NE;
  for (int e = p0 + lane; e < p1; e += 64) {
    int src = recs[e].x;
    need[(size_t)src * 4 + b] = 1;
  }
}

// ---------------- rel = query @ rel_lin_w.T + b (interleaved) ----------------
__global__ void k_rel(const float* __restrict__ rlw, const float* __restrict__ rlb,
                      float* __restrict__ ws) {
  int l = blockIdx.y;
  int rd = blockIdx.x * blockDim.x + threadIdx.x;
  const float4* wrow = (const float4*)(rlw + ((size_t)(l * NR * DD + rd)) * DD);
  float4 wreg[16];
#pragma unroll
  for (int kk = 0; kk < 16; ++kk) wreg[kk] = wrow[kk];
  float bias = rlb[l * NR * DD + rd];
  int r = rd >> 6, d = rd & 63;
  for (int b = 0; b < NB; ++b) {
    const float4* q4 = (const float4*)(ws + OFF_QUERY + b * DD);
    float acc = 0.f;
#pragma unroll
    for (int kk = 0; kk < 16; ++kk) {
      float4 q = q4[kk];
      acc += q.x * wreg[kk].x + q.y * wreg[kk].y + q.z * wreg[kk].z + q.w * wreg[kk].w;
    }
    ws[OFF_RELI + (size_t)(l * NR + r) * (NB * DD) + b * DD + d] = acc + bias;
  }
}

// ---------------- l0 fused: sparse agg + inline gemm for flagged rows -> X1 -----------
__global__ __launch_bounds__(256) void k_l0(const float* __restrict__ tw,
                                            const float* __restrict__ tb,
                                            const float* __restrict__ linb,
                                            const float* __restrict__ lns,
                                            const float* __restrict__ lnb,
                                            float* __restrict__ ws) {
  __shared__ float aggbuf[4][NB][DD];
  int w = blockIdx.y;
  int lane = threadIdx.x & 63;
  int wv = threadIdx.x >> 6;
  int n = blockIdx.x * 4 + wv;
  int b = lane >> 4;
  int q4i = lane & 15;
  const int* wsi = (const int*)ws;
  int p0 = __builtin_amdgcn_readfirstlane(wsi[IOFF_PTR + w * (NN + 1) + n]);
  int p1 = __builtin_amdgcn_readfirstlane(wsi[IOFF_PTR + w * (NN + 1) + n + 1]);
  const int4* recs = ((const int4*)(wsi + IOFF_REC)) + (size_t)w * NE;
  const float4* RELI4 = (const float4*)(ws + OFF_RELI);  // l = 0
  const float4* TW4 = (const float4*)tw;
  const float4* TB4 = (const float4*)tb;
  int h00 = wsi[OFF_H0 + 0], h01 = wsi[OFF_H0 + 1];
  int h02 = wsi[OFF_H0 + 2], h03 = wsi[OFF_H0 + 3];
  int h0b = wsi[OFF_H0 + b];
  float4 q4b = ((const float4*)(ws + OFF_QUERY))[lane];
  float4 acc;
  if (n == h0b) acc = q4b;
  else { acc.x = 0.f; acc.y = 0.f; acc.z = 0.f; acc.w = 0.f; }
  bool cb = (n == h0b);
  for (int j = p0; j < p1; ++j) {
    int4 rec = recs[j];
    int src = rec.x;
    if (!((src == h00) | (src == h01) | (src == h02) | (src == h03))) continue;
    cb |= (src == h0b);
    int et = rec.y;
    float dtf = __int_as_float(rec.z);
    float m = (src == h0b) ? __int_as_float(rec.w) : 0.f;
    float4 r4 = RELI4[et * 64 + lane];
    float4 w4 = TW4[et * 16 + q4i];
    float4 b4 = TB4[et * 16 + q4i];
    acc.x = fmaf(q4b.x * r4.x, __cosf(fmaf(dtf, w4.x, b4.x)) * m, acc.x);
    acc.y = fmaf(q4b.y * r4.y, __cosf(fmaf(dtf, w4.y, b4.y)) * m, acc.y);
    acc.z = fmaf(q4b.z * r4.z, __cosf(fmaf(dtf, w4.z, b4.z)) * m, acc.z);
    acc.w = fmaf(q4b.w * r4.w, __cosf(fmaf(dtf, w4.w, b4.w)) * m, acc.w);
  }
  char* flg = (char*)(wsi + IOFF_FLG);
  if (q4i == 0) flg[((size_t)w * NN + n) * 4 + b] = cb ? 1 : 0;
  if (!__any(cb)) return;
  // wave-private LDS handoff (intra-wave ordering handled by compiler lgkmcnt)
  *(float4*)&aggbuf[wv][b][q4i * 4] = acc;
  unsigned long long bal = __ballot(cb);
  int c = lane;
  const float* WT = ws + OFF_LINT;  // l = 0
  float* X1 = ws + OFF_X + (size_t)w * XSZ;
  float sc = lns[c], bc = lnb[c];
#pragma unroll 1
  for (int r = 0; r < NB; ++r) {
    if (!((bal >> (r * 16)) & 1ull)) continue;
    int h0r = wsi[OFF_H0 + r];
    float a = linb[c];
    if (n == h0r) {
      const float4* q4 = (const float4*)(ws + OFF_QUERY + r * DD);
      for (int kk = 0; kk < 16; ++kk) {
        float4 qv = q4[kk];
        a = fmaf(qv.x, WT[(4 * kk + 0) * DD + c], a);
        a = fmaf(qv.y, WT[(4 * kk + 1) * DD + c], a);
        a = fmaf(qv.z, WT[(4 * kk + 2) * DD + c], a);
        a = fmaf(qv.w, WT[(4 * kk + 3) * DD + c], a);
      }
    }
#pragma unroll 8
    for (int k = 0; k < DD; ++k)
      a = fmaf(aggbuf[wv][r][k], WT[(DD + k) * DD + c], a);
    float s = a;
    for (int m = 1; m < 64; m <<= 1) s += __shfl_xor(s, m);
    float mean = s * (1.f / 64.f);
    float cv = a - mean;
    float vv = cv * cv;
    for (int m = 1; m < 64; m <<= 1) vv += __shfl_xor(vv, m);
    vv *= (1.f / 64.f);
    float y = cv * __frsqrt_rn(vv + LN_EPS) * sc + bc;
    y = fmaxf(y, 0.f);
    float xo = (n == h0r) ? ws[OFF_QUERY + r * DD + c] : 0.f;
    X1[((size_t)n * NB + r) * DD + c] = xo + y;
  }
}

// ---------------- l1 fused: needed-node agg + inline gemm -> X2 -----------------------
__global__ __launch_bounds__(256) void k_l1(const float* __restrict__ tw,
                                            const float* __restrict__ tb,
                                            const float* __restrict__ linb,
                                            const float* __restrict__ lns,
                                            const float* __restrict__ lnb,
                                            float* __restrict__ ws) {
  __shared__ float aggbuf[4][NB][DD];
  int w = blockIdx.y;
  int lane = threadIdx.x & 63;
  int wv = threadIdx.x >> 6;
  int n = blockIdx.x * 4 + wv;
  int b = lane >> 4;
  int q4i = lane & 15;
  const int* wsi = (const int*)ws;
  unsigned int needw = ((const unsigned int*)(wsi + IOFF_NEED))[(size_t)w * NN + n];
  if (needw == 0u) return;
  int p0 = __builtin_amdgcn_readfirstlane(wsi[IOFF_PTR + w * (NN + 1) + n]);
  int p1 = __builtin_amdgcn_readfirstlane(wsi[IOFF_PTR + w * (NN + 1) + n + 1]);
  const int4* recs = ((const int4*)(wsi + IOFF_REC)) + (size_t)w * NE;
  const float4* X14 = (const float4*)(ws + OFF_X + (size_t)w * XSZ);
  const float4* RELI4 = (const float4*)(ws + OFF_RELI) + (size_t)1 * NR * 64;
  const float4* TW4 = (const float4*)(tw + (size_t)1 * NR * DD);
  const float4* TB4 = (const float4*)(tb + (size_t)1 * NR * DD);
  const unsigned int* xflg = (const unsigned int*)(wsi + IOFF_FLG) + (size_t)w * NN;
  int h0b = wsi[OFF_H0 + b];
  float4 q4b = ((const float4*)(ws + OFF_QUERY))[lane];
  float4 yc4 = ((const float4*)(ws + OFF_YC))[q4i];
  float4 acc;
  if (n == h0b) acc = q4b;
  else { acc.x = 0.f; acc.y = 0.f; acc.z = 0.f; acc.w = 0.f; }
  for (int j = p0; j < p1; ++j) {
    int4 rec = recs[j];
    int src = rec.x, et = rec.y;
    float dtf = __int_as_float(rec.z), wgt = __int_as_float(rec.w);
    unsigned int fw = xflg[src];
    float4 x4;
    if (fw == 0u) {
      x4 = yc4;
    } else {
      int myf = (fw >> (b * 8)) & 0xff;
      if (myf) x4 = X14[(size_t)src * 64 + lane];
      else x4 = yc4;
    }
    float4 r4 = RELI4[et * 64 + lane];
    float4 w4 = TW4[et * 16 + q4i];
    float4 b4 = TB4[et * 16 + q4i];
    acc.x = fmaf(x4.x * r4.x, __cosf(fmaf(dtf, w4.x, b4.x)) * wgt, acc.x);
    acc.y = fmaf(x4.y * r4.y, __cosf(fmaf(dtf, w4.y, b4.y)) * wgt, acc.y);
    acc.z = fmaf(x4.z * r4.z, __cosf(fmaf(dtf, w4.z, b4.z)) * wgt, acc.z);
    acc.w = fmaf(x4.w * r4.w, __cosf(fmaf(dtf, w4.w, b4.w)) * wgt, acc.w);
  }
  // LDS handoff
  *(float4*)&aggbuf[wv][b][q4i * 4] = acc;
  int c = lane;
  const float* WT = ws + OFF_LINT + 2 * DD * DD;  // l = 1
  const float* X1 = ws + OFF_X + (size_t)w * XSZ;
  float* X2 = ws + OFF_X2 + (size_t)w * XSZ;
  const unsigned char* fb = (const unsigned char*)(wsi + IOFF_FLG) + (size_t)w * NN * 4;
  float sc = lns[DD + c], bc = lnb[DD + c];
  float hcx = ws[OFF_YC + 64 + c];
  float ycc = ws[OFF_YC + c];
#pragma unroll 1
  for (int r = 0; r < NB; ++r) {
    if (!((needw >> (r * 8)) & 0xffu)) continue;
    int f = fb[(size_t)n * 4 + r];
    float a = linb[DD + c];
    if (f) {
      const float* xr = X1 + ((size_t)n * NB + r) * DD;
#pragma unroll 8
      for (int k = 0; k < DD; ++k) a = fmaf(xr[k], WT[k * DD + c], a);
    } else {
      a += hcx;
    }
#pragma unroll 8
    for (int k = 0; k < DD; ++k)
      a = fmaf(aggbuf[wv][r][k], WT[(DD + k) * DD + c], a);
    float s = a;
    for (int m = 1; m < 64; m <<= 1) s += __shfl_xor(s, m);
    float mean = s * (1.f / 64.f);
    float cv = a - mean;
    float vv = cv * cv;
    for (int m = 1; m < 64; m <<= 1) vv += __shfl_xor(vv, m);
    vv *= (1.f / 64.f);
    float y = cv * __frsqrt_rn(vv + LN_EPS) * sc + bc;
    y = fmaxf(y, 0.f);
    float xo = f ? X1[((size_t)n * NB + r) * DD + c] : ycc;
    X2[((size_t)n * NB + r) * DD + c] = xo + y;
  }
}

// ---------------- l=2 tail-only -> TOK ----------------
__global__ __launch_bounds__(256) void k_ltail(const float* __restrict__ tw,
                                               const float* __restrict__ tb,
                                               const float* __restrict__ pe,
                                               const float* __restrict__ linb,
                                               const float* __restrict__ lns,
                                               const float* __restrict__ lnb,
                                               float* __restrict__ ws) {
  __shared__ float rowx[4][DD], rowa[4][DD];
  int b = threadIdx.x >> 6, d = threadIdx.x & 63;
  int j = blockIdx.x, w = blockIdx.y;
  const int* wsi = (const int*)ws;
  int t = wsi[OFF_TSW + b * NNEG + j];
  int h0b = wsi[OFF_H0 + b];
  int p0 = wsi[IOFF_PTR + w * (NN + 1) + t];
  int p1 = wsi[IOFF_PTR + w * (NN + 1) + t + 1];
  const int4* recs = ((const int4*)(wsi + IOFF_REC)) + (size_t)w * NE;
  const float* rell = ws + OFF_RELI + (size_t)2 * NR * NB * DD;
  const float* twl = tw + 2 * NR * DD;
  const float* tbl = tb + 2 * NR * DD;
  const float* xw = ws + OFF_X2 + (size_t)w * XSZ;
  float acc = (t == h0b) ? ws[OFF_QUERY + b * DD + d] : 0.f;
  for (int e = p0; e < p1; ++e) {
    int4 rec = recs[e];
    int src = rec.x, et = rec.y;
    float dtf = __int_as_float(rec.z), wgt = __int_as_float(rec.w);
    float xv = xw[(size_t)src * (NB * DD) + b * DD + d];
    float rv = rell[(size_t)et * (NB * DD) + b * DD + d];
    float te = __cosf(fmaf(dtf, twl[et * DD + d], tbl[et * DD + d]));
    acc = fmaf(xv * rv, te * wgt, acc);
  }
  float xo = xw[(size_t)t * (NB * DD) + b * DD + d];
  rowa[b][d] = acc;
  rowx[b][d] = xo;
  int c = d;
  const float* WT = ws + OFF_LINT + 2 * 2 * DD * DD;  // l = 2
  float hid = linb[2 * DD + c];
#pragma unroll 8
  for (int k = 0; k < DD; ++k) hid = fmaf(rowx[b][k], WT[k * DD + c], hid);
#pragma unroll 8
  for (int k = 0; k < DD; ++k) hid = fmaf(rowa[b][k], WT[(DD + k) * DD + c], hid);
  float s = hid;
  for (int m = 1; m < 64; m <<= 1) s += __shfl_xor(s, m);
  float mean = s * (1.f / 64.f);
  float cv = hid - mean;
  float vv = cv * cv;
  for (int m = 1; m < 64; m <<= 1) vv += __shfl_xor(vv, m);
  vv *= (1.f / 64.f);
  float y = cv * __frsqrt_rn(vv + LN_EPS) * lns[2 * DD + c] + lnb[2 * DD + c];
  y = fmaxf(y, 0.f);
  ws[OFF_TOK + (b * NNEG + j) * NW * DD + w * DD + c] = xo + y + pe[w * DD + c];
}

// ---------------- transformer + final MLP (round-4 structure) ----------------
__global__ __launch_bounds__(768) void k_xform(
    const float* __restrict__ wq, const float* __restrict__ wk,
    const float* __restrict__ wv, const float* __restrict__ wo,
    const float* __restrict__ ffw1, const float* __restrict__ ffb1,
    const float* __restrict__ ffw2, const float* __restrict__ ffb2,
    const float* __restrict__ fln1s, const float* __restrict__ fln1b,
    const float* __restrict__ fln2s, const float* __restrict__ fln2b,
    const float* __restrict__ m1w, const float* __restrict__ m1b,
    const float* __restrict__ m2w, const float* __restrict__ m2b,
    float* __restrict__ ws, float* __restrict__ out) {
  __shared__ float tok[RPB][NW][DD], kvb[RPB][NW][DD], vvb[RPB][NW][DD];
  __shared__ float hbuf[RPB][NW][NFFN];
  __shared__ float feat[RPB][2 * DD];
  __shared__ float red[RPB][2];
  __shared__ float4 wbuf4[4352];
  int tid = threadIdx.x;
  int rr = tid / 192;
  int t192 = tid - rr * 192;
  int tk = t192 >> 6, d = t192 & 63;
  int row = blockIdx.x * RPB + rr, b = row / NNEG;
  tok[rr][tk][d] = ws[OFF_TOK + row * NW * DD + tk * DD + d];
  for (int f = 0; f < NFL; ++f) {
    {
      const float4* s0 = (const float4*)(wq + (size_t)f * DD * DD);
      const float4* s1 = (const float4*)(wk + (size_t)f * DD * DD);
      const float4* s2 = (const float4*)(wv + (size_t)f * DD * DD);
      const float4* s3 = (const float4*)(wo + (size_t)f * DD * DD);
      for (int idx = tid; idx < 4096; idx += 768) {
        int m = idx >> 10, rem = idx & 1023;
        int rrow = rem >> 4, c4 = rem & 15;
        const float4* s = (m == 0) ? s0 : (m == 1) ? s1 : (m == 2) ? s2 : s3;
        wbuf4[(m * 64 + rrow) * 17 + c4] = s[rem];
      }
    }
    __syncthreads();
    float qd = 0.f, kd = 0.f, vd = 0.f;
#pragma unroll
    for (int kk = 0; kk < 16; ++kk) {
      float4 tv = *(const float4*)&tok[rr][tk][4 * kk];
      float4 aq = wbuf4[(0 * 64 + d) * 17 + kk];
      float4 ak = wbuf4[(1 * 64 + d) * 17 + kk];
      float4 av = wbuf4[(2 * 64 + d) * 17 + kk];
      qd += tv.x * aq.x + tv.y * aq.y + tv.z * aq.z + tv.w * aq.w;
      kd += tv.x * ak.x + tv.y * ak.y + tv.z * ak.z + tv.w * ak.w;
      vd += tv.x * av.x + tv.y * av.y + tv.z * av.z + tv.w * av.w;
    }
    kvb[rr][tk][d] = kd;
    vvb[rr][tk][d] = vd;
    __syncthreads();
    float sc[NW];
#pragma unroll
    for (int j = 0; j < NW; ++j) {
      float p = qd * kvb[rr][j][d];
      p += __shfl_xor(p, 1);
      p += __shfl_xor(p, 2);
      p += __shfl_xor(p, 4);
      p += __shfl_xor(p, 8);
      sc[j] = p * 0.25f;
    }
    float mx = fmaxf(sc[0], fmaxf(sc[1], sc[2]));
    float e0 = expf(sc[0] - mx), e1 = expf(sc[1] - mx), e2 = expf(sc[2] - mx);
    float inv = 1.f / (e0 + e1 + e2);
    float od = (e0 * vvb[rr][0][d] + e1 * vvb[rr][1][d] + e2 * vvb[rr][2][d]) * inv;
    __syncthreads();
    kvb[rr][tk][d] = od;
    float ao = 0.f;
#pragma unroll
    for (int kk = 0; kk < 16; ++kk) {
      float4 ov = *(const float4*)&kvb[rr][tk][4 * kk];
      float4 w4 = wbuf4[(3 * 64 + d) * 17 + kk];
      ao += ov.x * w4.x + ov.y * w4.y + ov.z * w4.z + ov.w * w4.w;
    }
    float t1 = tok[rr][tk][d] + ao;
    float s = t1;
    for (int m = 1; m < 64; m <<= 1) s += __shfl_xor(s, m);
    float mean = s * (1.f / 64.f);
    float cv = t1 - mean;
    float v = cv * cv;
    for (int m = 1; m < 64; m <<= 1) v += __shfl_xor(v, m);
    v *= (1.f / 64.f);
    t1 = cv * __frsqrt_rn(v + LN_EPS) * fln1s[f * DD + d] + fln1b[f * DD + d];
    tok[rr][tk][d] = t1;
    __syncthreads();
    {
      const float4* s4 = (const float4*)(ffw1 + (size_t)f * NFFN * DD);
      for (int idx = tid; idx < 4096; idx += 768) {
        int rrow = idx >> 4, c4 = idx & 15;
        wbuf4[rrow * 17 + c4] = s4[idx];
      }
    }
    __syncthreads();
    float h[4];
#pragma unroll
    for (int uu = 0; uu < 4; ++uu) h[uu] = ffb1[f * NFFN + d + 64 * uu];
#pragma unroll
    for (int kk = 0; kk < 16; ++kk) {
      float4 tv = *(const float4*)&tok[rr][tk][4 * kk];
      float4 w0 = wbuf4[(d + 0) * 17 + kk];
      float4 w1 = wbuf4[(d + 64) * 17 + kk];
      float4 w2 = wbuf4[(d + 128) * 17 + kk];
      float4 w3 = wbuf4[(d + 192) * 17 + kk];
      h[0] += tv.x * w0.x + tv.y * w0.y + tv.z * w0.z + tv.w * w0.w;
      h[1] += tv.x * w1.x + tv.y * w1.y + tv.z * w1.z + tv.w * w1.w;
      h[2] += tv.x * w2.x + tv.y * w2.y + tv.z * w2.z + tv.w * w2.w;
      h[3] += tv.x * w3.x + tv.y * w3.y + tv.z * w3.z + tv.w * w3.w;
    }
#pragma unroll
    for (int uu = 0; uu < 4; ++uu) hbuf[rr][tk][d + 64 * uu] = fmaxf(h[uu], 0.f);
    __syncthreads();
    {
      const float4* s4 = (const float4*)(ffw2 + (size_t)f * DD * NFFN);
      for (int idx = tid; idx < 4096; idx += 768) {
        int rrow = idx >> 6, c4 = idx & 63;
        wbuf4[rrow * 65 + c4] = s4[idx];
      }
    }
    __syncthreads();
    float ff = ffb2[f * DD + d];
#pragma unroll 8
    for (int kk = 0; kk < 64; ++kk) {
      float4 hv = *(const float4*)&hbuf[rr][tk][4 * kk];
      float4 w4 = wbuf4[d * 65 + kk];
      ff += hv.x * w4.x + hv.y * w4.y + hv.z * w4.z + hv.w * w4.w;
    }
    float t2 = t1 + ff;
    s = t2;
    for (int m = 1; m < 64; m <<= 1) s += __shfl_xor(s, m);
    mean = s * (1.f / 64.f);
    cv = t2 - mean;
    v = cv * cv;
    for (int m = 1; m < 64; m <<= 1) v += __shfl_xor(v, m);
    v *= (1.f / 64.f);
    t2 = cv * __frsqrt_rn(v + LN_EPS) * fln2s[f * DD + d] + fln2b[f * DD + d];
    tok[rr][tk][d] = t2;
    __syncthreads();
  }
  if (tk == 2) {
    feat[rr][d] = tok[rr][2][d];
    feat[rr][DD + d] = ws[OFF_QUERY + b * DD + d];
  }
  {
    const float4* s4 = (const float4*)m1w;
    for (int idx = tid; idx < 4096; idx += 768) {
      int rrow = idx >> 5, c4 = idx & 31;
      wbuf4[rrow * 33 + c4] = s4[idx];
    }
  }
  __syncthreads();
  float partial = 0.f;
  if (t192 < 2 * DD) {
    int hh = t192;
    float acc = m1b[hh];
#pragma unroll
    for (int kk = 0; kk < 32; ++kk) {
      float4 fv = *(const float4*)&feat[rr][4 * kk];
      float4 w4 = wbuf4[hh * 33 + kk];
      acc += fv.x * w4.x + fv.y * w4.y + fv.z * w4.z + fv.w * w4.w;
    }
    acc = fmaxf(acc, 0.f);
    partial = acc * m2w[hh];
  }
  for (int m = 1; m < 64; m <<= 1) partial += __shfl_xor(partial, m);
  if (d == 0 && tk < 2) red[rr][tk] = partial;
  __syncthreads();
  if (t192 == 0) out[row] = red[rr][0] + red[rr][1] + m2b[0];
}

extern "C" void kernel_launch(void* const* d_in, const int* in_sizes, int n_in,
                              void* d_out, int out_size, void* d_ws, size_t ws_size,
                              hipStream_t stream) {
  const int* qt = (const int*)d_in[0];
  const int* eidx = (const int*)d_in[1];
  const int* etype = (const int*)d_in[2];
  const int* etime = (const int*)d_in[3];
  const float* qemb = (const float*)d_in[4];
  const float* ew = (const float*)d_in[5];
  const float* rlw = (const float*)d_in[6];
  const float* rlb = (const float*)d_in[7];
  const float* tw = (const float*)d_in[8];
  const float* tb = (const float*)d_in[9];
  const float* linw = (const float*)d_in[10];
  const float* linb = (const float*)d_in[11];
  const float* lns = (const float*)d_in[12];
  const float* lnb = (const float*)d_in[13];
  const float* pe = (const float*)d_in[14];
  const float* wq = (const float*)d_in[15];
  const float* wk = (const float*)d_in[16];
  const float* wv = (const float*)d_in[17];
  const float* wo = (const float*)d_in[18];
  const float* ffw1 = (const float*)d_in[19];
  const float* ffb1 = (const float*)d_in[20];
  const float* ffw2 = (const float*)d_in[21];
  const float* ffb2 = (const float*)d_in[22];
  const float* fln1s = (const float*)d_in[23];
  const float* fln1b = (const float*)d_in[24];
  const float* fln2s = (const float*)d_in[25];
  const float* fln2b = (const float*)d_in[26];
  const float* m1w = (const float*)d_in[27];
  const float* m1b = (const float*)d_in[28];
  const float* m2w = (const float*)d_in[29];
  const float* m2b = (const float*)d_in[30];
  float* ws = (float*)d_ws;
  float* out = (float*)d_out;

  k_prep<<<1, 256, 0, stream>>>(qt, qemb, ws);
  k_mint<<<(NE + 255) / 256, 256, 0, stream>>>(etime, ws);
  k_zero_ptr<<<(NW * (NN + 1) + 255) / 256, 256, 0, stream>>>(ws);
  k_transpose<<<(NL * 2 * DD * DD + 255) / 256, 256, 0, stream>>>(linw, ws);
  k_yconst<<<1, 64, 0, stream>>>(linb, lns, lnb, ws);
  k_rel<<<dim3(NR * DD / 256, NL), 256, 0, stream>>>(rlw, rlb, ws);
  k_hist<<<dim3((NE + 255) / 256, NW), 256, 0, stream>>>(eidx, ws);
  k_scan<<<NW, 256, 0, stream>>>(ws);
  k_curinit<<<(NW * NN + 255) / 256, 256, 0, stream>>>(ws);
  k_scatter<<<dim3((NE + 255) / 256, NW), 256, 0, stream>>>(eidx, etype, etime, ew, ws);
  k_need<<<dim3(NNEG, NW), 256, 0, stream>>>(ws);

  k_l0<<<dim3(NN / 4, NW), 256, 0, stream>>>(tw, tb, linb, lns, lnb, ws);
  k_l1<<<dim3(NN / 4, NW), 256, 0, stream>>>(tw, tb, linb, lns, lnb, ws);
  k_ltail<<<dim3(NNEG, NW), 256, 0, stream>>>(tw, tb, pe, linb, lns, lnb, ws);
  k_xform<<<NB * NNEG / RPB, 768, 0, stream>>>(wq, wk, wv, wo, ffw1, ffb1, ffw2, ffb2,
                                                fln1s, fln1b, fln2s, fln2b, m1w, m1b, m2w,
                                                m2b, ws, out);
}